// Round 5
// baseline (653.796 us; speedup 1.0000x reference)
//
#include <hip/hip_runtime.h>
#include <cstdint>

// GCN via CSR built by 2-level radix partition (bucket = node>>9) — zero
// global atomics in preprocessing. Z/H tables bf16 (25.6 MB each, L2/L3
// resident). Pooling commutes with @W2 -> final GEMM is [G,128]x[128,128].

#define DD 128
#define PB 512   // partition pass-1 blocks

__device__ __forceinline__ void gAtomAdd(float* p, float v) { unsafeAtomicAdd(p, v); }

__device__ __forceinline__ unsigned short f2bf(float f) {
  union { float f; unsigned u; } v; v.f = f;
  unsigned r = (v.u + 0x7fff + ((v.u >> 16) & 1)) >> 16;   // round-nearest-even
  return (unsigned short)r;
}
__device__ __forceinline__ float bfhi(unsigned u) {
  union { unsigned u; float f; } v; v.u = u & 0xffff0000u; return v.f;
}
__device__ __forceinline__ float bflo(unsigned u) {
  union { unsigned u; float f; } v; v.u = u << 16; return v.f;
}

// ---- per-graph node counts (LDS histogram) ----
__global__ __launch_bounds__(256) void k_gcnt(const int* __restrict__ gid, int* __restrict__ gcnt,
                                              int N, int G) {
  __shared__ int h[64];
  if (threadIdx.x < 64) h[threadIdx.x] = 0;
  __syncthreads();
  int stride = gridDim.x * blockDim.x;
  for (int i = blockIdx.x * blockDim.x + threadIdx.x; i < N; i += stride)
    atomicAdd(&h[gid[i]], 1);
  __syncthreads();
  if (threadIdx.x < (unsigned)G) {
    int v = h[threadIdx.x];
    if (v) atomicAdd(&gcnt[threadIdx.x], v);
  }
}

// ---- partition pass 1a: per-block 256-bin LDS histograms of dst>>9 and src>>9 ----
__global__ __launch_bounds__(256) void k_part1a(const int* __restrict__ src, const int* __restrict__ dst,
                                                unsigned* __restrict__ histD, unsigned* __restrict__ histS,
                                                int E) {
  __shared__ unsigned hD[256], hS[256];
  hD[threadIdx.x] = 0; hS[threadIdx.x] = 0;
  __syncthreads();
  int chunk = (E + gridDim.x - 1) / gridDim.x;
  int e0 = blockIdx.x * chunk, e1 = min(E, e0 + chunk);
  for (int e = e0 + threadIdx.x; e < e1; e += 256) {
    atomicAdd(&hD[(unsigned)dst[e] >> 9], 1u);
    atomicAdd(&hS[(unsigned)src[e] >> 9], 1u);
  }
  __syncthreads();
  histD[blockIdx.x * 256 + threadIdx.x] = hD[threadIdx.x];
  histS[blockIdx.x * 256 + threadIdx.x] = hS[threadIdx.x];
}

// ---- pass 1b: bucket starts + per-(block,bucket) cursors, in place; one block ----
__global__ __launch_bounds__(256) void k_part1b(unsigned* __restrict__ histD, unsigned* __restrict__ histS,
                                                int* __restrict__ bsD, int* __restrict__ bsS, int B) {
  __shared__ unsigned s[256];
  int t = threadIdx.x;
#pragma unroll
  for (int which = 0; which < 2; ++which) {
    unsigned* hist = which ? histS : histD;
    int* bs = which ? bsS : bsD;
    unsigned tot = 0;
    for (int i = 0; i < B; ++i) tot += hist[i * 256 + t];
    s[t] = tot;
    __syncthreads();
    for (int off = 1; off < 256; off <<= 1) {
      unsigned x = (t >= off) ? s[t - off] : 0;
      __syncthreads();
      s[t] += x;
      __syncthreads();
    }
    unsigned excl = s[t] - tot;
    bs[t] = (int)excl;
    if (t == 255) bs[256] = (int)s[255];
    unsigned run = excl;
    for (int i = 0; i < B; ++i) {
      unsigned h = hist[i * 256 + t];
      hist[i * 256 + t] = run;
      run += h;
    }
    __syncthreads();
  }
}

// ---- pass 1c: scatter into reserved per-block slices (no global atomics) ----
__global__ __launch_bounds__(256) void k_part1c(const int* __restrict__ src, const int* __restrict__ dst,
                                                const unsigned* __restrict__ histD, const unsigned* __restrict__ histS,
                                                uint2* __restrict__ pairD, int* __restrict__ partS, int E) {
  __shared__ unsigned cD[256], cS[256];
  cD[threadIdx.x] = histD[blockIdx.x * 256 + threadIdx.x];
  cS[threadIdx.x] = histS[blockIdx.x * 256 + threadIdx.x];
  __syncthreads();
  int chunk = (E + gridDim.x - 1) / gridDim.x;
  int e0 = blockIdx.x * chunk, e1 = min(E, e0 + chunk);
  for (int e = e0 + threadIdx.x; e < e1; e += 256) {
    int sv = src[e], dv = dst[e];
    unsigned p = atomicAdd(&cD[(unsigned)dv >> 9], 1u);
    pairD[p] = make_uint2((unsigned)sv, (unsigned)dv);
    unsigned q = atomicAdd(&cS[(unsigned)sv >> 9], 1u);
    partS[q] = sv;
  }
}

// ---- pass 2d: per dst-bucket — local hist, scan, write offs/degI, place srcS ----
__global__ __launch_bounds__(256) void k_part2d(const uint2* __restrict__ pairD, const int* __restrict__ bsD,
                                                int* __restrict__ offs, int* __restrict__ degI,
                                                int* __restrict__ srcS, int N) {
  __shared__ unsigned hist[512], excl[512], psc[256];
  int k = blockIdx.x, base = k << 9;
  int b0 = bsD[k], b1 = bsD[k + 1];
  hist[threadIdx.x] = 0; hist[threadIdx.x + 256] = 0;
  __syncthreads();
  for (int i = b0 + threadIdx.x; i < b1; i += 256)
    atomicAdd(&hist[pairD[i].y - base], 1u);
  __syncthreads();
  unsigned s0 = hist[2 * threadIdx.x], s1 = hist[2 * threadIdx.x + 1];
  unsigned pr = s0 + s1;
  psc[threadIdx.x] = pr;
  __syncthreads();
  for (int off = 1; off < 256; off <<= 1) {
    unsigned x = (threadIdx.x >= off) ? psc[threadIdx.x - off] : 0;
    __syncthreads();
    psc[threadIdx.x] += x;
    __syncthreads();
  }
  unsigned pex = psc[threadIdx.x] - pr;
  excl[2 * threadIdx.x] = pex;
  excl[2 * threadIdx.x + 1] = pex + s0;
  __syncthreads();
  for (int j = threadIdx.x; j < 512; j += 256) {
    int node = base + j;
    if (node <= N) offs[node] = b0 + (int)excl[j];   // offs[N]=E falls out (dst<N)
    if (node < N) degI[node] = (int)hist[j];
  }
  __syncthreads();
  for (int i = b0 + threadIdx.x; i < b1; i += 256) {
    uint2 p = pairD[i];
    unsigned pos = atomicAdd(&excl[p.y - base], 1u);
    srcS[b0 + (int)pos] = (int)p.x;
  }
}

// ---- pass 2s: per src-bucket — local hist -> nsrc directly ----
__global__ __launch_bounds__(256) void k_part2s(const int* __restrict__ partS, const int* __restrict__ bsS,
                                                float* __restrict__ nsrc, int N) {
  __shared__ unsigned hist[512];
  int k = blockIdx.x, base = k << 9;
  int b0 = bsS[k], b1 = bsS[k + 1];
  hist[threadIdx.x] = 0; hist[threadIdx.x + 256] = 0;
  __syncthreads();
  for (int i = b0 + threadIdx.x; i < b1; i += 256)
    atomicAdd(&hist[partS[i] - base], 1u);
  __syncthreads();
  for (int j = threadIdx.x; j < 512; j += 256) {
    int node = base + j;
    if (node < N) {
      float g = (float)hist[j]; g = g > 0.f ? g : 1.f;
      nsrc[node] = rsqrtf(g);
    }
  }
}

// ---- norms for dst side + pooling weights ----
__global__ __launch_bounds__(256) void k_norm(const int* __restrict__ degI, const int* __restrict__ gcnt,
                                              const int* __restrict__ gid,
                                              float* __restrict__ ndst, float* __restrict__ poolw, int N) {
  int i = blockIdx.x * blockDim.x + threadIdx.x;
  if (i >= N) return;
  float gi = (float)degI[i]; gi = gi > 0.f ? gi : 1.f;
  float nd = rsqrtf(gi);
  ndst[i] = nd;
  float c = (float)gcnt[gid[i]]; c = c > 1.f ? c : 1.f;
  poolw[i] = nd / c;
}

// ---- GEMM1: Zb = bf16( (X @ W1) * nsrc[row] ) ----
__global__ __launch_bounds__(256) void k_gemm1(const float* __restrict__ X, const float* __restrict__ W,
                                               const float* __restrict__ nsrc,
                                               unsigned short* __restrict__ Zb, int N) {
  __shared__ float Wl[128 * 64];
  __shared__ float Xl[64 * 128];
  int bid = blockIdx.x;
  int rb = bid >> 1, ch = bid & 1;
  int row0 = rb * 64;
  int t = threadIdx.x;
  for (int i = t; i < 128 * 16; i += 256) {
    int r = i >> 4, c4 = i & 15;
    float4 v = *(const float4*)(W + r * 128 + ch * 64 + c4 * 4);
    *(float4*)(Wl + r * 64 + c4 * 4) = v;
  }
  for (int i = t; i < 64 * 32; i += 256) {
    int r = i >> 5, c4 = i & 31;
    int row = row0 + r; if (row >= N) row = N - 1;
    float4 v = *(const float4*)(X + (size_t)row * 128 + c4 * 4);
    *(float4*)(Xl + r * 128 + c4 * 4) = v;
  }
  __syncthreads();
  int tx = t & 31, ty = t >> 5;
  float acc[8][2] = {};
  for (int k = 0; k < 128; k += 4) {
    float4 xv[8];
#pragma unroll
    for (int rr = 0; rr < 8; ++rr) xv[rr] = *(const float4*)(Xl + (ty * 8 + rr) * 128 + k);
#pragma unroll
    for (int kk = 0; kk < 4; ++kk) {
      float w0 = Wl[(k + kk) * 64 + tx];
      float w1 = Wl[(k + kk) * 64 + tx + 32];
#pragma unroll
      for (int rr = 0; rr < 8; ++rr) {
        float x = ((const float*)&xv[rr])[kk];
        acc[rr][0] = fmaf(x, w0, acc[rr][0]);
        acc[rr][1] = fmaf(x, w1, acc[rr][1]);
      }
    }
  }
#pragma unroll
  for (int rr = 0; rr < 8; ++rr) {
    int row = row0 + ty * 8 + rr;
    if (row < N) {
      float s = nsrc[row];
      Zb[(size_t)row * 128 + ch * 64 + tx]      = f2bf(acc[rr][0] * s);
      Zb[(size_t)row * 128 + ch * 64 + tx + 32] = f2bf(acc[rr][1] * s);
    }
  }
}

// ---- layer1: per-dst gather-reduce (bf16 rows, half-wave pairs) + fused post-op ----
__global__ __launch_bounds__(256) void k_layer1(const unsigned short* __restrict__ Zb,
                                                const int* __restrict__ offs, const int* __restrict__ srcS,
                                                const float* __restrict__ b1,
                                                const float* __restrict__ nsrc, const float* __restrict__ ndst,
                                                unsigned short* __restrict__ Hb, int N) {
  int lane = threadIdx.x & 63;
  int half = lane >> 5, l32 = lane & 31;
  int d = blockIdx.x * 4 + (threadIdx.x >> 6);
  if (d >= N) return;
  int start = offs[d], end = offs[d + 1];
  float a0 = 0.f, a1 = 0.f, a2 = 0.f, a3 = 0.f;
  int e = start;
  for (; e + 8 <= end; e += 8) {
    int s0 = srcS[e + half], s1 = srcS[e + 2 + half];
    int s2 = srcS[e + 4 + half], s3 = srcS[e + 6 + half];
    uint2 u0 = *(const uint2*)(Zb + (size_t)s0 * 128 + l32 * 4);
    uint2 u1 = *(const uint2*)(Zb + (size_t)s1 * 128 + l32 * 4);
    uint2 u2 = *(const uint2*)(Zb + (size_t)s2 * 128 + l32 * 4);
    uint2 u3 = *(const uint2*)(Zb + (size_t)s3 * 128 + l32 * 4);
    a0 += (bflo(u0.x) + bflo(u1.x)) + (bflo(u2.x) + bflo(u3.x));
    a1 += (bfhi(u0.x) + bfhi(u1.x)) + (bfhi(u2.x) + bfhi(u3.x));
    a2 += (bflo(u0.y) + bflo(u1.y)) + (bflo(u2.y) + bflo(u3.y));
    a3 += (bfhi(u0.y) + bfhi(u1.y)) + (bfhi(u2.y) + bfhi(u3.y));
  }
  for (; e + 2 <= end; e += 2) {
    int s = srcS[e + half];
    uint2 u = *(const uint2*)(Zb + (size_t)s * 128 + l32 * 4);
    a0 += bflo(u.x); a1 += bfhi(u.x); a2 += bflo(u.y); a3 += bfhi(u.y);
  }
  if (e < end && half == 0) {
    int s = srcS[e];
    uint2 u = *(const uint2*)(Zb + (size_t)s * 128 + l32 * 4);
    a0 += bflo(u.x); a1 += bfhi(u.x); a2 += bflo(u.y); a3 += bfhi(u.y);
  }
  a0 += __shfl_xor(a0, 32, 64);
  a1 += __shfl_xor(a1, 32, 64);
  a2 += __shfl_xor(a2, 32, 64);
  a3 += __shfl_xor(a3, 32, 64);
  if (half == 0) {
    float nd = ndst[d], ns = nsrc[d];
    int f = l32 * 4;
    float h0 = fmaxf(fmaf(nd, a0, b1[f + 0]), 0.f) * ns;
    float h1 = fmaxf(fmaf(nd, a1, b1[f + 1]), 0.f) * ns;
    float h2 = fmaxf(fmaf(nd, a2, b1[f + 2]), 0.f) * ns;
    float h3 = fmaxf(fmaf(nd, a3, b1[f + 3]), 0.f) * ns;
    ushort4 o; o.x = f2bf(h0); o.y = f2bf(h1); o.z = f2bf(h2); o.w = f2bf(h3);
    *(ushort4*)(Hb + (size_t)d * 128 + f) = o;
  }
}

// ---- layer2: per-dst gather-reduce (bf16), weighted LDS pool accumulate ----
__global__ __launch_bounds__(1024, 8) void k_layer2(const unsigned short* __restrict__ Hb,
                                                    const int* __restrict__ offs, const int* __restrict__ srcS,
                                                    const int* __restrict__ gid,
                                                    const float* __restrict__ poolw, float* __restrict__ pooled,
                                                    int N, int G) {
  __shared__ float acc[64 * DD];  // 32 KB
  int GD = G * DD;
  for (int i = threadIdx.x; i < GD; i += blockDim.x) acc[i] = 0.f;
  __syncthreads();
  int lane = threadIdx.x & 63;
  int half = lane >> 5, l32 = lane & 31;
  int wid = (blockIdx.x * blockDim.x + threadIdx.x) >> 6;
  int nw = (gridDim.x * blockDim.x) >> 6;
  for (int d = wid; d < N; d += nw) {
    int start = offs[d], end = offs[d + 1];
    float a0 = 0.f, a1 = 0.f, a2 = 0.f, a3 = 0.f;
    int e = start;
    for (; e + 8 <= end; e += 8) {
      int s0 = srcS[e + half], s1 = srcS[e + 2 + half];
      int s2 = srcS[e + 4 + half], s3 = srcS[e + 6 + half];
      uint2 u0 = *(const uint2*)(Hb + (size_t)s0 * 128 + l32 * 4);
      uint2 u1 = *(const uint2*)(Hb + (size_t)s1 * 128 + l32 * 4);
      uint2 u2 = *(const uint2*)(Hb + (size_t)s2 * 128 + l32 * 4);
      uint2 u3 = *(const uint2*)(Hb + (size_t)s3 * 128 + l32 * 4);
      a0 += (bflo(u0.x) + bflo(u1.x)) + (bflo(u2.x) + bflo(u3.x));
      a1 += (bfhi(u0.x) + bfhi(u1.x)) + (bfhi(u2.x) + bfhi(u3.x));
      a2 += (bflo(u0.y) + bflo(u1.y)) + (bflo(u2.y) + bflo(u3.y));
      a3 += (bfhi(u0.y) + bfhi(u1.y)) + (bfhi(u2.y) + bfhi(u3.y));
    }
    for (; e + 2 <= end; e += 2) {
      int s = srcS[e + half];
      uint2 u = *(const uint2*)(Hb + (size_t)s * 128 + l32 * 4);
      a0 += bflo(u.x); a1 += bfhi(u.x); a2 += bflo(u.y); a3 += bfhi(u.y);
    }
    if (e < end && half == 0) {
      int s = srcS[e];
      uint2 u = *(const uint2*)(Hb + (size_t)s * 128 + l32 * 4);
      a0 += bflo(u.x); a1 += bfhi(u.x); a2 += bflo(u.y); a3 += bfhi(u.y);
    }
    a0 += __shfl_xor(a0, 32, 64);
    a1 += __shfl_xor(a1, 32, 64);
    a2 += __shfl_xor(a2, 32, 64);
    a3 += __shfl_xor(a3, 32, 64);
    float w = poolw[d];
    int g = gid[d];
    float* ap = acc + g * DD + l32 * 4;
    if (half == 0) { atomicAdd(ap + 0, w * a0); atomicAdd(ap + 1, w * a1); }
    else           { atomicAdd(ap + 2, w * a2); atomicAdd(ap + 3, w * a3); }
  }
  __syncthreads();
  for (int i = threadIdx.x; i < GD; i += blockDim.x) {
    float v = acc[i];
    if (v != 0.f) gAtomAdd(&pooled[i], v);
  }
}

// ---- out = pooled @ W2 + b2 ----
__global__ __launch_bounds__(128) void k_out(const float* __restrict__ pooled, const float* __restrict__ W2,
                                             const float* __restrict__ b2, float* __restrict__ out) {
  __shared__ float p[DD];
  int g = blockIdx.x, d = threadIdx.x;
  p[d] = pooled[g * DD + d];
  __syncthreads();
  float a = b2[d];
#pragma unroll 4
  for (int k = 0; k < DD; ++k) a = fmaf(p[k], W2[k * DD + d], a);
  out[g * DD + d] = a;
}

extern "C" void kernel_launch(void* const* d_in, const int* in_sizes, int n_in,
                              void* d_out, int out_size, void* d_ws, size_t ws_size,
                              hipStream_t stream) {
  const float* X  = (const float*)d_in[0];
  const float* W1 = (const float*)d_in[1];
  const float* b1 = (const float*)d_in[2];
  const float* W2 = (const float*)d_in[3];
  const float* b2 = (const float*)d_in[4];
  const int* src  = (const int*)d_in[5];
  const int* dst  = (const int*)d_in[6];
  const int* gid  = (const int*)d_in[7];
  int E = in_sizes[5];
  int N = in_sizes[7];
  int G = out_size / DD;   // 64
  int nb = (N >> 9) + 1;   // node buckets (dst < N < 131072 -> key < 256)

  char* w = (char*)d_ws;
  size_t o = 0;
  auto carve = [&](size_t bytes) { char* p = w + o; o += (bytes + 255) & ~(size_t)255; return p; };
  // zero-init region (contiguous at start)
  int*   gcnt   = (int*)  carve((size_t)G * 4);
  float* pooled = (float*)carve((size_t)G * DD * 4);
  size_t zeroBytes = o;
  // rest (all fully written before read)
  unsigned* histD = (unsigned*)carve((size_t)PB * 256 * 4);
  unsigned* histS = (unsigned*)carve((size_t)PB * 256 * 4);
  int*   bsD    = (int*)  carve(257 * 4);
  int*   bsS    = (int*)  carve(257 * 4);
  uint2* pairD  = (uint2*)carve((size_t)E * 8);
  int*   partS  = (int*)  carve((size_t)E * 4);
  int*   srcS   = (int*)  carve((size_t)E * 4);
  int*   offs   = (int*)  carve((size_t)(N + 1) * 4);
  int*   degI   = (int*)  carve((size_t)N * 4);
  float* nsrc   = (float*)carve((size_t)N * 4);
  float* ndst   = (float*)carve((size_t)N * 4);
  float* poolw  = (float*)carve((size_t)N * 4);
  unsigned short* Zb = (unsigned short*)carve((size_t)N * DD * 2);
  unsigned short* Hb = (unsigned short*)carve((size_t)N * DD * 2);

  hipMemsetAsync(d_ws, 0, zeroBytes, stream);

  k_gcnt<<<256, 256, 0, stream>>>(gid, gcnt, N, G);
  k_part1a<<<PB, 256, 0, stream>>>(src, dst, histD, histS, E);
  k_part1b<<<1, 256, 0, stream>>>(histD, histS, bsD, bsS, PB);
  k_part1c<<<PB, 256, 0, stream>>>(src, dst, histD, histS, pairD, partS, E);
  k_part2d<<<nb, 256, 0, stream>>>(pairD, bsD, offs, degI, srcS, N);
  k_part2s<<<nb, 256, 0, stream>>>(partS, bsS, nsrc, N);
  k_norm<<<(N + 255) / 256, 256, 0, stream>>>(degI, gcnt, gid, ndst, poolw, N);
  int rb = (N + 63) / 64;
  k_gemm1<<<rb * 2, 256, 0, stream>>>(X, W1, nsrc, Zb, N);
  k_layer1<<<(N + 3) / 4, 256, 0, stream>>>(Zb, offs, srcS, b1, nsrc, ndst, Hb, N);
  k_layer2<<<512, 1024, 0, stream>>>(Hb, offs, srcS, gid, poolw, pooled, N, G);
  k_out<<<G, DD, 0, stream>>>(pooled, W2, b2, (float*)d_out);
}

// Round 6
// 419.179 us; speedup vs baseline: 1.5597x; 1.5597x over previous
//
#include <hip/hip_runtime.h>
#include <cstdint>

// GCN via CSR built by 2-level radix partition (bucket = node>>9) — zero
// global atomics in preprocessing. Z/H tables bf16 (25.6 MB each, L2/L3
// resident). Pooling commutes with @W2 -> final GEMM is [G,128]x[128,128].

#define DD 128
#define PB 512   // partition pass-1 blocks

__device__ __forceinline__ void gAtomAdd(float* p, float v) { unsafeAtomicAdd(p, v); }

__device__ __forceinline__ unsigned short f2bf(float f) {
  union { float f; unsigned u; } v; v.f = f;
  unsigned r = (v.u + 0x7fff + ((v.u >> 16) & 1)) >> 16;   // round-nearest-even
  return (unsigned short)r;
}
__device__ __forceinline__ float bfhi(unsigned u) {
  union { unsigned u; float f; } v; v.u = u & 0xffff0000u; return v.f;
}
__device__ __forceinline__ float bflo(unsigned u) {
  union { unsigned u; float f; } v; v.u = u << 16; return v.f;
}

// ---- per-graph node counts (LDS histogram) ----
__global__ __launch_bounds__(256) void k_gcnt(const int* __restrict__ gid, int* __restrict__ gcnt,
                                              int N, int G) {
  __shared__ int h[64];
  if (threadIdx.x < 64) h[threadIdx.x] = 0;
  __syncthreads();
  int stride = gridDim.x * blockDim.x;
  for (int i = blockIdx.x * blockDim.x + threadIdx.x; i < N; i += stride)
    atomicAdd(&h[gid[i]], 1);
  __syncthreads();
  if (threadIdx.x < (unsigned)G) {
    int v = h[threadIdx.x];
    if (v) atomicAdd(&gcnt[threadIdx.x], v);
  }
}

// ---- partition pass 1a: per-block 256-bin LDS histograms of dst>>9 and src>>9 ----
__global__ __launch_bounds__(256) void k_part1a(const int* __restrict__ src, const int* __restrict__ dst,
                                                unsigned* __restrict__ histD, unsigned* __restrict__ histS,
                                                int E) {
  __shared__ unsigned hD[256], hS[256];
  hD[threadIdx.x] = 0; hS[threadIdx.x] = 0;
  __syncthreads();
  int chunk = (E + gridDim.x - 1) / gridDim.x;
  int e0 = blockIdx.x * chunk, e1 = min(E, e0 + chunk);
  for (int e = e0 + threadIdx.x; e < e1; e += 256) {
    atomicAdd(&hD[(unsigned)dst[e] >> 9], 1u);
    atomicAdd(&hS[(unsigned)src[e] >> 9], 1u);
  }
  __syncthreads();
  histD[blockIdx.x * 256 + threadIdx.x] = hD[threadIdx.x];
  histS[blockIdx.x * 256 + threadIdx.x] = hS[threadIdx.x];
}

// ---- pscanA: per (table,bucket) — scan the 512 per-block counts in LDS ----
// grid 512: table = blockIdx.x>>8, bucket = blockIdx.x&255
__global__ __launch_bounds__(256) void k_pscanA(unsigned* __restrict__ histD, unsigned* __restrict__ histS,
                                                unsigned* __restrict__ tot) {
  __shared__ unsigned excl[2 * PB / 2], psc[256];   // PB entries
  int table = blockIdx.x >> 8, b = blockIdx.x & 255;
  unsigned* hist = table ? histS : histD;
  int t = threadIdx.x;
  unsigned s0 = hist[(2 * t) * 256 + b];
  unsigned s1 = hist[(2 * t + 1) * 256 + b];
  unsigned pr = s0 + s1;
  psc[t] = pr;
  __syncthreads();
  for (int off = 1; off < 256; off <<= 1) {
    unsigned x = (t >= off) ? psc[t - off] : 0;
    __syncthreads();
    psc[t] += x;
    __syncthreads();
  }
  unsigned pex = psc[t] - pr;
  excl[2 * t] = pex;
  excl[2 * t + 1] = pex + s0;
  __syncthreads();
  hist[(2 * t) * 256 + b] = excl[2 * t];
  hist[(2 * t + 1) * 256 + b] = excl[2 * t + 1];
  if (t == 255) tot[table * 256 + b] = psc[255];
}

// ---- pscanB: one block — scan bucket totals for both tables ----
__global__ __launch_bounds__(256) void k_pscanB(const unsigned* __restrict__ tot,
                                                int* __restrict__ bsD, int* __restrict__ bsS) {
  __shared__ unsigned s[256];
  int t = threadIdx.x;
#pragma unroll
  for (int table = 0; table < 2; ++table) {
    int* bs = table ? bsS : bsD;
    unsigned v = tot[table * 256 + t];
    s[t] = v;
    __syncthreads();
    for (int off = 1; off < 256; off <<= 1) {
      unsigned x = (t >= off) ? s[t - off] : 0;
      __syncthreads();
      s[t] += x;
      __syncthreads();
    }
    bs[t] = (int)(s[t] - v);
    if (t == 255) bs[256] = (int)s[255];
    __syncthreads();
  }
}

// ---- pscanC: add bucket base into every per-(block,bucket) cursor (coalesced) ----
// grid 2*PB: table = blockIdx.x>>9, row i = blockIdx.x&(PB-1)
__global__ __launch_bounds__(256) void k_pscanC(unsigned* __restrict__ histD, unsigned* __restrict__ histS,
                                                const int* __restrict__ bsD, const int* __restrict__ bsS) {
  int table = blockIdx.x >> 9, i = blockIdx.x & (PB - 1);
  unsigned* hist = table ? histS : histD;
  const int* bs = table ? bsS : bsD;
  hist[i * 256 + threadIdx.x] += (unsigned)bs[threadIdx.x];
}

// ---- pass 1c: scatter into reserved per-block slices (no global atomics) ----
__global__ __launch_bounds__(256) void k_part1c(const int* __restrict__ src, const int* __restrict__ dst,
                                                const unsigned* __restrict__ histD, const unsigned* __restrict__ histS,
                                                uint2* __restrict__ pairD, int* __restrict__ partS, int E) {
  __shared__ unsigned cD[256], cS[256];
  cD[threadIdx.x] = histD[blockIdx.x * 256 + threadIdx.x];
  cS[threadIdx.x] = histS[blockIdx.x * 256 + threadIdx.x];
  __syncthreads();
  int chunk = (E + gridDim.x - 1) / gridDim.x;
  int e0 = blockIdx.x * chunk, e1 = min(E, e0 + chunk);
  for (int e = e0 + threadIdx.x; e < e1; e += 256) {
    int sv = src[e], dv = dst[e];
    unsigned p = atomicAdd(&cD[(unsigned)dv >> 9], 1u);
    pairD[p] = make_uint2((unsigned)sv, (unsigned)dv);
    unsigned q = atomicAdd(&cS[(unsigned)sv >> 9], 1u);
    partS[q] = sv;
  }
}

// ---- pass 2d: per dst-bucket — local hist, scan, write offs/degI, place srcS ----
__global__ __launch_bounds__(256) void k_part2d(const uint2* __restrict__ pairD, const int* __restrict__ bsD,
                                                int* __restrict__ offs, int* __restrict__ degI,
                                                int* __restrict__ srcS, int N) {
  __shared__ unsigned hist[512], excl[512], psc[256];
  int k = blockIdx.x, base = k << 9;
  int b0 = bsD[k], b1 = bsD[k + 1];
  hist[threadIdx.x] = 0; hist[threadIdx.x + 256] = 0;
  __syncthreads();
  for (int i = b0 + threadIdx.x; i < b1; i += 256)
    atomicAdd(&hist[pairD[i].y - base], 1u);
  __syncthreads();
  unsigned s0 = hist[2 * threadIdx.x], s1 = hist[2 * threadIdx.x + 1];
  unsigned pr = s0 + s1;
  psc[threadIdx.x] = pr;
  __syncthreads();
  for (int off = 1; off < 256; off <<= 1) {
    unsigned x = (threadIdx.x >= off) ? psc[threadIdx.x - off] : 0;
    __syncthreads();
    psc[threadIdx.x] += x;
    __syncthreads();
  }
  unsigned pex = psc[threadIdx.x] - pr;
  excl[2 * threadIdx.x] = pex;
  excl[2 * threadIdx.x + 1] = pex + s0;
  __syncthreads();
  for (int j = threadIdx.x; j < 512; j += 256) {
    int node = base + j;
    if (node <= N) offs[node] = b0 + (int)excl[j];   // offs[N]=E falls out (dst<N)
    if (node < N) degI[node] = (int)hist[j];
  }
  __syncthreads();
  for (int i = b0 + threadIdx.x; i < b1; i += 256) {
    uint2 p = pairD[i];
    unsigned pos = atomicAdd(&excl[p.y - base], 1u);
    srcS[b0 + (int)pos] = (int)p.x;
  }
}

// ---- pass 2s: per src-bucket — local hist -> nsrc directly ----
__global__ __launch_bounds__(256) void k_part2s(const int* __restrict__ partS, const int* __restrict__ bsS,
                                                float* __restrict__ nsrc, int N) {
  __shared__ unsigned hist[512];
  int k = blockIdx.x, base = k << 9;
  int b0 = bsS[k], b1 = bsS[k + 1];
  hist[threadIdx.x] = 0; hist[threadIdx.x + 256] = 0;
  __syncthreads();
  for (int i = b0 + threadIdx.x; i < b1; i += 256)
    atomicAdd(&hist[partS[i] - base], 1u);
  __syncthreads();
  for (int j = threadIdx.x; j < 512; j += 256) {
    int node = base + j;
    if (node < N) {
      float g = (float)hist[j]; g = g > 0.f ? g : 1.f;
      nsrc[node] = rsqrtf(g);
    }
  }
}

// ---- norms for dst side + pooling weights ----
__global__ __launch_bounds__(256) void k_norm(const int* __restrict__ degI, const int* __restrict__ gcnt,
                                              const int* __restrict__ gid,
                                              float* __restrict__ ndst, float* __restrict__ poolw, int N) {
  int i = blockIdx.x * blockDim.x + threadIdx.x;
  if (i >= N) return;
  float gi = (float)degI[i]; gi = gi > 0.f ? gi : 1.f;
  float nd = rsqrtf(gi);
  ndst[i] = nd;
  float c = (float)gcnt[gid[i]]; c = c > 1.f ? c : 1.f;
  poolw[i] = nd / c;
}

// ---- GEMM1: Zb = bf16( (X @ W1) * nsrc[row] ) ----
__global__ __launch_bounds__(256) void k_gemm1(const float* __restrict__ X, const float* __restrict__ W,
                                               const float* __restrict__ nsrc,
                                               unsigned short* __restrict__ Zb, int N) {
  __shared__ float Wl[128 * 64];
  __shared__ float Xl[64 * 128];
  int bid = blockIdx.x;
  int rb = bid >> 1, ch = bid & 1;
  int row0 = rb * 64;
  int t = threadIdx.x;
  for (int i = t; i < 128 * 16; i += 256) {
    int r = i >> 4, c4 = i & 15;
    float4 v = *(const float4*)(W + r * 128 + ch * 64 + c4 * 4);
    *(float4*)(Wl + r * 64 + c4 * 4) = v;
  }
  for (int i = t; i < 64 * 32; i += 256) {
    int r = i >> 5, c4 = i & 31;
    int row = row0 + r; if (row >= N) row = N - 1;
    float4 v = *(const float4*)(X + (size_t)row * 128 + c4 * 4);
    *(float4*)(Xl + r * 128 + c4 * 4) = v;
  }
  __syncthreads();
  int tx = t & 31, ty = t >> 5;
  float acc[8][2] = {};
  for (int k = 0; k < 128; k += 4) {
    float4 xv[8];
#pragma unroll
    for (int rr = 0; rr < 8; ++rr) xv[rr] = *(const float4*)(Xl + (ty * 8 + rr) * 128 + k);
#pragma unroll
    for (int kk = 0; kk < 4; ++kk) {
      float w0 = Wl[(k + kk) * 64 + tx];
      float w1 = Wl[(k + kk) * 64 + tx + 32];
#pragma unroll
      for (int rr = 0; rr < 8; ++rr) {
        float x = ((const float*)&xv[rr])[kk];
        acc[rr][0] = fmaf(x, w0, acc[rr][0]);
        acc[rr][1] = fmaf(x, w1, acc[rr][1]);
      }
    }
  }
#pragma unroll
  for (int rr = 0; rr < 8; ++rr) {
    int row = row0 + ty * 8 + rr;
    if (row < N) {
      float s = nsrc[row];
      Zb[(size_t)row * 128 + ch * 64 + tx]      = f2bf(acc[rr][0] * s);
      Zb[(size_t)row * 128 + ch * 64 + tx + 32] = f2bf(acc[rr][1] * s);
    }
  }
}

// ---- layer1: per-dst gather-reduce (bf16 rows, half-wave pairs) + fused post-op ----
__global__ __launch_bounds__(256) void k_layer1(const unsigned short* __restrict__ Zb,
                                                const int* __restrict__ offs, const int* __restrict__ srcS,
                                                const float* __restrict__ b1,
                                                const float* __restrict__ nsrc, const float* __restrict__ ndst,
                                                unsigned short* __restrict__ Hb, int N) {
  int lane = threadIdx.x & 63;
  int half = lane >> 5, l32 = lane & 31;
  int d = blockIdx.x * 4 + (threadIdx.x >> 6);
  if (d >= N) return;
  int start = offs[d], end = offs[d + 1];
  float a0 = 0.f, a1 = 0.f, a2 = 0.f, a3 = 0.f;
  int e = start;
  for (; e + 8 <= end; e += 8) {
    int s0 = srcS[e + half], s1 = srcS[e + 2 + half];
    int s2 = srcS[e + 4 + half], s3 = srcS[e + 6 + half];
    uint2 u0 = *(const uint2*)(Zb + (size_t)s0 * 128 + l32 * 4);
    uint2 u1 = *(const uint2*)(Zb + (size_t)s1 * 128 + l32 * 4);
    uint2 u2 = *(const uint2*)(Zb + (size_t)s2 * 128 + l32 * 4);
    uint2 u3 = *(const uint2*)(Zb + (size_t)s3 * 128 + l32 * 4);
    a0 += (bflo(u0.x) + bflo(u1.x)) + (bflo(u2.x) + bflo(u3.x));
    a1 += (bfhi(u0.x) + bfhi(u1.x)) + (bfhi(u2.x) + bfhi(u3.x));
    a2 += (bflo(u0.y) + bflo(u1.y)) + (bflo(u2.y) + bflo(u3.y));
    a3 += (bfhi(u0.y) + bfhi(u1.y)) + (bfhi(u2.y) + bfhi(u3.y));
  }
  for (; e + 2 <= end; e += 2) {
    int s = srcS[e + half];
    uint2 u = *(const uint2*)(Zb + (size_t)s * 128 + l32 * 4);
    a0 += bflo(u.x); a1 += bfhi(u.x); a2 += bflo(u.y); a3 += bfhi(u.y);
  }
  if (e < end && half == 0) {
    int s = srcS[e];
    uint2 u = *(const uint2*)(Zb + (size_t)s * 128 + l32 * 4);
    a0 += bflo(u.x); a1 += bfhi(u.x); a2 += bflo(u.y); a3 += bfhi(u.y);
  }
  a0 += __shfl_xor(a0, 32, 64);
  a1 += __shfl_xor(a1, 32, 64);
  a2 += __shfl_xor(a2, 32, 64);
  a3 += __shfl_xor(a3, 32, 64);
  if (half == 0) {
    float nd = ndst[d], ns = nsrc[d];
    int f = l32 * 4;
    float h0 = fmaxf(fmaf(nd, a0, b1[f + 0]), 0.f) * ns;
    float h1 = fmaxf(fmaf(nd, a1, b1[f + 1]), 0.f) * ns;
    float h2 = fmaxf(fmaf(nd, a2, b1[f + 2]), 0.f) * ns;
    float h3 = fmaxf(fmaf(nd, a3, b1[f + 3]), 0.f) * ns;
    ushort4 o; o.x = f2bf(h0); o.y = f2bf(h1); o.z = f2bf(h2); o.w = f2bf(h3);
    *(ushort4*)(Hb + (size_t)d * 128 + f) = o;
  }
}

// ---- layer2: per-dst gather-reduce (bf16), weighted LDS pool accumulate ----
__global__ __launch_bounds__(1024, 8) void k_layer2(const unsigned short* __restrict__ Hb,
                                                    const int* __restrict__ offs, const int* __restrict__ srcS,
                                                    const int* __restrict__ gid,
                                                    const float* __restrict__ poolw, float* __restrict__ pooled,
                                                    int N, int G) {
  __shared__ float acc[64 * DD];  // 32 KB
  int GD = G * DD;
  for (int i = threadIdx.x; i < GD; i += blockDim.x) acc[i] = 0.f;
  __syncthreads();
  int lane = threadIdx.x & 63;
  int half = lane >> 5, l32 = lane & 31;
  int wid = (blockIdx.x * blockDim.x + threadIdx.x) >> 6;
  int nw = (gridDim.x * blockDim.x) >> 6;
  for (int d = wid; d < N; d += nw) {
    int start = offs[d], end = offs[d + 1];
    float a0 = 0.f, a1 = 0.f, a2 = 0.f, a3 = 0.f;
    int e = start;
    for (; e + 8 <= end; e += 8) {
      int s0 = srcS[e + half], s1 = srcS[e + 2 + half];
      int s2 = srcS[e + 4 + half], s3 = srcS[e + 6 + half];
      uint2 u0 = *(const uint2*)(Hb + (size_t)s0 * 128 + l32 * 4);
      uint2 u1 = *(const uint2*)(Hb + (size_t)s1 * 128 + l32 * 4);
      uint2 u2 = *(const uint2*)(Hb + (size_t)s2 * 128 + l32 * 4);
      uint2 u3 = *(const uint2*)(Hb + (size_t)s3 * 128 + l32 * 4);
      a0 += (bflo(u0.x) + bflo(u1.x)) + (bflo(u2.x) + bflo(u3.x));
      a1 += (bfhi(u0.x) + bfhi(u1.x)) + (bfhi(u2.x) + bfhi(u3.x));
      a2 += (bflo(u0.y) + bflo(u1.y)) + (bflo(u2.y) + bflo(u3.y));
      a3 += (bfhi(u0.y) + bfhi(u1.y)) + (bfhi(u2.y) + bfhi(u3.y));
    }
    for (; e + 2 <= end; e += 2) {
      int s = srcS[e + half];
      uint2 u = *(const uint2*)(Hb + (size_t)s * 128 + l32 * 4);
      a0 += bflo(u.x); a1 += bfhi(u.x); a2 += bflo(u.y); a3 += bfhi(u.y);
    }
    if (e < end && half == 0) {
      int s = srcS[e];
      uint2 u = *(const uint2*)(Hb + (size_t)s * 128 + l32 * 4);
      a0 += bflo(u.x); a1 += bfhi(u.x); a2 += bflo(u.y); a3 += bfhi(u.y);
    }
    a0 += __shfl_xor(a0, 32, 64);
    a1 += __shfl_xor(a1, 32, 64);
    a2 += __shfl_xor(a2, 32, 64);
    a3 += __shfl_xor(a3, 32, 64);
    float w = poolw[d];
    int g = gid[d];
    float* ap = acc + g * DD + l32 * 4;
    if (half == 0) { atomicAdd(ap + 0, w * a0); atomicAdd(ap + 1, w * a1); }
    else           { atomicAdd(ap + 2, w * a2); atomicAdd(ap + 3, w * a3); }
  }
  __syncthreads();
  for (int i = threadIdx.x; i < GD; i += blockDim.x) {
    float v = acc[i];
    if (v != 0.f) gAtomAdd(&pooled[i], v);
  }
}

// ---- out = pooled @ W2 + b2 ----
__global__ __launch_bounds__(128) void k_out(const float* __restrict__ pooled, const float* __restrict__ W2,
                                             const float* __restrict__ b2, float* __restrict__ out) {
  __shared__ float p[DD];
  int g = blockIdx.x, d = threadIdx.x;
  p[d] = pooled[g * DD + d];
  __syncthreads();
  float a = b2[d];
#pragma unroll 4
  for (int k = 0; k < DD; ++k) a = fmaf(p[k], W2[k * DD + d], a);
  out[g * DD + d] = a;
}

extern "C" void kernel_launch(void* const* d_in, const int* in_sizes, int n_in,
                              void* d_out, int out_size, void* d_ws, size_t ws_size,
                              hipStream_t stream) {
  const float* X  = (const float*)d_in[0];
  const float* W1 = (const float*)d_in[1];
  const float* b1 = (const float*)d_in[2];
  const float* W2 = (const float*)d_in[3];
  const float* b2 = (const float*)d_in[4];
  const int* src  = (const int*)d_in[5];
  const int* dst  = (const int*)d_in[6];
  const int* gid  = (const int*)d_in[7];
  int E = in_sizes[5];
  int N = in_sizes[7];
  int G = out_size / DD;   // 64
  int nb = (N >> 9) + 1;   // node buckets (node < N <= 131072 -> key < 256)

  char* w = (char*)d_ws;
  size_t o = 0;
  auto carve = [&](size_t bytes) { char* p = w + o; o += (bytes + 255) & ~(size_t)255; return p; };
  // zero-init region (contiguous at start)
  int*   gcnt   = (int*)  carve((size_t)G * 4);
  float* pooled = (float*)carve((size_t)G * DD * 4);
  size_t zeroBytes = o;
  // rest (all fully written before read)
  unsigned* histD = (unsigned*)carve((size_t)PB * 256 * 4);
  unsigned* histS = (unsigned*)carve((size_t)PB * 256 * 4);
  unsigned* tot   = (unsigned*)carve(512 * 4);
  int*   bsD    = (int*)  carve(257 * 4);
  int*   bsS    = (int*)  carve(257 * 4);
  uint2* pairD  = (uint2*)carve((size_t)E * 8);
  int*   partS  = (int*)  carve((size_t)E * 4);
  int*   srcS   = (int*)  carve((size_t)E * 4);
  int*   offs   = (int*)  carve((size_t)(N + 1) * 4);
  int*   degI   = (int*)  carve((size_t)N * 4);
  float* nsrc   = (float*)carve((size_t)N * 4);
  float* ndst   = (float*)carve((size_t)N * 4);
  float* poolw  = (float*)carve((size_t)N * 4);
  unsigned short* Zb = (unsigned short*)carve((size_t)N * DD * 2);
  unsigned short* Hb = (unsigned short*)carve((size_t)N * DD * 2);

  hipMemsetAsync(d_ws, 0, zeroBytes, stream);

  k_gcnt<<<256, 256, 0, stream>>>(gid, gcnt, N, G);
  k_part1a<<<PB, 256, 0, stream>>>(src, dst, histD, histS, E);
  k_pscanA<<<512, 256, 0, stream>>>(histD, histS, tot);
  k_pscanB<<<1, 256, 0, stream>>>(tot, bsD, bsS);
  k_pscanC<<<2 * PB, 256, 0, stream>>>(histD, histS, bsD, bsS);
  k_part1c<<<PB, 256, 0, stream>>>(src, dst, histD, histS, pairD, partS, E);
  k_part2d<<<nb, 256, 0, stream>>>(pairD, bsD, offs, degI, srcS, N);
  k_part2s<<<nb, 256, 0, stream>>>(partS, bsS, nsrc, N);
  k_norm<<<(N + 255) / 256, 256, 0, stream>>>(degI, gcnt, gid, ndst, poolw, N);
  int rb = (N + 63) / 64;
  k_gemm1<<<rb * 2, 256, 0, stream>>>(X, W1, nsrc, Zb, N);
  k_layer1<<<(N + 3) / 4, 256, 0, stream>>>(Zb, offs, srcS, b1, nsrc, ndst, Hb, N);
  k_layer2<<<512, 1024, 0, stream>>>(Hb, offs, srcS, gid, poolw, pooled, N, G);
  k_out<<<G, DD, 0, stream>>>(pooled, W2, b2, (float*)d_out);
}

// Round 7
// 418.363 us; speedup vs baseline: 1.5627x; 1.0020x over previous
//
#include <hip/hip_runtime.h>
#include <cstdint>

// GCN via CSR/CSC radix partition (bucket = node>>9) — zero global atomics.
// Layer1: per-dst gather of bf16 Z rows. Layer2+pool GEMM-ized:
// pooled = P^T H with P[s][g] = sum_{e:src=s} poolw[dst]·[gid[dst]=g],
// built from the CSC with tiny 8B random loads; then dense streaming GEMM.

#define DD 128
#define PB 512   // partition pass-1 blocks
#define GB 256   // poolgemm split-K blocks
#define KC 32    // poolgemm K-chunk

__device__ __forceinline__ unsigned short f2bf(float f) {
  union { float f; unsigned u; } v; v.f = f;
  unsigned r = (v.u + 0x7fff + ((v.u >> 16) & 1)) >> 16;   // round-nearest-even
  return (unsigned short)r;
}
__device__ __forceinline__ float bfhi(unsigned u) {
  union { unsigned u; float f; } v; v.u = u & 0xffff0000u; return v.f;
}
__device__ __forceinline__ float bflo(unsigned u) {
  union { unsigned u; float f; } v; v.u = u << 16; return v.f;
}

// ---- per-graph node counts (LDS histogram) ----
__global__ __launch_bounds__(256) void k_gcnt(const int* __restrict__ gid, int* __restrict__ gcnt,
                                              int N, int G) {
  __shared__ int h[64];
  if (threadIdx.x < 64) h[threadIdx.x] = 0;
  __syncthreads();
  int stride = gridDim.x * blockDim.x;
  for (int i = blockIdx.x * blockDim.x + threadIdx.x; i < N; i += stride)
    atomicAdd(&h[gid[i]], 1);
  __syncthreads();
  if (threadIdx.x < (unsigned)G) {
    int v = h[threadIdx.x];
    if (v) atomicAdd(&gcnt[threadIdx.x], v);
  }
}

// ---- pass 1a: per-block 256-bin LDS histograms of dst>>9 and src>>9 ----
__global__ __launch_bounds__(256) void k_part1a(const int* __restrict__ src, const int* __restrict__ dst,
                                                unsigned* __restrict__ histD, unsigned* __restrict__ histS,
                                                int E) {
  __shared__ unsigned hD[256], hS[256];
  hD[threadIdx.x] = 0; hS[threadIdx.x] = 0;
  __syncthreads();
  int chunk = (E + gridDim.x - 1) / gridDim.x;
  int e0 = blockIdx.x * chunk, e1 = min(E, e0 + chunk);
  for (int e = e0 + threadIdx.x; e < e1; e += 256) {
    atomicAdd(&hD[(unsigned)dst[e] >> 9], 1u);
    atomicAdd(&hS[(unsigned)src[e] >> 9], 1u);
  }
  __syncthreads();
  histD[blockIdx.x * 256 + threadIdx.x] = hD[threadIdx.x];
  histS[blockIdx.x * 256 + threadIdx.x] = hS[threadIdx.x];
}

// ---- pscanA: per (table,bucket) — scan the PB per-block counts ----
__global__ __launch_bounds__(256) void k_pscanA(unsigned* __restrict__ histD, unsigned* __restrict__ histS,
                                                unsigned* __restrict__ tot) {
  __shared__ unsigned excl[PB], psc[256];
  int table = blockIdx.x >> 8, b = blockIdx.x & 255;
  unsigned* hist = table ? histS : histD;
  int t = threadIdx.x;
  unsigned s0 = hist[(2 * t) * 256 + b];
  unsigned s1 = hist[(2 * t + 1) * 256 + b];
  unsigned pr = s0 + s1;
  psc[t] = pr;
  __syncthreads();
  for (int off = 1; off < 256; off <<= 1) {
    unsigned x = (t >= off) ? psc[t - off] : 0;
    __syncthreads();
    psc[t] += x;
    __syncthreads();
  }
  unsigned pex = psc[t] - pr;
  excl[2 * t] = pex;
  excl[2 * t + 1] = pex + s0;
  __syncthreads();
  hist[(2 * t) * 256 + b] = excl[2 * t];
  hist[(2 * t + 1) * 256 + b] = excl[2 * t + 1];
  if (t == 255) tot[table * 256 + b] = psc[255];
}

// ---- pscanB: one block — scan bucket totals for both tables ----
__global__ __launch_bounds__(256) void k_pscanB(const unsigned* __restrict__ tot,
                                                int* __restrict__ bsD, int* __restrict__ bsS) {
  __shared__ unsigned s[256];
  int t = threadIdx.x;
#pragma unroll
  for (int table = 0; table < 2; ++table) {
    int* bs = table ? bsS : bsD;
    unsigned v = tot[table * 256 + t];
    s[t] = v;
    __syncthreads();
    for (int off = 1; off < 256; off <<= 1) {
      unsigned x = (t >= off) ? s[t - off] : 0;
      __syncthreads();
      s[t] += x;
      __syncthreads();
    }
    bs[t] = (int)(s[t] - v);
    if (t == 255) bs[256] = (int)s[255];
    __syncthreads();
  }
}

// ---- pscanC: add bucket base into per-(block,bucket) cursors ----
__global__ __launch_bounds__(256) void k_pscanC(unsigned* __restrict__ histD, unsigned* __restrict__ histS,
                                                const int* __restrict__ bsD, const int* __restrict__ bsS) {
  int table = blockIdx.x >> 9, i = blockIdx.x & (PB - 1);
  unsigned* hist = table ? histS : histD;
  const int* bs = table ? bsS : bsD;
  hist[i * 256 + threadIdx.x] += (unsigned)bs[threadIdx.x];
}

// ---- pass 1c: scatter (src,dst) pairs into both partitions ----
__global__ __launch_bounds__(256) void k_part1c(const int* __restrict__ src, const int* __restrict__ dst,
                                                const unsigned* __restrict__ histD, const unsigned* __restrict__ histS,
                                                uint2* __restrict__ pairD, uint2* __restrict__ pairS, int E) {
  __shared__ unsigned cD[256], cS[256];
  cD[threadIdx.x] = histD[blockIdx.x * 256 + threadIdx.x];
  cS[threadIdx.x] = histS[blockIdx.x * 256 + threadIdx.x];
  __syncthreads();
  int chunk = (E + gridDim.x - 1) / gridDim.x;
  int e0 = blockIdx.x * chunk, e1 = min(E, e0 + chunk);
  for (int e = e0 + threadIdx.x; e < e1; e += 256) {
    int sv = src[e], dv = dst[e];
    unsigned p = atomicAdd(&cD[(unsigned)dv >> 9], 1u);
    pairD[p] = make_uint2((unsigned)sv, (unsigned)dv);
    unsigned q = atomicAdd(&cS[(unsigned)sv >> 9], 1u);
    pairS[q] = make_uint2((unsigned)sv, (unsigned)dv);
  }
}

// ---- pass 2d: per dst-bucket — hist, scan, write offs/degI, place srcS ----
__global__ __launch_bounds__(256) void k_part2d(const uint2* __restrict__ pairD, const int* __restrict__ bsD,
                                                int* __restrict__ offs, int* __restrict__ degI,
                                                int* __restrict__ srcS, int N) {
  __shared__ unsigned hist[512], excl[512], psc[256];
  int k = blockIdx.x, base = k << 9;
  int b0 = bsD[k], b1 = bsD[k + 1];
  hist[threadIdx.x] = 0; hist[threadIdx.x + 256] = 0;
  __syncthreads();
  for (int i = b0 + threadIdx.x; i < b1; i += 256)
    atomicAdd(&hist[pairD[i].y - base], 1u);
  __syncthreads();
  unsigned s0 = hist[2 * threadIdx.x], s1 = hist[2 * threadIdx.x + 1];
  unsigned pr = s0 + s1;
  psc[threadIdx.x] = pr;
  __syncthreads();
  for (int off = 1; off < 256; off <<= 1) {
    unsigned x = (threadIdx.x >= off) ? psc[threadIdx.x - off] : 0;
    __syncthreads();
    psc[threadIdx.x] += x;
    __syncthreads();
  }
  unsigned pex = psc[threadIdx.x] - pr;
  excl[2 * threadIdx.x] = pex;
  excl[2 * threadIdx.x + 1] = pex + s0;
  __syncthreads();
  for (int j = threadIdx.x; j < 512; j += 256) {
    int node = base + j;
    if (node <= N) offs[node] = b0 + (int)excl[j];
    if (node < N) degI[node] = (int)hist[j];
  }
  __syncthreads();
  for (int i = b0 + threadIdx.x; i < b1; i += 256) {
    uint2 p = pairD[i];
    unsigned pos = atomicAdd(&excl[p.y - base], 1u);
    srcS[b0 + (int)pos] = (int)p.x;
  }
}

// ---- pass 2s: per src-bucket — hist -> nsrc + CSC (offsC, cscD of dst values) ----
__global__ __launch_bounds__(256) void k_part2s(const uint2* __restrict__ pairS, const int* __restrict__ bsS,
                                                int* __restrict__ offsC, int* __restrict__ cscD,
                                                float* __restrict__ nsrc, int N) {
  __shared__ unsigned hist[512], excl[512], psc[256];
  int k = blockIdx.x, base = k << 9;
  int b0 = bsS[k], b1 = bsS[k + 1];
  hist[threadIdx.x] = 0; hist[threadIdx.x + 256] = 0;
  __syncthreads();
  for (int i = b0 + threadIdx.x; i < b1; i += 256)
    atomicAdd(&hist[pairS[i].x - base], 1u);
  __syncthreads();
  unsigned s0 = hist[2 * threadIdx.x], s1 = hist[2 * threadIdx.x + 1];
  unsigned pr = s0 + s1;
  psc[threadIdx.x] = pr;
  __syncthreads();
  for (int off = 1; off < 256; off <<= 1) {
    unsigned x = (threadIdx.x >= off) ? psc[threadIdx.x - off] : 0;
    __syncthreads();
    psc[threadIdx.x] += x;
    __syncthreads();
  }
  unsigned pex = psc[threadIdx.x] - pr;
  excl[2 * threadIdx.x] = pex;
  excl[2 * threadIdx.x + 1] = pex + s0;
  __syncthreads();
  for (int j = threadIdx.x; j < 512; j += 256) {
    int node = base + j;
    if (node <= N) offsC[node] = b0 + (int)excl[j];
    if (node < N) {
      float g = (float)hist[j]; g = g > 0.f ? g : 1.f;
      nsrc[node] = rsqrtf(g);
    }
  }
  __syncthreads();
  for (int i = b0 + threadIdx.x; i < b1; i += 256) {
    uint2 p = pairS[i];
    unsigned pos = atomicAdd(&excl[p.x - base], 1u);
    cscD[b0 + (int)pos] = (int)p.y;
  }
}

// ---- norms for dst side + packed (poolw, gid) ----
__global__ __launch_bounds__(256) void k_norm(const int* __restrict__ degI, const int* __restrict__ gcnt,
                                              const int* __restrict__ gid,
                                              float* __restrict__ ndst, uint2* __restrict__ pwg, int N) {
  int i = blockIdx.x * blockDim.x + threadIdx.x;
  if (i >= N) return;
  float gi = (float)degI[i]; gi = gi > 0.f ? gi : 1.f;
  float nd = rsqrtf(gi);
  ndst[i] = nd;
  float c = (float)gcnt[gid[i]]; c = c > 1.f ? c : 1.f;
  float w = nd / c;
  union { float f; unsigned u; } v; v.f = w;
  pwg[i] = make_uint2(v.u, (unsigned)gid[i]);
}

// ---- GEMM1: Zb = bf16( (X @ W1) * nsrc[row] ) ----
__global__ __launch_bounds__(256) void k_gemm1(const float* __restrict__ X, const float* __restrict__ W,
                                               const float* __restrict__ nsrc,
                                               unsigned short* __restrict__ Zb, int N) {
  __shared__ float Wl[128 * 64];
  __shared__ float Xl[64 * 128];
  int bid = blockIdx.x;
  int rb = bid >> 1, ch = bid & 1;
  int row0 = rb * 64;
  int t = threadIdx.x;
  for (int i = t; i < 128 * 16; i += 256) {
    int r = i >> 4, c4 = i & 15;
    float4 v = *(const float4*)(W + r * 128 + ch * 64 + c4 * 4);
    *(float4*)(Wl + r * 64 + c4 * 4) = v;
  }
  for (int i = t; i < 64 * 32; i += 256) {
    int r = i >> 5, c4 = i & 31;
    int row = row0 + r; if (row >= N) row = N - 1;
    float4 v = *(const float4*)(X + (size_t)row * 128 + c4 * 4);
    *(float4*)(Xl + r * 128 + c4 * 4) = v;
  }
  __syncthreads();
  int tx = t & 31, ty = t >> 5;
  float acc[8][2] = {};
  for (int k = 0; k < 128; k += 4) {
    float4 xv[8];
#pragma unroll
    for (int rr = 0; rr < 8; ++rr) xv[rr] = *(const float4*)(Xl + (ty * 8 + rr) * 128 + k);
#pragma unroll
    for (int kk = 0; kk < 4; ++kk) {
      float w0 = Wl[(k + kk) * 64 + tx];
      float w1 = Wl[(k + kk) * 64 + tx + 32];
#pragma unroll
      for (int rr = 0; rr < 8; ++rr) {
        float x = ((const float*)&xv[rr])[kk];
        acc[rr][0] = fmaf(x, w0, acc[rr][0]);
        acc[rr][1] = fmaf(x, w1, acc[rr][1]);
      }
    }
  }
#pragma unroll
  for (int rr = 0; rr < 8; ++rr) {
    int row = row0 + ty * 8 + rr;
    if (row < N) {
      float s = nsrc[row];
      Zb[(size_t)row * 128 + ch * 64 + tx]      = f2bf(acc[rr][0] * s);
      Zb[(size_t)row * 128 + ch * 64 + tx + 32] = f2bf(acc[rr][1] * s);
    }
  }
}

// ---- layer1: per-dst gather-reduce (bf16 rows, half-wave pairs) + fused post-op ----
__global__ __launch_bounds__(256) void k_layer1(const unsigned short* __restrict__ Zb,
                                                const int* __restrict__ offs, const int* __restrict__ srcS,
                                                const float* __restrict__ b1,
                                                const float* __restrict__ nsrc, const float* __restrict__ ndst,
                                                unsigned short* __restrict__ Hb, int N) {
  int lane = threadIdx.x & 63;
  int half = lane >> 5, l32 = lane & 31;
  int d = blockIdx.x * 4 + (threadIdx.x >> 6);
  if (d >= N) return;
  int start = offs[d], end = offs[d + 1];
  float a0 = 0.f, a1 = 0.f, a2 = 0.f, a3 = 0.f;
  int e = start;
  for (; e + 8 <= end; e += 8) {
    int s0 = srcS[e + half], s1 = srcS[e + 2 + half];
    int s2 = srcS[e + 4 + half], s3 = srcS[e + 6 + half];
    uint2 u0 = *(const uint2*)(Zb + (size_t)s0 * 128 + l32 * 4);
    uint2 u1 = *(const uint2*)(Zb + (size_t)s1 * 128 + l32 * 4);
    uint2 u2 = *(const uint2*)(Zb + (size_t)s2 * 128 + l32 * 4);
    uint2 u3 = *(const uint2*)(Zb + (size_t)s3 * 128 + l32 * 4);
    a0 += (bflo(u0.x) + bflo(u1.x)) + (bflo(u2.x) + bflo(u3.x));
    a1 += (bfhi(u0.x) + bfhi(u1.x)) + (bfhi(u2.x) + bfhi(u3.x));
    a2 += (bflo(u0.y) + bflo(u1.y)) + (bflo(u2.y) + bflo(u3.y));
    a3 += (bfhi(u0.y) + bfhi(u1.y)) + (bfhi(u2.y) + bfhi(u3.y));
  }
  for (; e + 2 <= end; e += 2) {
    int s = srcS[e + half];
    uint2 u = *(const uint2*)(Zb + (size_t)s * 128 + l32 * 4);
    a0 += bflo(u.x); a1 += bfhi(u.x); a2 += bflo(u.y); a3 += bfhi(u.y);
  }
  if (e < end && half == 0) {
    int s = srcS[e];
    uint2 u = *(const uint2*)(Zb + (size_t)s * 128 + l32 * 4);
    a0 += bflo(u.x); a1 += bfhi(u.x); a2 += bflo(u.y); a3 += bfhi(u.y);
  }
  a0 += __shfl_xor(a0, 32, 64);
  a1 += __shfl_xor(a1, 32, 64);
  a2 += __shfl_xor(a2, 32, 64);
  a3 += __shfl_xor(a3, 32, 64);
  if (half == 0) {
    float nd = ndst[d], ns = nsrc[d];
    int f = l32 * 4;
    float h0 = fmaxf(fmaf(nd, a0, b1[f + 0]), 0.f) * ns;
    float h1 = fmaxf(fmaf(nd, a1, b1[f + 1]), 0.f) * ns;
    float h2 = fmaxf(fmaf(nd, a2, b1[f + 2]), 0.f) * ns;
    float h3 = fmaxf(fmaf(nd, a3, b1[f + 3]), 0.f) * ns;
    ushort4 o; o.x = f2bf(h0); o.y = f2bf(h1); o.z = f2bf(h2); o.w = f2bf(h3);
    *(ushort4*)(Hb + (size_t)d * 128 + f) = o;
  }
}

// ---- k_pw: P[s][g] = sum over out-edges of s of poolw[dst]·[gid[dst]=g] ----
__global__ __launch_bounds__(256) void k_pw(const int* __restrict__ offsC, const int* __restrict__ cscD,
                                            const uint2* __restrict__ pwg, float* __restrict__ P, int N) {
  __shared__ float scratch[4][64];
  int wave = threadIdx.x >> 6, lane = threadIdx.x & 63;
  int s = blockIdx.x * 4 + wave;
  bool valid = s < N;
  scratch[wave][lane] = 0.f;
  __syncthreads();
  if (valid) {
    int b0 = offsC[s], b1 = offsC[s + 1];
    for (int e = b0 + lane; e < b1; e += 64) {
      int dv = cscD[e];
      uint2 u = pwg[dv];
      union { unsigned u; float f; } w; w.u = u.x;
      atomicAdd(&scratch[wave][u.y], w.f);
    }
  }
  __syncthreads();
  if (valid) P[(size_t)s * 64 + lane] = scratch[wave][lane];
}

// ---- k_poolgemm: part[b] = P[rows]^T · H[rows]  (streaming split-K GEMM) ----
__global__ __launch_bounds__(256) void k_poolgemm(const float* __restrict__ P,
                                                  const unsigned short* __restrict__ Hb,
                                                  float* __restrict__ part, int N) {
  __shared__ float Pl[KC * 64];    // 8 KB
  __shared__ float Hl[KC * 128];   // 16 KB
  int t = threadIdx.x;
  int chunk = (N + gridDim.x - 1) / gridDim.x;
  int r0 = blockIdx.x * chunk, r1 = min(N, r0 + chunk);
  float acc[4][8] = {};
  int gq = (t & 15) * 4, fo = (t >> 4) * 8;
  for (int rb = r0; rb < r1; rb += KC) {
    {   // stage P chunk: thread t covers 8 floats
      int idx = t * 8;
      int r = idx >> 6, c = idx & 63;
      int row = rb + r;
      float4 z = make_float4(0.f, 0.f, 0.f, 0.f);
      float4 v0 = z, v1 = z;
      if (row < r1) {
        v0 = *(const float4*)(P + (size_t)row * 64 + c);
        v1 = *(const float4*)(P + (size_t)row * 64 + c + 4);
      }
      *(float4*)(Pl + idx) = v0;
      *(float4*)(Pl + idx + 4) = v1;
    }
    {   // stage H chunk: thread t covers 16 bf16 -> f32
      int idx = t * 16;
      int r = idx >> 7, c = idx & 127;
      int row = rb + r;
      if (row < r1) {
        uint4 ua = *(const uint4*)(Hb + (size_t)row * 128 + c);
        uint4 ub = *(const uint4*)(Hb + (size_t)row * 128 + c + 8);
        *(float4*)(Hl + idx)      = make_float4(bflo(ua.x), bfhi(ua.x), bflo(ua.y), bfhi(ua.y));
        *(float4*)(Hl + idx + 4)  = make_float4(bflo(ua.z), bfhi(ua.z), bflo(ua.w), bfhi(ua.w));
        *(float4*)(Hl + idx + 8)  = make_float4(bflo(ub.x), bfhi(ub.x), bflo(ub.y), bfhi(ub.y));
        *(float4*)(Hl + idx + 12) = make_float4(bflo(ub.z), bfhi(ub.z), bflo(ub.w), bfhi(ub.w));
      } else {
        float4 z = make_float4(0.f, 0.f, 0.f, 0.f);
        *(float4*)(Hl + idx) = z; *(float4*)(Hl + idx + 4) = z;
        *(float4*)(Hl + idx + 8) = z; *(float4*)(Hl + idx + 12) = z;
      }
    }
    __syncthreads();
#pragma unroll 4
    for (int r = 0; r < KC; ++r) {
      float4 pv = *(const float4*)(Pl + r * 64 + gq);
      float4 h0 = *(const float4*)(Hl + r * 128 + fo);
      float4 h1 = *(const float4*)(Hl + r * 128 + fo + 4);
      const float* pf = (const float*)&pv;
      const float* hf0 = (const float*)&h0;
      const float* hf1 = (const float*)&h1;
#pragma unroll
      for (int gg = 0; gg < 4; ++gg) {
#pragma unroll
        for (int ff = 0; ff < 4; ++ff) {
          acc[gg][ff]     = fmaf(pf[gg], hf0[ff], acc[gg][ff]);
          acc[gg][ff + 4] = fmaf(pf[gg], hf1[ff], acc[gg][ff + 4]);
        }
      }
    }
    __syncthreads();
  }
  float* base = part + (size_t)blockIdx.x * 64 * DD;
#pragma unroll
  for (int gg = 0; gg < 4; ++gg) {
    *(float4*)(base + (gq + gg) * DD + fo)     = make_float4(acc[gg][0], acc[gg][1], acc[gg][2], acc[gg][3]);
    *(float4*)(base + (gq + gg) * DD + fo + 4) = make_float4(acc[gg][4], acc[gg][5], acc[gg][6], acc[gg][7]);
  }
}

// ---- out: fold split-K partials, then @W2 + b2 ----
__global__ __launch_bounds__(128) void k_out(const float* __restrict__ part, const float* __restrict__ W2,
                                             const float* __restrict__ b2, float* __restrict__ out) {
  __shared__ float p[DD];
  int g = blockIdx.x, d = threadIdx.x;
  float s = 0.f;
#pragma unroll 4
  for (int k = 0; k < GB; ++k) s += part[(size_t)k * 64 * DD + g * DD + d];
  p[d] = s;
  __syncthreads();
  float a = b2[d];
#pragma unroll 4
  for (int k = 0; k < DD; ++k) a = fmaf(p[k], W2[k * DD + d], a);
  out[g * DD + d] = a;
}

extern "C" void kernel_launch(void* const* d_in, const int* in_sizes, int n_in,
                              void* d_out, int out_size, void* d_ws, size_t ws_size,
                              hipStream_t stream) {
  const float* X  = (const float*)d_in[0];
  const float* W1 = (const float*)d_in[1];
  const float* b1 = (const float*)d_in[2];
  const float* W2 = (const float*)d_in[3];
  const float* b2 = (const float*)d_in[4];
  const int* src  = (const int*)d_in[5];
  const int* dst  = (const int*)d_in[6];
  const int* gid  = (const int*)d_in[7];
  int E = in_sizes[5];
  int N = in_sizes[7];
  int G = out_size / DD;   // 64
  int nb = (N >> 9) + 1;   // node buckets

  char* w = (char*)d_ws;
  size_t o = 0;
  auto carve = [&](size_t bytes) { char* p = w + o; o += (bytes + 255) & ~(size_t)255; return p; };
  // zero-init region
  int*   gcnt   = (int*)  carve((size_t)G * 4);
  size_t zeroBytes = o;
  // rest (fully written before read)
  unsigned* histD = (unsigned*)carve((size_t)PB * 256 * 4);
  unsigned* histS = (unsigned*)carve((size_t)PB * 256 * 4);
  unsigned* tot   = (unsigned*)carve(512 * 4);
  int*   bsD    = (int*)  carve(257 * 4);
  int*   bsS    = (int*)  carve(257 * 4);
  uint2* pairD  = (uint2*)carve((size_t)E * 8);   // } together aliased as P [N*64 f32]
  uint2* pairS  = (uint2*)carve((size_t)E * 8);   // }
  int*   srcS   = (int*)  carve((size_t)E * 4);
  int*   cscD   = (int*)  carve((size_t)E * 4);
  int*   offs   = (int*)  carve((size_t)(N + 1) * 4);
  int*   offsC  = (int*)  carve((size_t)(N + 1) * 4);
  int*   degI   = (int*)  carve((size_t)N * 4);
  float* nsrc   = (float*)carve((size_t)N * 4);
  float* ndst   = (float*)carve((size_t)N * 4);
  uint2* pwg    = (uint2*)carve((size_t)N * 8);
  unsigned short* Zb = (unsigned short*)carve((size_t)N * DD * 2);  // aliased as part after layer1
  unsigned short* Hb = (unsigned short*)carve((size_t)N * DD * 2);
  float* P    = (float*)pairD;   // 25.6 MB: pairD+pairS space, dead after part2d/part2s
  float* part = (float*)Zb;      // 8.4 MB:  Zb dead after layer1

  hipMemsetAsync(d_ws, 0, zeroBytes, stream);

  k_gcnt<<<256, 256, 0, stream>>>(gid, gcnt, N, G);
  k_part1a<<<PB, 256, 0, stream>>>(src, dst, histD, histS, E);
  k_pscanA<<<512, 256, 0, stream>>>(histD, histS, tot);
  k_pscanB<<<1, 256, 0, stream>>>(tot, bsD, bsS);
  k_pscanC<<<2 * PB, 256, 0, stream>>>(histD, histS, bsD, bsS);
  k_part1c<<<PB, 256, 0, stream>>>(src, dst, histD, histS, pairD, pairS, E);
  k_part2d<<<nb, 256, 0, stream>>>(pairD, bsD, offs, degI, srcS, N);
  k_part2s<<<nb, 256, 0, stream>>>(pairS, bsS, offsC, cscD, nsrc, N);
  k_norm<<<(N + 255) / 256, 256, 0, stream>>>(degI, gcnt, gid, ndst, pwg, N);
  int rb = (N + 63) / 64;
  k_gemm1<<<rb * 2, 256, 0, stream>>>(X, W1, nsrc, Zb, N);
  k_layer1<<<(N + 3) / 4, 256, 0, stream>>>(Zb, offs, srcS, b1, nsrc, ndst, Hb, N);
  k_pw<<<(N + 3) / 4, 256, 0, stream>>>(offsC, cscD, pwg, P, N);
  k_poolgemm<<<GB, 256, 0, stream>>>(P, Hb, part, N);
  k_out<<<G, DD, 0, stream>>>(part, W2, b2, (float*)d_out);
}

// Round 8
// 387.535 us; speedup vs baseline: 1.6871x; 1.0795x over previous
//
#include <hip/hip_runtime.h>
#include <cstdint>

// GCN via CSR/CSC radix partition (bucket = node>>9) — zero global atomics.
// GEMM1 now bf16 MFMA (16x16x32), LDS-free. Layer1: per-dst gather of bf16 Z.
// Layer2+pool GEMM-ized: pooled = P^T H, P[s][g] = sum_{e:src=s} poolw[dst]·[gid[dst]=g].

#define DD 128
#define PB 512   // partition pass-1 blocks
#define GB 256   // poolgemm split-K blocks
#define KC 32    // poolgemm K-chunk

typedef __attribute__((ext_vector_type(8))) short bf16x8;
typedef __attribute__((ext_vector_type(4))) float f32x4;

__device__ __forceinline__ unsigned short f2bf(float f) {
  union { float f; unsigned u; } v; v.f = f;
  unsigned r = (v.u + 0x7fff + ((v.u >> 16) & 1)) >> 16;   // round-nearest-even
  return (unsigned short)r;
}
__device__ __forceinline__ float bfhi(unsigned u) {
  union { unsigned u; float f; } v; v.u = u & 0xffff0000u; return v.f;
}
__device__ __forceinline__ float bflo(unsigned u) {
  union { unsigned u; float f; } v; v.u = u << 16; return v.f;
}

// ---- per-graph node counts (LDS histogram) ----
__global__ __launch_bounds__(256) void k_gcnt(const int* __restrict__ gid, int* __restrict__ gcnt,
                                              int N, int G) {
  __shared__ int h[64];
  if (threadIdx.x < 64) h[threadIdx.x] = 0;
  __syncthreads();
  int stride = gridDim.x * blockDim.x;
  for (int i = blockIdx.x * blockDim.x + threadIdx.x; i < N; i += stride)
    atomicAdd(&h[gid[i]], 1);
  __syncthreads();
  if (threadIdx.x < (unsigned)G) {
    int v = h[threadIdx.x];
    if (v) atomicAdd(&gcnt[threadIdx.x], v);
  }
}

// ---- pass 1a: per-block 256-bin LDS histograms of dst>>9 and src>>9 ----
__global__ __launch_bounds__(256) void k_part1a(const int* __restrict__ src, const int* __restrict__ dst,
                                                unsigned* __restrict__ histD, unsigned* __restrict__ histS,
                                                int E) {
  __shared__ unsigned hD[256], hS[256];
  hD[threadIdx.x] = 0; hS[threadIdx.x] = 0;
  __syncthreads();
  int chunk = (E + gridDim.x - 1) / gridDim.x;
  int e0 = blockIdx.x * chunk, e1 = min(E, e0 + chunk);
  for (int e = e0 + threadIdx.x; e < e1; e += 256) {
    atomicAdd(&hD[(unsigned)dst[e] >> 9], 1u);
    atomicAdd(&hS[(unsigned)src[e] >> 9], 1u);
  }
  __syncthreads();
  histD[blockIdx.x * 256 + threadIdx.x] = hD[threadIdx.x];
  histS[blockIdx.x * 256 + threadIdx.x] = hS[threadIdx.x];
}

// ---- pscanA: per (table,bucket) — scan the PB per-block counts ----
__global__ __launch_bounds__(256) void k_pscanA(unsigned* __restrict__ histD, unsigned* __restrict__ histS,
                                                unsigned* __restrict__ tot) {
  __shared__ unsigned excl[PB], psc[256];
  int table = blockIdx.x >> 8, b = blockIdx.x & 255;
  unsigned* hist = table ? histS : histD;
  int t = threadIdx.x;
  unsigned s0 = hist[(2 * t) * 256 + b];
  unsigned s1 = hist[(2 * t + 1) * 256 + b];
  unsigned pr = s0 + s1;
  psc[t] = pr;
  __syncthreads();
  for (int off = 1; off < 256; off <<= 1) {
    unsigned x = (t >= off) ? psc[t - off] : 0;
    __syncthreads();
    psc[t] += x;
    __syncthreads();
  }
  unsigned pex = psc[t] - pr;
  excl[2 * t] = pex;
  excl[2 * t + 1] = pex + s0;
  __syncthreads();
  hist[(2 * t) * 256 + b] = excl[2 * t];
  hist[(2 * t + 1) * 256 + b] = excl[2 * t + 1];
  if (t == 255) tot[table * 256 + b] = psc[255];
}

// ---- pscanB: one block — scan bucket totals for both tables ----
__global__ __launch_bounds__(256) void k_pscanB(const unsigned* __restrict__ tot,
                                                int* __restrict__ bsD, int* __restrict__ bsS) {
  __shared__ unsigned s[256];
  int t = threadIdx.x;
#pragma unroll
  for (int table = 0; table < 2; ++table) {
    int* bs = table ? bsS : bsD;
    unsigned v = tot[table * 256 + t];
    s[t] = v;
    __syncthreads();
    for (int off = 1; off < 256; off <<= 1) {
      unsigned x = (t >= off) ? s[t - off] : 0;
      __syncthreads();
      s[t] += x;
      __syncthreads();
    }
    bs[t] = (int)(s[t] - v);
    if (t == 255) bs[256] = (int)s[255];
    __syncthreads();
  }
}

// ---- pscanC: add bucket base into per-(block,bucket) cursors ----
__global__ __launch_bounds__(256) void k_pscanC(unsigned* __restrict__ histD, unsigned* __restrict__ histS,
                                                const int* __restrict__ bsD, const int* __restrict__ bsS) {
  int table = blockIdx.x >> 9, i = blockIdx.x & (PB - 1);
  unsigned* hist = table ? histS : histD;
  const int* bs = table ? bsS : bsD;
  hist[i * 256 + threadIdx.x] += (unsigned)bs[threadIdx.x];
}

// ---- pass 1c: scatter (src,dst) pairs into both partitions ----
__global__ __launch_bounds__(256) void k_part1c(const int* __restrict__ src, const int* __restrict__ dst,
                                                const unsigned* __restrict__ histD, const unsigned* __restrict__ histS,
                                                uint2* __restrict__ pairD, uint2* __restrict__ pairS, int E) {
  __shared__ unsigned cD[256], cS[256];
  cD[threadIdx.x] = histD[blockIdx.x * 256 + threadIdx.x];
  cS[threadIdx.x] = histS[blockIdx.x * 256 + threadIdx.x];
  __syncthreads();
  int chunk = (E + gridDim.x - 1) / gridDim.x;
  int e0 = blockIdx.x * chunk, e1 = min(E, e0 + chunk);
  for (int e = e0 + threadIdx.x; e < e1; e += 256) {
    int sv = src[e], dv = dst[e];
    unsigned p = atomicAdd(&cD[(unsigned)dv >> 9], 1u);
    pairD[p] = make_uint2((unsigned)sv, (unsigned)dv);
    unsigned q = atomicAdd(&cS[(unsigned)sv >> 9], 1u);
    pairS[q] = make_uint2((unsigned)sv, (unsigned)dv);
  }
}

// ---- pass 2d: per dst-bucket — hist, scan, write offs/degI, place srcS ----
__global__ __launch_bounds__(256) void k_part2d(const uint2* __restrict__ pairD, const int* __restrict__ bsD,
                                                int* __restrict__ offs, int* __restrict__ degI,
                                                int* __restrict__ srcS, int N) {
  __shared__ unsigned hist[512], excl[512], psc[256];
  int k = blockIdx.x, base = k << 9;
  int b0 = bsD[k], b1 = bsD[k + 1];
  hist[threadIdx.x] = 0; hist[threadIdx.x + 256] = 0;
  __syncthreads();
  for (int i = b0 + threadIdx.x; i < b1; i += 256)
    atomicAdd(&hist[pairD[i].y - base], 1u);
  __syncthreads();
  unsigned s0 = hist[2 * threadIdx.x], s1 = hist[2 * threadIdx.x + 1];
  unsigned pr = s0 + s1;
  psc[threadIdx.x] = pr;
  __syncthreads();
  for (int off = 1; off < 256; off <<= 1) {
    unsigned x = (threadIdx.x >= off) ? psc[threadIdx.x - off] : 0;
    __syncthreads();
    psc[threadIdx.x] += x;
    __syncthreads();
  }
  unsigned pex = psc[threadIdx.x] - pr;
  excl[2 * threadIdx.x] = pex;
  excl[2 * threadIdx.x + 1] = pex + s0;
  __syncthreads();
  for (int j = threadIdx.x; j < 512; j += 256) {
    int node = base + j;
    if (node <= N) offs[node] = b0 + (int)excl[j];
    if (node < N) degI[node] = (int)hist[j];
  }
  __syncthreads();
  for (int i = b0 + threadIdx.x; i < b1; i += 256) {
    uint2 p = pairD[i];
    unsigned pos = atomicAdd(&excl[p.y - base], 1u);
    srcS[b0 + (int)pos] = (int)p.x;
  }
}

// ---- pass 2s: per src-bucket — hist -> nsrc + CSC (offsC, cscD of dst values) ----
__global__ __launch_bounds__(256) void k_part2s(const uint2* __restrict__ pairS, const int* __restrict__ bsS,
                                                int* __restrict__ offsC, int* __restrict__ cscD,
                                                float* __restrict__ nsrc, int N) {
  __shared__ unsigned hist[512], excl[512], psc[256];
  int k = blockIdx.x, base = k << 9;
  int b0 = bsS[k], b1 = bsS[k + 1];
  hist[threadIdx.x] = 0; hist[threadIdx.x + 256] = 0;
  __syncthreads();
  for (int i = b0 + threadIdx.x; i < b1; i += 256)
    atomicAdd(&hist[pairS[i].x - base], 1u);
  __syncthreads();
  unsigned s0 = hist[2 * threadIdx.x], s1 = hist[2 * threadIdx.x + 1];
  unsigned pr = s0 + s1;
  psc[threadIdx.x] = pr;
  __syncthreads();
  for (int off = 1; off < 256; off <<= 1) {
    unsigned x = (threadIdx.x >= off) ? psc[threadIdx.x - off] : 0;
    __syncthreads();
    psc[threadIdx.x] += x;
    __syncthreads();
  }
  unsigned pex = psc[threadIdx.x] - pr;
  excl[2 * threadIdx.x] = pex;
  excl[2 * threadIdx.x + 1] = pex + s0;
  __syncthreads();
  for (int j = threadIdx.x; j < 512; j += 256) {
    int node = base + j;
    if (node <= N) offsC[node] = b0 + (int)excl[j];
    if (node < N) {
      float g = (float)hist[j]; g = g > 0.f ? g : 1.f;
      nsrc[node] = rsqrtf(g);
    }
  }
  __syncthreads();
  for (int i = b0 + threadIdx.x; i < b1; i += 256) {
    uint2 p = pairS[i];
    unsigned pos = atomicAdd(&excl[p.x - base], 1u);
    cscD[b0 + (int)pos] = (int)p.y;
  }
}

// ---- norms for dst side + packed (poolw, gid) ----
__global__ __launch_bounds__(256) void k_norm(const int* __restrict__ degI, const int* __restrict__ gcnt,
                                              const int* __restrict__ gid,
                                              float* __restrict__ ndst, uint2* __restrict__ pwg, int N) {
  int i = blockIdx.x * blockDim.x + threadIdx.x;
  if (i >= N) return;
  float gi = (float)degI[i]; gi = gi > 0.f ? gi : 1.f;
  float nd = rsqrtf(gi);
  ndst[i] = nd;
  float c = (float)gcnt[gid[i]]; c = c > 1.f ? c : 1.f;
  float w = nd / c;
  union { float f; unsigned u; } v; v.f = w;
  pwg[i] = make_uint2(v.u, (unsigned)gid[i]);
}

// ---- wprep: Wt[n][k] = bf16(W1[k][n])  (32 KB L1-resident B table) ----
__global__ __launch_bounds__(128) void k_wprep(const float* __restrict__ W, unsigned short* __restrict__ Wt) {
  int n = blockIdx.x, k = threadIdx.x;
  Wt[n * 128 + k] = f2bf(W[k * 128 + n]);
}

// ---- GEMM1 (MFMA): Zb = bf16( (X @ W1) * nsrc[row] ), LDS-free ----
// wave = 16 rows; A[m=lane&15][k=quad*8+j]; B[k][n=lane&15] from Wt[n][k];
// C/D: col=lane&15, row=quad*4+reg (verified map).
__global__ __launch_bounds__(256) void k_gemm1(const float* __restrict__ X, const unsigned short* __restrict__ Wt,
                                               const float* __restrict__ nsrc,
                                               unsigned short* __restrict__ Zb, int N) {
  int wave = threadIdx.x >> 6, lane = threadIdx.x & 63;
  int quad = lane >> 4, l16 = lane & 15;
  int row0 = blockIdx.x * 64 + wave * 16;
  int arow = row0 + l16; if (arow >= N) arow = N - 1;
  const float* xr = X + (size_t)arow * 128 + quad * 8;
  f32x4 acc[8];
#pragma unroll
  for (int i = 0; i < 8; ++i) acc[i] = (f32x4){0.f, 0.f, 0.f, 0.f};
#pragma unroll
  for (int kb = 0; kb < 128; kb += 32) {
    float4 x0 = *(const float4*)(xr + kb);
    float4 x1 = *(const float4*)(xr + kb + 4);
    bf16x8 a;
    a[0] = (short)f2bf(x0.x); a[1] = (short)f2bf(x0.y);
    a[2] = (short)f2bf(x0.z); a[3] = (short)f2bf(x0.w);
    a[4] = (short)f2bf(x1.x); a[5] = (short)f2bf(x1.y);
    a[6] = (short)f2bf(x1.z); a[7] = (short)f2bf(x1.w);
#pragma unroll
    for (int nt = 0; nt < 8; ++nt) {
      bf16x8 b = *(const bf16x8*)(Wt + (size_t)(nt * 16 + l16) * 128 + kb + quad * 8);
      acc[nt] = __builtin_amdgcn_mfma_f32_16x16x32_bf16(a, b, acc[nt], 0, 0, 0);
    }
  }
  int rbase = row0 + quad * 4;
#pragma unroll
  for (int r = 0; r < 4; ++r) {
    int row = rbase + r;
    if (row < N) {
      float s = nsrc[row];
#pragma unroll
      for (int nt = 0; nt < 8; ++nt)
        Zb[(size_t)row * 128 + nt * 16 + l16] = f2bf(acc[nt][r] * s);
    }
  }
}

// ---- layer1: per-dst gather-reduce (bf16 rows, half-wave pairs) + fused post-op ----
__global__ __launch_bounds__(256) void k_layer1(const unsigned short* __restrict__ Zb,
                                                const int* __restrict__ offs, const int* __restrict__ srcS,
                                                const float* __restrict__ b1,
                                                const float* __restrict__ nsrc, const float* __restrict__ ndst,
                                                unsigned short* __restrict__ Hb, int N) {
  int lane = threadIdx.x & 63;
  int half = lane >> 5, l32 = lane & 31;
  int d = blockIdx.x * 4 + (threadIdx.x >> 6);
  if (d >= N) return;
  int start = offs[d], end = offs[d + 1];
  float a0 = 0.f, a1 = 0.f, a2 = 0.f, a3 = 0.f;
  int e = start;
  for (; e + 8 <= end; e += 8) {
    int s0 = srcS[e + half], s1 = srcS[e + 2 + half];
    int s2 = srcS[e + 4 + half], s3 = srcS[e + 6 + half];
    uint2 u0 = *(const uint2*)(Zb + (size_t)s0 * 128 + l32 * 4);
    uint2 u1 = *(const uint2*)(Zb + (size_t)s1 * 128 + l32 * 4);
    uint2 u2 = *(const uint2*)(Zb + (size_t)s2 * 128 + l32 * 4);
    uint2 u3 = *(const uint2*)(Zb + (size_t)s3 * 128 + l32 * 4);
    a0 += (bflo(u0.x) + bflo(u1.x)) + (bflo(u2.x) + bflo(u3.x));
    a1 += (bfhi(u0.x) + bfhi(u1.x)) + (bfhi(u2.x) + bfhi(u3.x));
    a2 += (bflo(u0.y) + bflo(u1.y)) + (bflo(u2.y) + bflo(u3.y));
    a3 += (bfhi(u0.y) + bfhi(u1.y)) + (bfhi(u2.y) + bfhi(u3.y));
  }
  for (; e + 2 <= end; e += 2) {
    int s = srcS[e + half];
    uint2 u = *(const uint2*)(Zb + (size_t)s * 128 + l32 * 4);
    a0 += bflo(u.x); a1 += bfhi(u.x); a2 += bflo(u.y); a3 += bfhi(u.y);
  }
  if (e < end && half == 0) {
    int s = srcS[e];
    uint2 u = *(const uint2*)(Zb + (size_t)s * 128 + l32 * 4);
    a0 += bflo(u.x); a1 += bfhi(u.x); a2 += bflo(u.y); a3 += bfhi(u.y);
  }
  a0 += __shfl_xor(a0, 32, 64);
  a1 += __shfl_xor(a1, 32, 64);
  a2 += __shfl_xor(a2, 32, 64);
  a3 += __shfl_xor(a3, 32, 64);
  if (half == 0) {
    float nd = ndst[d], ns = nsrc[d];
    int f = l32 * 4;
    float h0 = fmaxf(fmaf(nd, a0, b1[f + 0]), 0.f) * ns;
    float h1 = fmaxf(fmaf(nd, a1, b1[f + 1]), 0.f) * ns;
    float h2 = fmaxf(fmaf(nd, a2, b1[f + 2]), 0.f) * ns;
    float h3 = fmaxf(fmaf(nd, a3, b1[f + 3]), 0.f) * ns;
    ushort4 o; o.x = f2bf(h0); o.y = f2bf(h1); o.z = f2bf(h2); o.w = f2bf(h3);
    *(ushort4*)(Hb + (size_t)d * 128 + f) = o;
  }
}

// ---- k_pw: P[s][g] = sum over out-edges of s of poolw[dst]·[gid[dst]=g] ----
__global__ __launch_bounds__(256) void k_pw(const int* __restrict__ offsC, const int* __restrict__ cscD,
                                            const uint2* __restrict__ pwg, float* __restrict__ P, int N) {
  __shared__ float scratch[4][64];
  int wave = threadIdx.x >> 6, lane = threadIdx.x & 63;
  int s = blockIdx.x * 4 + wave;
  bool valid = s < N;
  scratch[wave][lane] = 0.f;
  __syncthreads();
  if (valid) {
    int b0 = offsC[s], b1 = offsC[s + 1];
    for (int e = b0 + lane; e < b1; e += 64) {
      int dv = cscD[e];
      uint2 u = pwg[dv];
      union { unsigned u; float f; } w; w.u = u.x;
      atomicAdd(&scratch[wave][u.y], w.f);
    }
  }
  __syncthreads();
  if (valid) P[(size_t)s * 64 + lane] = scratch[wave][lane];
}

// ---- k_poolgemm: part[b] = P[rows]^T · H[rows]  (streaming split-K GEMM) ----
__global__ __launch_bounds__(256) void k_poolgemm(const float* __restrict__ P,
                                                  const unsigned short* __restrict__ Hb,
                                                  float* __restrict__ part, int N) {
  __shared__ float Pl[KC * 64];    // 8 KB
  __shared__ float Hl[KC * 128];   // 16 KB
  int t = threadIdx.x;
  int chunk = (N + gridDim.x - 1) / gridDim.x;
  int r0 = blockIdx.x * chunk, r1 = min(N, r0 + chunk);
  float acc[4][8] = {};
  int gq = (t & 15) * 4, fo = (t >> 4) * 8;
  for (int rb = r0; rb < r1; rb += KC) {
    {
      int idx = t * 8;
      int r = idx >> 6, c = idx & 63;
      int row = rb + r;
      float4 z = make_float4(0.f, 0.f, 0.f, 0.f);
      float4 v0 = z, v1 = z;
      if (row < r1) {
        v0 = *(const float4*)(P + (size_t)row * 64 + c);
        v1 = *(const float4*)(P + (size_t)row * 64 + c + 4);
      }
      *(float4*)(Pl + idx) = v0;
      *(float4*)(Pl + idx + 4) = v1;
    }
    {
      int idx = t * 16;
      int r = idx >> 7, c = idx & 127;
      int row = rb + r;
      if (row < r1) {
        uint4 ua = *(const uint4*)(Hb + (size_t)row * 128 + c);
        uint4 ub = *(const uint4*)(Hb + (size_t)row * 128 + c + 8);
        *(float4*)(Hl + idx)      = make_float4(bflo(ua.x), bfhi(ua.x), bflo(ua.y), bfhi(ua.y));
        *(float4*)(Hl + idx + 4)  = make_float4(bflo(ua.z), bfhi(ua.z), bflo(ua.w), bfhi(ua.w));
        *(float4*)(Hl + idx + 8)  = make_float4(bflo(ub.x), bfhi(ub.x), bflo(ub.y), bfhi(ub.y));
        *(float4*)(Hl + idx + 12) = make_float4(bflo(ub.z), bfhi(ub.z), bflo(ub.w), bfhi(ub.w));
      } else {
        float4 z = make_float4(0.f, 0.f, 0.f, 0.f);
        *(float4*)(Hl + idx) = z; *(float4*)(Hl + idx + 4) = z;
        *(float4*)(Hl + idx + 8) = z; *(float4*)(Hl + idx + 12) = z;
      }
    }
    __syncthreads();
#pragma unroll 4
    for (int r = 0; r < KC; ++r) {
      float4 pv = *(const float4*)(Pl + r * 64 + gq);
      float4 h0 = *(const float4*)(Hl + r * 128 + fo);
      float4 h1 = *(const float4*)(Hl + r * 128 + fo + 4);
      const float* pf = (const float*)&pv;
      const float* hf0 = (const float*)&h0;
      const float* hf1 = (const float*)&h1;
#pragma unroll
      for (int gg = 0; gg < 4; ++gg) {
#pragma unroll
        for (int ff = 0; ff < 4; ++ff) {
          acc[gg][ff]     = fmaf(pf[gg], hf0[ff], acc[gg][ff]);
          acc[gg][ff + 4] = fmaf(pf[gg], hf1[ff], acc[gg][ff + 4]);
        }
      }
    }
    __syncthreads();
  }
  float* base = part + (size_t)blockIdx.x * 64 * DD;
#pragma unroll
  for (int gg = 0; gg < 4; ++gg) {
    *(float4*)(base + (gq + gg) * DD + fo)     = make_float4(acc[gg][0], acc[gg][1], acc[gg][2], acc[gg][3]);
    *(float4*)(base + (gq + gg) * DD + fo + 4) = make_float4(acc[gg][4], acc[gg][5], acc[gg][6], acc[gg][7]);
  }
}

// ---- out: fold split-K partials, then @W2 + b2 ----
__global__ __launch_bounds__(128) void k_out(const float* __restrict__ part, const float* __restrict__ W2,
                                             const float* __restrict__ b2, float* __restrict__ out) {
  __shared__ float p[DD];
  int g = blockIdx.x, d = threadIdx.x;
  float s = 0.f;
#pragma unroll 4
  for (int k = 0; k < GB; ++k) s += part[(size_t)k * 64 * DD + g * DD + d];
  p[d] = s;
  __syncthreads();
  float a = b2[d];
#pragma unroll 4
  for (int k = 0; k < DD; ++k) a = fmaf(p[k], W2[k * DD + d], a);
  out[g * DD + d] = a;
}

extern "C" void kernel_launch(void* const* d_in, const int* in_sizes, int n_in,
                              void* d_out, int out_size, void* d_ws, size_t ws_size,
                              hipStream_t stream) {
  const float* X  = (const float*)d_in[0];
  const float* W1 = (const float*)d_in[1];
  const float* b1 = (const float*)d_in[2];
  const float* W2 = (const float*)d_in[3];
  const float* b2 = (const float*)d_in[4];
  const int* src  = (const int*)d_in[5];
  const int* dst  = (const int*)d_in[6];
  const int* gid  = (const int*)d_in[7];
  int E = in_sizes[5];
  int N = in_sizes[7];
  int G = out_size / DD;   // 64
  int nb = (N >> 9) + 1;   // node buckets

  char* w = (char*)d_ws;
  size_t o = 0;
  auto carve = [&](size_t bytes) { char* p = w + o; o += (bytes + 255) & ~(size_t)255; return p; };
  // zero-init region
  int*   gcnt   = (int*)  carve((size_t)G * 4);
  size_t zeroBytes = o;
  // rest (fully written before read)
  unsigned* histD = (unsigned*)carve((size_t)PB * 256 * 4);
  unsigned* histS = (unsigned*)carve((size_t)PB * 256 * 4);
  unsigned* tot   = (unsigned*)carve(512 * 4);
  int*   bsD    = (int*)  carve(257 * 4);
  int*   bsS    = (int*)  carve(257 * 4);
  uint2* pairD  = (uint2*)carve((size_t)E * 8);   // } together aliased as P [N*64 f32]
  uint2* pairS  = (uint2*)carve((size_t)E * 8);   // }
  int*   srcS   = (int*)  carve((size_t)E * 4);
  int*   cscD   = (int*)  carve((size_t)E * 4);
  int*   offs   = (int*)  carve((size_t)(N + 1) * 4);
  int*   offsC  = (int*)  carve((size_t)(N + 1) * 4);
  int*   degI   = (int*)  carve((size_t)N * 4);
  float* nsrc   = (float*)carve((size_t)N * 4);
  float* ndst   = (float*)carve((size_t)N * 4);
  uint2* pwg    = (uint2*)carve((size_t)N * 8);
  unsigned short* Wt = (unsigned short*)carve(128 * 128 * 2);
  unsigned short* Zb = (unsigned short*)carve((size_t)N * DD * 2);  // aliased as part after layer1
  unsigned short* Hb = (unsigned short*)carve((size_t)N * DD * 2);
  float* P    = (float*)pairD;   // 25.6 MB: pairD+pairS space, dead after part2d/part2s
  float* part = (float*)Zb;      // 8.4 MB:  Zb dead after layer1

  hipMemsetAsync(d_ws, 0, zeroBytes, stream);

  k_gcnt<<<256, 256, 0, stream>>>(gid, gcnt, N, G);
  k_part1a<<<PB, 256, 0, stream>>>(src, dst, histD, histS, E);
  k_pscanA<<<512, 256, 0, stream>>>(histD, histS, tot);
  k_pscanB<<<1, 256, 0, stream>>>(tot, bsD, bsS);
  k_pscanC<<<2 * PB, 256, 0, stream>>>(histD, histS, bsD, bsS);
  k_part1c<<<PB, 256, 0, stream>>>(src, dst, histD, histS, pairD, pairS, E);
  k_part2d<<<nb, 256, 0, stream>>>(pairD, bsD, offs, degI, srcS, N);
  k_part2s<<<nb, 256, 0, stream>>>(pairS, bsS, offsC, cscD, nsrc, N);
  k_norm<<<(N + 255) / 256, 256, 0, stream>>>(degI, gcnt, gid, ndst, pwg, N);
  k_wprep<<<128, 128, 0, stream>>>(W1, Wt);
  k_gemm1<<<(N + 63) / 64, 256, 0, stream>>>(X, Wt, nsrc, Zb, N);
  k_layer1<<<(N + 3) / 4, 256, 0, stream>>>(Zb, offs, srcS, b1, nsrc, ndst, Hb, N);
  k_pw<<<(N + 3) / 4, 256, 0, stream>>>(offsC, cscD, pwg, P, N);
  k_poolgemm<<<GB, 256, 0, stream>>>(P, Hb, part, N);
  k_out<<<G, DD, 0, stream>>>(part, W2, b2, (float*)d_out);
}

// Round 9
// 372.051 us; speedup vs baseline: 1.7573x; 1.0416x over previous
//
#include <hip/hip_runtime.h>
#include <cstdint>

// GCN via radix partition (bucket = node>>9), packed u32 edge records.
// Z table fp8-e4m3 (12.8 MB) — layer1 gather bytes halved. H bf16.
// pooled = P^T H (P built per-src-bucket in 128 KB LDS tiles); out = pooled@W2+b2.

#define DD 128
#define PB 512   // partition pass-1 blocks
#define GB 256   // poolgemm split-K blocks
#define KC 32    // poolgemm K-chunk

typedef __attribute__((ext_vector_type(8))) short bf16x8;
typedef __attribute__((ext_vector_type(4))) float f32x4;
typedef __attribute__((ext_vector_type(2))) float f32x2;

__device__ __forceinline__ unsigned short f2bf(float f) {
  union { float f; unsigned u; } v; v.f = f;
  unsigned r = (v.u + 0x7fff + ((v.u >> 16) & 1)) >> 16;   // round-nearest-even
  return (unsigned short)r;
}
__device__ __forceinline__ float bfhi(unsigned u) {
  union { unsigned u; float f; } v; v.u = u & 0xffff0000u; return v.f;
}
__device__ __forceinline__ float bflo(unsigned u) {
  union { unsigned u; float f; } v; v.u = u << 16; return v.f;
}
__device__ __forceinline__ unsigned char f2fp8(float f) {
  return (unsigned char)(__builtin_amdgcn_cvt_pk_fp8_f32(f, f, 0, false) & 0xff);
}

// ---- per-graph node counts (LDS histogram) ----
__global__ __launch_bounds__(256) void k_gcnt(const int* __restrict__ gid, int* __restrict__ gcnt,
                                              int N, int G) {
  __shared__ int h[64];
  if (threadIdx.x < 64) h[threadIdx.x] = 0;
  __syncthreads();
  int stride = gridDim.x * blockDim.x;
  for (int i = blockIdx.x * blockDim.x + threadIdx.x; i < N; i += stride)
    atomicAdd(&h[gid[i]], 1);
  __syncthreads();
  if (threadIdx.x < (unsigned)G) {
    int v = h[threadIdx.x];
    if (v) atomicAdd(&gcnt[threadIdx.x], v);
  }
}

// ---- pass 1a: per-block 256-bin LDS histograms of dst>>9 and src>>9 ----
__global__ __launch_bounds__(256) void k_part1a(const int* __restrict__ src, const int* __restrict__ dst,
                                                unsigned* __restrict__ histD, unsigned* __restrict__ histS,
                                                int E) {
  __shared__ unsigned hD[256], hS[256];
  hD[threadIdx.x] = 0; hS[threadIdx.x] = 0;
  __syncthreads();
  int chunk = (E + gridDim.x - 1) / gridDim.x;
  int e0 = blockIdx.x * chunk, e1 = min(E, e0 + chunk);
  for (int e = e0 + threadIdx.x; e < e1; e += 256) {
    atomicAdd(&hD[(unsigned)dst[e] >> 9], 1u);
    atomicAdd(&hS[(unsigned)src[e] >> 9], 1u);
  }
  __syncthreads();
  histD[blockIdx.x * 256 + threadIdx.x] = hD[threadIdx.x];
  histS[blockIdx.x * 256 + threadIdx.x] = hS[threadIdx.x];
}

// ---- pscanA: per (table,bucket) — scan the PB per-block counts ----
__global__ __launch_bounds__(256) void k_pscanA(unsigned* __restrict__ histD, unsigned* __restrict__ histS,
                                                unsigned* __restrict__ tot) {
  __shared__ unsigned excl[PB], psc[256];
  int table = blockIdx.x >> 8, b = blockIdx.x & 255;
  unsigned* hist = table ? histS : histD;
  int t = threadIdx.x;
  unsigned s0 = hist[(2 * t) * 256 + b];
  unsigned s1 = hist[(2 * t + 1) * 256 + b];
  unsigned pr = s0 + s1;
  psc[t] = pr;
  __syncthreads();
  for (int off = 1; off < 256; off <<= 1) {
    unsigned x = (t >= off) ? psc[t - off] : 0;
    __syncthreads();
    psc[t] += x;
    __syncthreads();
  }
  unsigned pex = psc[t] - pr;
  excl[2 * t] = pex;
  excl[2 * t + 1] = pex + s0;
  __syncthreads();
  hist[(2 * t) * 256 + b] = excl[2 * t];
  hist[(2 * t + 1) * 256 + b] = excl[2 * t + 1];
  if (t == 255) tot[table * 256 + b] = psc[255];
}

// ---- pscanB: one block — scan bucket totals for both tables ----
__global__ __launch_bounds__(256) void k_pscanB(const unsigned* __restrict__ tot,
                                                int* __restrict__ bsD, int* __restrict__ bsS) {
  __shared__ unsigned s[256];
  int t = threadIdx.x;
#pragma unroll
  for (int table = 0; table < 2; ++table) {
    int* bs = table ? bsS : bsD;
    unsigned v = tot[table * 256 + t];
    s[t] = v;
    __syncthreads();
    for (int off = 1; off < 256; off <<= 1) {
      unsigned x = (t >= off) ? s[t - off] : 0;
      __syncthreads();
      s[t] += x;
      __syncthreads();
    }
    bs[t] = (int)(s[t] - v);
    if (t == 255) bs[256] = (int)s[255];
    __syncthreads();
  }
}

// ---- pscanC: add bucket base into per-(block,bucket) cursors ----
__global__ __launch_bounds__(256) void k_pscanC(unsigned* __restrict__ histD, unsigned* __restrict__ histS,
                                                const int* __restrict__ bsD, const int* __restrict__ bsS) {
  int table = blockIdx.x >> 9, i = blockIdx.x & (PB - 1);
  unsigned* hist = table ? histS : histD;
  const int* bs = table ? bsS : bsD;
  hist[i * 256 + threadIdx.x] += (unsigned)bs[threadIdx.x];
}

// ---- pass 1c: scatter packed edge records into both partitions ----
// pairD: (dst&511)<<17 | src ; pairS: (src&511)<<17 | dst   (N < 2^17)
__global__ __launch_bounds__(256) void k_part1c(const int* __restrict__ src, const int* __restrict__ dst,
                                                const unsigned* __restrict__ histD, const unsigned* __restrict__ histS,
                                                unsigned* __restrict__ pairD, unsigned* __restrict__ pairS, int E) {
  __shared__ unsigned cD[256], cS[256];
  cD[threadIdx.x] = histD[blockIdx.x * 256 + threadIdx.x];
  cS[threadIdx.x] = histS[blockIdx.x * 256 + threadIdx.x];
  __syncthreads();
  int chunk = (E + gridDim.x - 1) / gridDim.x;
  int e0 = blockIdx.x * chunk, e1 = min(E, e0 + chunk);
  for (int e = e0 + threadIdx.x; e < e1; e += 256) {
    unsigned sv = (unsigned)src[e], dv = (unsigned)dst[e];
    unsigned p = atomicAdd(&cD[dv >> 9], 1u);
    pairD[p] = ((dv & 511u) << 17) | sv;
    unsigned q = atomicAdd(&cS[sv >> 9], 1u);
    pairS[q] = ((sv & 511u) << 17) | dv;
  }
}

// ---- pass 2d: per dst-bucket — hist, scan, write offs/degI, place srcS ----
__global__ __launch_bounds__(256) void k_part2d(const unsigned* __restrict__ pairD, const int* __restrict__ bsD,
                                                int* __restrict__ offs, int* __restrict__ degI,
                                                int* __restrict__ srcS, int N) {
  __shared__ unsigned hist[512], excl[512], psc[256];
  int k = blockIdx.x, base = k << 9;
  int b0 = bsD[k], b1 = bsD[k + 1];
  hist[threadIdx.x] = 0; hist[threadIdx.x + 256] = 0;
  __syncthreads();
  for (int i = b0 + threadIdx.x; i < b1; i += 256)
    atomicAdd(&hist[pairD[i] >> 17], 1u);
  __syncthreads();
  unsigned s0 = hist[2 * threadIdx.x], s1 = hist[2 * threadIdx.x + 1];
  unsigned pr = s0 + s1;
  psc[threadIdx.x] = pr;
  __syncthreads();
  for (int off = 1; off < 256; off <<= 1) {
    unsigned x = (threadIdx.x >= off) ? psc[threadIdx.x - off] : 0;
    __syncthreads();
    psc[threadIdx.x] += x;
    __syncthreads();
  }
  unsigned pex = psc[threadIdx.x] - pr;
  excl[2 * threadIdx.x] = pex;
  excl[2 * threadIdx.x + 1] = pex + s0;
  __syncthreads();
  for (int j = threadIdx.x; j < 512; j += 256) {
    int node = base + j;
    if (node <= N) offs[node] = b0 + (int)excl[j];
    if (node < N) degI[node] = (int)hist[j];
  }
  __syncthreads();
  for (int i = b0 + threadIdx.x; i < b1; i += 256) {
    unsigned pk = pairD[i];
    unsigned pos = atomicAdd(&excl[pk >> 17], 1u);
    srcS[b0 + (int)pos] = (int)(pk & 0x1FFFFu);
  }
}

// ---- pass 2s (lite): per src-bucket — hist only -> nsrc ----
__global__ __launch_bounds__(256) void k_part2s(const unsigned* __restrict__ pairS, const int* __restrict__ bsS,
                                                float* __restrict__ nsrc, int N) {
  __shared__ unsigned hist[512];
  int k = blockIdx.x, base = k << 9;
  int b0 = bsS[k], b1 = bsS[k + 1];
  hist[threadIdx.x] = 0; hist[threadIdx.x + 256] = 0;
  __syncthreads();
  for (int i = b0 + threadIdx.x; i < b1; i += 256)
    atomicAdd(&hist[pairS[i] >> 17], 1u);
  __syncthreads();
  for (int j = threadIdx.x; j < 512; j += 256) {
    int node = base + j;
    if (node < N) {
      float g = (float)hist[j]; g = g > 0.f ? g : 1.f;
      nsrc[node] = rsqrtf(g);
    }
  }
}

// ---- norms for dst side + packed (poolw, gid) ----
__global__ __launch_bounds__(256) void k_norm(const int* __restrict__ degI, const int* __restrict__ gcnt,
                                              const int* __restrict__ gid,
                                              float* __restrict__ ndst, uint2* __restrict__ pwg, int N) {
  int i = blockIdx.x * blockDim.x + threadIdx.x;
  if (i >= N) return;
  float gi = (float)degI[i]; gi = gi > 0.f ? gi : 1.f;
  float nd = rsqrtf(gi);
  ndst[i] = nd;
  float c = (float)gcnt[gid[i]]; c = c > 1.f ? c : 1.f;
  float w = nd / c;
  union { float f; unsigned u; } v; v.f = w;
  pwg[i] = make_uint2(v.u, (unsigned)gid[i]);
}

// ---- wprep: Wt[n][k] = bf16(W1[k][n]) ----
__global__ __launch_bounds__(128) void k_wprep(const float* __restrict__ W, unsigned short* __restrict__ Wt) {
  int n = blockIdx.x, k = threadIdx.x;
  Wt[n * 128 + k] = f2bf(W[k * 128 + n]);
}

// ---- GEMM1 (MFMA): Z8 = fp8( (X @ W1) * nsrc[row] ), LDS-free ----
__global__ __launch_bounds__(256) void k_gemm1(const float* __restrict__ X, const unsigned short* __restrict__ Wt,
                                               const float* __restrict__ nsrc,
                                               unsigned char* __restrict__ Z8, int N) {
  int wave = threadIdx.x >> 6, lane = threadIdx.x & 63;
  int quad = lane >> 4, l16 = lane & 15;
  int row0 = blockIdx.x * 64 + wave * 16;
  int arow = row0 + l16; if (arow >= N) arow = N - 1;
  const float* xr = X + (size_t)arow * 128 + quad * 8;
  f32x4 acc[8];
#pragma unroll
  for (int i = 0; i < 8; ++i) acc[i] = (f32x4){0.f, 0.f, 0.f, 0.f};
#pragma unroll
  for (int kb = 0; kb < 128; kb += 32) {
    float4 x0 = *(const float4*)(xr + kb);
    float4 x1 = *(const float4*)(xr + kb + 4);
    bf16x8 a;
    a[0] = (short)f2bf(x0.x); a[1] = (short)f2bf(x0.y);
    a[2] = (short)f2bf(x0.z); a[3] = (short)f2bf(x0.w);
    a[4] = (short)f2bf(x1.x); a[5] = (short)f2bf(x1.y);
    a[6] = (short)f2bf(x1.z); a[7] = (short)f2bf(x1.w);
#pragma unroll
    for (int nt = 0; nt < 8; ++nt) {
      bf16x8 b = *(const bf16x8*)(Wt + (size_t)(nt * 16 + l16) * 128 + kb + quad * 8);
      acc[nt] = __builtin_amdgcn_mfma_f32_16x16x32_bf16(a, b, acc[nt], 0, 0, 0);
    }
  }
  int rbase = row0 + quad * 4;
#pragma unroll
  for (int r = 0; r < 4; ++r) {
    int row = rbase + r;
    if (row < N) {
      float s = nsrc[row];
#pragma unroll
      for (int nt = 0; nt < 8; ++nt)
        Z8[(size_t)row * 128 + nt * 16 + l16] = f2fp8(acc[nt][r] * s);
    }
  }
}

// ---- layer1: per-dst gather-reduce (fp8 rows, half-wave pairs) + fused post-op ----
// lane half handles edge e+half; lanes l32 cover 4 features via one dword (4 fp8).
__global__ __launch_bounds__(256) void k_layer1(const unsigned char* __restrict__ Z8,
                                                const int* __restrict__ offs, const int* __restrict__ srcS,
                                                const float* __restrict__ b1,
                                                const float* __restrict__ nsrc, const float* __restrict__ ndst,
                                                unsigned short* __restrict__ Hb, int N) {
  int lane = threadIdx.x & 63;
  int half = lane >> 5, l32 = lane & 31;
  int d = blockIdx.x * 4 + (threadIdx.x >> 6);
  if (d >= N) return;
  int start = offs[d], end = offs[d + 1];
  float a0 = 0.f, a1 = 0.f, a2 = 0.f, a3 = 0.f;
  int e = start;
  for (; e + 8 <= end; e += 8) {
    int s0 = srcS[e + half], s1 = srcS[e + 2 + half];
    int s2 = srcS[e + 4 + half], s3 = srcS[e + 6 + half];
    unsigned u0 = *(const unsigned*)(Z8 + (size_t)s0 * 128 + l32 * 4);
    unsigned u1 = *(const unsigned*)(Z8 + (size_t)s1 * 128 + l32 * 4);
    unsigned u2 = *(const unsigned*)(Z8 + (size_t)s2 * 128 + l32 * 4);
    unsigned u3 = *(const unsigned*)(Z8 + (size_t)s3 * 128 + l32 * 4);
    f32x2 p0 = __builtin_amdgcn_cvt_pk_f32_fp8(u0, false), q0 = __builtin_amdgcn_cvt_pk_f32_fp8(u0, true);
    f32x2 p1 = __builtin_amdgcn_cvt_pk_f32_fp8(u1, false), q1 = __builtin_amdgcn_cvt_pk_f32_fp8(u1, true);
    f32x2 p2 = __builtin_amdgcn_cvt_pk_f32_fp8(u2, false), q2 = __builtin_amdgcn_cvt_pk_f32_fp8(u2, true);
    f32x2 p3 = __builtin_amdgcn_cvt_pk_f32_fp8(u3, false), q3 = __builtin_amdgcn_cvt_pk_f32_fp8(u3, true);
    a0 += (p0[0] + p1[0]) + (p2[0] + p3[0]);
    a1 += (p0[1] + p1[1]) + (p2[1] + p3[1]);
    a2 += (q0[0] + q1[0]) + (q2[0] + q3[0]);
    a3 += (q0[1] + q1[1]) + (q2[1] + q3[1]);
  }
  for (; e + 2 <= end; e += 2) {
    int s = srcS[e + half];
    unsigned u = *(const unsigned*)(Z8 + (size_t)s * 128 + l32 * 4);
    f32x2 p = __builtin_amdgcn_cvt_pk_f32_fp8(u, false), q = __builtin_amdgcn_cvt_pk_f32_fp8(u, true);
    a0 += p[0]; a1 += p[1]; a2 += q[0]; a3 += q[1];
  }
  if (e < end && half == 0) {
    int s = srcS[e];
    unsigned u = *(const unsigned*)(Z8 + (size_t)s * 128 + l32 * 4);
    f32x2 p = __builtin_amdgcn_cvt_pk_f32_fp8(u, false), q = __builtin_amdgcn_cvt_pk_f32_fp8(u, true);
    a0 += p[0]; a1 += p[1]; a2 += q[0]; a3 += q[1];
  }
  a0 += __shfl_xor(a0, 32, 64);
  a1 += __shfl_xor(a1, 32, 64);
  a2 += __shfl_xor(a2, 32, 64);
  a3 += __shfl_xor(a3, 32, 64);
  if (half == 0) {
    float nd = ndst[d], ns = nsrc[d];
    int f = l32 * 4;
    float h0 = fmaxf(fmaf(nd, a0, b1[f + 0]), 0.f) * ns;
    float h1 = fmaxf(fmaf(nd, a1, b1[f + 1]), 0.f) * ns;
    float h2 = fmaxf(fmaf(nd, a2, b1[f + 2]), 0.f) * ns;
    float h3 = fmaxf(fmaf(nd, a3, b1[f + 3]), 0.f) * ns;
    ushort4 o; o.x = f2bf(h0); o.y = f2bf(h1); o.z = f2bf(h2); o.w = f2bf(h3);
    *(ushort4*)(Hb + (size_t)d * 128 + f) = o;
  }
}

// ---- k_pw: per src-bucket — 128 KB LDS P-tile accumulated from packed pairS ----
__global__ __launch_bounds__(256) void k_pw(const unsigned* __restrict__ pairS, const int* __restrict__ bsS,
                                            const uint2* __restrict__ pwg, float* __restrict__ P, int N) {
  __shared__ float tile[512 * 64];   // 128 KB -> 1 block/CU
  int k = blockIdx.x, base = k << 9;
  int b0 = bsS[k], b1 = bsS[k + 1];
  for (int i = threadIdx.x; i < 512 * 64; i += 256) tile[i] = 0.f;
  __syncthreads();
  for (int i = b0 + threadIdx.x; i < b1; i += 256) {
    unsigned pk = pairS[i];
    unsigned dv = pk & 0x1FFFFu;
    unsigned sloc = pk >> 17;
    uint2 u = pwg[dv];
    union { unsigned u; float f; } w; w.u = u.x;
    atomicAdd(&tile[sloc * 64 + u.y], w.f);
  }
  __syncthreads();
  for (int i = threadIdx.x; i < 512 * 64; i += 256) {
    int node = base + (i >> 6);
    if (node < N) P[(size_t)node * 64 + (i & 63)] = tile[i];
  }
}

// ---- k_poolgemm: part[b] = P[rows]^T · H[rows]  (streaming split-K GEMM) ----
__global__ __launch_bounds__(256) void k_poolgemm(const float* __restrict__ P,
                                                  const unsigned short* __restrict__ Hb,
                                                  float* __restrict__ part, int N) {
  __shared__ float Pl[KC * 64];    // 8 KB
  __shared__ float Hl[KC * 128];   // 16 KB
  int t = threadIdx.x;
  int chunk = (N + gridDim.x - 1) / gridDim.x;
  int r0 = blockIdx.x * chunk, r1 = min(N, r0 + chunk);
  float acc[4][8] = {};
  int gq = (t & 15) * 4, fo = (t >> 4) * 8;
  for (int rb = r0; rb < r1; rb += KC) {
    {
      int idx = t * 8;
      int r = idx >> 6, c = idx & 63;
      int row = rb + r;
      float4 z = make_float4(0.f, 0.f, 0.f, 0.f);
      float4 v0 = z, v1 = z;
      if (row < r1) {
        v0 = *(const float4*)(P + (size_t)row * 64 + c);
        v1 = *(const float4*)(P + (size_t)row * 64 + c + 4);
      }
      *(float4*)(Pl + idx) = v0;
      *(float4*)(Pl + idx + 4) = v1;
    }
    {
      int idx = t * 16;
      int r = idx >> 7, c = idx & 127;
      int row = rb + r;
      if (row < r1) {
        uint4 ua = *(const uint4*)(Hb + (size_t)row * 128 + c);
        uint4 ub = *(const uint4*)(Hb + (size_t)row * 128 + c + 8);
        *(float4*)(Hl + idx)      = make_float4(bflo(ua.x), bfhi(ua.x), bflo(ua.y), bfhi(ua.y));
        *(float4*)(Hl + idx + 4)  = make_float4(bflo(ua.z), bfhi(ua.z), bflo(ua.w), bfhi(ua.w));
        *(float4*)(Hl + idx + 8)  = make_float4(bflo(ub.x), bfhi(ub.x), bflo(ub.y), bfhi(ub.y));
        *(float4*)(Hl + idx + 12) = make_float4(bflo(ub.z), bfhi(ub.z), bflo(ub.w), bfhi(ub.w));
      } else {
        float4 z = make_float4(0.f, 0.f, 0.f, 0.f);
        *(float4*)(Hl + idx) = z; *(float4*)(Hl + idx + 4) = z;
        *(float4*)(Hl + idx + 8) = z; *(float4*)(Hl + idx + 12) = z;
      }
    }
    __syncthreads();
#pragma unroll 4
    for (int r = 0; r < KC; ++r) {
      float4 pv = *(const float4*)(Pl + r * 64 + gq);
      float4 h0 = *(const float4*)(Hl + r * 128 + fo);
      float4 h1 = *(const float4*)(Hl + r * 128 + fo + 4);
      const float* pf = (const float*)&pv;
      const float* hf0 = (const float*)&h0;
      const float* hf1 = (const float*)&h1;
#pragma unroll
      for (int gg = 0; gg < 4; ++gg) {
#pragma unroll
        for (int ff = 0; ff < 4; ++ff) {
          acc[gg][ff]     = fmaf(pf[gg], hf0[ff], acc[gg][ff]);
          acc[gg][ff + 4] = fmaf(pf[gg], hf1[ff], acc[gg][ff + 4]);
        }
      }
    }
    __syncthreads();
  }
  float* base = part + (size_t)blockIdx.x * 64 * DD;
#pragma unroll
  for (int gg = 0; gg < 4; ++gg) {
    *(float4*)(base + (gq + gg) * DD + fo)     = make_float4(acc[gg][0], acc[gg][1], acc[gg][2], acc[gg][3]);
    *(float4*)(base + (gq + gg) * DD + fo + 4) = make_float4(acc[gg][4], acc[gg][5], acc[gg][6], acc[gg][7]);
  }
}

// ---- out: fold split-K partials, then @W2 + b2 ----
__global__ __launch_bounds__(128) void k_out(const float* __restrict__ part, const float* __restrict__ W2,
                                             const float* __restrict__ b2, float* __restrict__ out) {
  __shared__ float p[DD];
  int g = blockIdx.x, d = threadIdx.x;
  float s = 0.f;
#pragma unroll 4
  for (int k = 0; k < GB; ++k) s += part[(size_t)k * 64 * DD + g * DD + d];
  p[d] = s;
  __syncthreads();
  float a = b2[d];
#pragma unroll 4
  for (int k = 0; k < DD; ++k) a = fmaf(p[k], W2[k * DD + d], a);
  out[g * DD + d] = a;
}

extern "C" void kernel_launch(void* const* d_in, const int* in_sizes, int n_in,
                              void* d_out, int out_size, void* d_ws, size_t ws_size,
                              hipStream_t stream) {
  const float* X  = (const float*)d_in[0];
  const float* W1 = (const float*)d_in[1];
  const float* b1 = (const float*)d_in[2];
  const float* W2 = (const float*)d_in[3];
  const float* b2 = (const float*)d_in[4];
  const int* src  = (const int*)d_in[5];
  const int* dst  = (const int*)d_in[6];
  const int* gid  = (const int*)d_in[7];
  int E = in_sizes[5];
  int N = in_sizes[7];
  int G = out_size / DD;   // 64
  int nb = (N >> 9) + 1;   // node buckets

  char* w = (char*)d_ws;
  size_t o = 0;
  auto carve = [&](size_t bytes) { char* p = w + o; o += (bytes + 255) & ~(size_t)255; return p; };
  // zero-init region
  int*   gcnt   = (int*)  carve((size_t)G * 4);
  size_t zeroBytes = o;
  // rest (fully written before read)
  unsigned* histD = (unsigned*)carve((size_t)PB * 256 * 4);
  unsigned* histS = (unsigned*)carve((size_t)PB * 256 * 4);
  unsigned* tot   = (unsigned*)carve(512 * 4);
  int*   bsD    = (int*)  carve(257 * 4);
  int*   bsS    = (int*)  carve(257 * 4);
  unsigned* pairD = (unsigned*)carve((size_t)E * 4);
  unsigned* pairS = (unsigned*)carve((size_t)E * 4);
  int*   srcS   = (int*)  carve((size_t)E * 4);
  int*   offs   = (int*)  carve((size_t)(N + 1) * 4);
  int*   degI   = (int*)  carve((size_t)N * 4);
  float* nsrc   = (float*)carve((size_t)N * 4);
  float* ndst   = (float*)carve((size_t)N * 4);
  uint2* pwg    = (uint2*)carve((size_t)N * 8);
  unsigned short* Wt = (unsigned short*)carve(128 * 128 * 2);
  unsigned char*  Z8 = (unsigned char*)carve((size_t)N * DD);      // fp8; aliased as part later
  unsigned short* Hb = (unsigned short*)carve((size_t)N * DD * 2);
  float* P      = (float*)carve((size_t)N * 64 * 4);
  float* part   = (float*)Z8;    // 8.4 MB needed < 12.8 MB Z8 (dead after layer1)

  hipMemsetAsync(d_ws, 0, zeroBytes, stream);

  k_gcnt<<<256, 256, 0, stream>>>(gid, gcnt, N, G);
  k_part1a<<<PB, 256, 0, stream>>>(src, dst, histD, histS, E);
  k_pscanA<<<512, 256, 0, stream>>>(histD, histS, tot);
  k_pscanB<<<1, 256, 0, stream>>>(tot, bsD, bsS);
  k_pscanC<<<2 * PB, 256, 0, stream>>>(histD, histS, bsD, bsS);
  k_part1c<<<PB, 256, 0, stream>>>(src, dst, histD, histS, pairD, pairS, E);
  k_part2d<<<nb, 256, 0, stream>>>(pairD, bsD, offs, degI, srcS, N);
  k_part2s<<<nb, 256, 0, stream>>>(pairS, bsS, nsrc, N);
  k_norm<<<(N + 255) / 256, 256, 0, stream>>>(degI, gcnt, gid, ndst, pwg, N);
  k_wprep<<<128, 128, 0, stream>>>(W1, Wt);
  k_gemm1<<<(N + 63) / 64, 256, 0, stream>>>(X, Wt, nsrc, Z8, N);
  k_layer1<<<(N + 3) / 4, 256, 0, stream>>>(Z8, offs, srcS, b1, nsrc, ndst, Hb, N);
  k_pw<<<nb, 256, 0, stream>>>(pairS, bsS, pwg, P, N);
  k_poolgemm<<<GB, 256, 0, stream>>>(P, Hb, part, N);
  k_out<<<G, DD, 0, stream>>>(part, W2, b2, (float*)d_out);
}

// Round 10
// 369.581 us; speedup vs baseline: 1.7690x; 1.0067x over previous
//
#include <hip/hip_runtime.h>
#include <cstdint>

// GCN via radix partition (bucket = node>>9), packed u32 edge records.
// Z table fp8-e4m3 (12.8 MB); layer1 = quarter-wave gather (16 lanes x 8B/row).
// pooled = P^T H (P built per-src-bucket in 128 KB LDS tiles, 1024 thr); out = pooled@W2+b2.

#define DD 128
#define PB 512   // partition pass-1 blocks
#define GB 384   // poolgemm split-K blocks (part aliased onto pairD+pairS: 384*32KB <= 12.8MB)
#define KC 32    // poolgemm K-chunk

typedef __attribute__((ext_vector_type(8))) short bf16x8;
typedef __attribute__((ext_vector_type(4))) float f32x4;
typedef __attribute__((ext_vector_type(2))) float f32x2;

__device__ __forceinline__ unsigned short f2bf(float f) {
  union { float f; unsigned u; } v; v.f = f;
  unsigned r = (v.u + 0x7fff + ((v.u >> 16) & 1)) >> 16;   // round-nearest-even
  return (unsigned short)r;
}
__device__ __forceinline__ float bfhi(unsigned u) {
  union { unsigned u; float f; } v; v.u = u & 0xffff0000u; return v.f;
}
__device__ __forceinline__ float bflo(unsigned u) {
  union { unsigned u; float f; } v; v.u = u << 16; return v.f;
}
__device__ __forceinline__ unsigned char f2fp8(float f) {
  return (unsigned char)(__builtin_amdgcn_cvt_pk_fp8_f32(f, f, 0, false) & 0xff);
}

// ---- per-graph node counts (LDS histogram) ----
__global__ __launch_bounds__(256) void k_gcnt(const int* __restrict__ gid, int* __restrict__ gcnt,
                                              int N, int G) {
  __shared__ int h[64];
  if (threadIdx.x < 64) h[threadIdx.x] = 0;
  __syncthreads();
  int stride = gridDim.x * blockDim.x;
  for (int i = blockIdx.x * blockDim.x + threadIdx.x; i < N; i += stride)
    atomicAdd(&h[gid[i]], 1);
  __syncthreads();
  if (threadIdx.x < (unsigned)G) {
    int v = h[threadIdx.x];
    if (v) atomicAdd(&gcnt[threadIdx.x], v);
  }
}

// ---- pass 1a: per-block 256-bin LDS histograms of dst>>9 and src>>9 ----
__global__ __launch_bounds__(256) void k_part1a(const int* __restrict__ src, const int* __restrict__ dst,
                                                unsigned* __restrict__ histD, unsigned* __restrict__ histS,
                                                int E) {
  __shared__ unsigned hD[256], hS[256];
  hD[threadIdx.x] = 0; hS[threadIdx.x] = 0;
  __syncthreads();
  int chunk = (E + gridDim.x - 1) / gridDim.x;
  int e0 = blockIdx.x * chunk, e1 = min(E, e0 + chunk);
  for (int e = e0 + threadIdx.x; e < e1; e += 256) {
    atomicAdd(&hD[(unsigned)dst[e] >> 9], 1u);
    atomicAdd(&hS[(unsigned)src[e] >> 9], 1u);
  }
  __syncthreads();
  histD[blockIdx.x * 256 + threadIdx.x] = hD[threadIdx.x];
  histS[blockIdx.x * 256 + threadIdx.x] = hS[threadIdx.x];
}

// ---- pscanA: per (table,bucket) — scan the PB per-block counts ----
__global__ __launch_bounds__(256) void k_pscanA(unsigned* __restrict__ histD, unsigned* __restrict__ histS,
                                                unsigned* __restrict__ tot) {
  __shared__ unsigned excl[PB], psc[256];
  int table = blockIdx.x >> 8, b = blockIdx.x & 255;
  unsigned* hist = table ? histS : histD;
  int t = threadIdx.x;
  unsigned s0 = hist[(2 * t) * 256 + b];
  unsigned s1 = hist[(2 * t + 1) * 256 + b];
  unsigned pr = s0 + s1;
  psc[t] = pr;
  __syncthreads();
  for (int off = 1; off < 256; off <<= 1) {
    unsigned x = (t >= off) ? psc[t - off] : 0;
    __syncthreads();
    psc[t] += x;
    __syncthreads();
  }
  unsigned pex = psc[t] - pr;
  excl[2 * t] = pex;
  excl[2 * t + 1] = pex + s0;
  __syncthreads();
  hist[(2 * t) * 256 + b] = excl[2 * t];
  hist[(2 * t + 1) * 256 + b] = excl[2 * t + 1];
  if (t == 255) tot[table * 256 + b] = psc[255];
}

// ---- pscanB: one block — scan bucket totals for both tables ----
__global__ __launch_bounds__(256) void k_pscanB(const unsigned* __restrict__ tot,
                                                int* __restrict__ bsD, int* __restrict__ bsS) {
  __shared__ unsigned s[256];
  int t = threadIdx.x;
#pragma unroll
  for (int table = 0; table < 2; ++table) {
    int* bs = table ? bsS : bsD;
    unsigned v = tot[table * 256 + t];
    s[t] = v;
    __syncthreads();
    for (int off = 1; off < 256; off <<= 1) {
      unsigned x = (t >= off) ? s[t - off] : 0;
      __syncthreads();
      s[t] += x;
      __syncthreads();
    }
    bs[t] = (int)(s[t] - v);
    if (t == 255) bs[256] = (int)s[255];
    __syncthreads();
  }
}

// ---- pscanC: add bucket base into per-(block,bucket) cursors ----
__global__ __launch_bounds__(256) void k_pscanC(unsigned* __restrict__ histD, unsigned* __restrict__ histS,
                                                const int* __restrict__ bsD, const int* __restrict__ bsS) {
  int table = blockIdx.x >> 9, i = blockIdx.x & (PB - 1);
  unsigned* hist = table ? histS : histD;
  const int* bs = table ? bsS : bsD;
  hist[i * 256 + threadIdx.x] += (unsigned)bs[threadIdx.x];
}

// ---- pass 1c: scatter packed edge records into both partitions ----
// pairD: (dst&511)<<17 | src ; pairS: (src&511)<<17 | dst   (N < 2^17)
__global__ __launch_bounds__(256) void k_part1c(const int* __restrict__ src, const int* __restrict__ dst,
                                                const unsigned* __restrict__ histD, const unsigned* __restrict__ histS,
                                                unsigned* __restrict__ pairD, unsigned* __restrict__ pairS, int E) {
  __shared__ unsigned cD[256], cS[256];
  cD[threadIdx.x] = histD[blockIdx.x * 256 + threadIdx.x];
  cS[threadIdx.x] = histS[blockIdx.x * 256 + threadIdx.x];
  __syncthreads();
  int chunk = (E + gridDim.x - 1) / gridDim.x;
  int e0 = blockIdx.x * chunk, e1 = min(E, e0 + chunk);
  for (int e = e0 + threadIdx.x; e < e1; e += 256) {
    unsigned sv = (unsigned)src[e], dv = (unsigned)dst[e];
    unsigned p = atomicAdd(&cD[dv >> 9], 1u);
    pairD[p] = ((dv & 511u) << 17) | sv;
    unsigned q = atomicAdd(&cS[sv >> 9], 1u);
    pairS[q] = ((sv & 511u) << 17) | dv;
  }
}

// ---- pass 2d: per dst-bucket — hist, scan, write offs/degI, place srcS ----
__global__ __launch_bounds__(256) void k_part2d(const unsigned* __restrict__ pairD, const int* __restrict__ bsD,
                                                int* __restrict__ offs, int* __restrict__ degI,
                                                int* __restrict__ srcS, int N) {
  __shared__ unsigned hist[512], excl[512], psc[256];
  int k = blockIdx.x, base = k << 9;
  int b0 = bsD[k], b1 = bsD[k + 1];
  hist[threadIdx.x] = 0; hist[threadIdx.x + 256] = 0;
  __syncthreads();
  for (int i = b0 + threadIdx.x; i < b1; i += 256)
    atomicAdd(&hist[pairD[i] >> 17], 1u);
  __syncthreads();
  unsigned s0 = hist[2 * threadIdx.x], s1 = hist[2 * threadIdx.x + 1];
  unsigned pr = s0 + s1;
  psc[threadIdx.x] = pr;
  __syncthreads();
  for (int off = 1; off < 256; off <<= 1) {
    unsigned x = (threadIdx.x >= off) ? psc[threadIdx.x - off] : 0;
    __syncthreads();
    psc[threadIdx.x] += x;
    __syncthreads();
  }
  unsigned pex = psc[threadIdx.x] - pr;
  excl[2 * threadIdx.x] = pex;
  excl[2 * threadIdx.x + 1] = pex + s0;
  __syncthreads();
  for (int j = threadIdx.x; j < 512; j += 256) {
    int node = base + j;
    if (node <= N) offs[node] = b0 + (int)excl[j];
    if (node < N) degI[node] = (int)hist[j];
  }
  __syncthreads();
  for (int i = b0 + threadIdx.x; i < b1; i += 256) {
    unsigned pk = pairD[i];
    unsigned pos = atomicAdd(&excl[pk >> 17], 1u);
    srcS[b0 + (int)pos] = (int)(pk & 0x1FFFFu);
  }
}

// ---- pass 2s (lite): per src-bucket — hist only -> nsrc ----
__global__ __launch_bounds__(256) void k_part2s(const unsigned* __restrict__ pairS, const int* __restrict__ bsS,
                                                float* __restrict__ nsrc, int N) {
  __shared__ unsigned hist[512];
  int k = blockIdx.x, base = k << 9;
  int b0 = bsS[k], b1 = bsS[k + 1];
  hist[threadIdx.x] = 0; hist[threadIdx.x + 256] = 0;
  __syncthreads();
  for (int i = b0 + threadIdx.x; i < b1; i += 256)
    atomicAdd(&hist[pairS[i] >> 17], 1u);
  __syncthreads();
  for (int j = threadIdx.x; j < 512; j += 256) {
    int node = base + j;
    if (node < N) {
      float g = (float)hist[j]; g = g > 0.f ? g : 1.f;
      nsrc[node] = rsqrtf(g);
    }
  }
}

// ---- norms for dst side + packed (poolw, gid) ----
__global__ __launch_bounds__(256) void k_norm(const int* __restrict__ degI, const int* __restrict__ gcnt,
                                              const int* __restrict__ gid,
                                              float* __restrict__ ndst, uint2* __restrict__ pwg, int N) {
  int i = blockIdx.x * blockDim.x + threadIdx.x;
  if (i >= N) return;
  float gi = (float)degI[i]; gi = gi > 0.f ? gi : 1.f;
  float nd = rsqrtf(gi);
  ndst[i] = nd;
  float c = (float)gcnt[gid[i]]; c = c > 1.f ? c : 1.f;
  float w = nd / c;
  union { float f; unsigned u; } v; v.f = w;
  pwg[i] = make_uint2(v.u, (unsigned)gid[i]);
}

// ---- wprep: Wt[n][k] = bf16(W1[k][n]) ----
__global__ __launch_bounds__(128) void k_wprep(const float* __restrict__ W, unsigned short* __restrict__ Wt) {
  int n = blockIdx.x, k = threadIdx.x;
  Wt[n * 128 + k] = f2bf(W[k * 128 + n]);
}

// ---- GEMM1 (MFMA): Z8 = fp8( (X @ W1) * nsrc[row] ), LDS-free ----
__global__ __launch_bounds__(256) void k_gemm1(const float* __restrict__ X, const unsigned short* __restrict__ Wt,
                                               const float* __restrict__ nsrc,
                                               unsigned char* __restrict__ Z8, int N) {
  int wave = threadIdx.x >> 6, lane = threadIdx.x & 63;
  int quad = lane >> 4, l16 = lane & 15;
  int row0 = blockIdx.x * 64 + wave * 16;
  int arow = row0 + l16; if (arow >= N) arow = N - 1;
  const float* xr = X + (size_t)arow * 128 + quad * 8;
  f32x4 acc[8];
#pragma unroll
  for (int i = 0; i < 8; ++i) acc[i] = (f32x4){0.f, 0.f, 0.f, 0.f};
#pragma unroll
  for (int kb = 0; kb < 128; kb += 32) {
    float4 x0 = *(const float4*)(xr + kb);
    float4 x1 = *(const float4*)(xr + kb + 4);
    bf16x8 a;
    a[0] = (short)f2bf(x0.x); a[1] = (short)f2bf(x0.y);
    a[2] = (short)f2bf(x0.z); a[3] = (short)f2bf(x0.w);
    a[4] = (short)f2bf(x1.x); a[5] = (short)f2bf(x1.y);
    a[6] = (short)f2bf(x1.z); a[7] = (short)f2bf(x1.w);
#pragma unroll
    for (int nt = 0; nt < 8; ++nt) {
      bf16x8 b = *(const bf16x8*)(Wt + (size_t)(nt * 16 + l16) * 128 + kb + quad * 8);
      acc[nt] = __builtin_amdgcn_mfma_f32_16x16x32_bf16(a, b, acc[nt], 0, 0, 0);
    }
  }
  int rbase = row0 + quad * 4;
#pragma unroll
  for (int r = 0; r < 4; ++r) {
    int row = rbase + r;
    if (row < N) {
      float s = nsrc[row];
#pragma unroll
      for (int nt = 0; nt < 8; ++nt)
        Z8[(size_t)row * 128 + nt * 16 + l16] = f2fp8(acc[nt][r] * s);
    }
  }
}

// ---- layer1: per-dst gather-reduce, quarter-wave (16 lanes x 8B) per fp8 row ----
// quarter q handles edges e+q / e+4+q; lane covers 8 features; 2-level shfl reduce.
__global__ __launch_bounds__(256) void k_layer1(const unsigned char* __restrict__ Z8,
                                                const int* __restrict__ offs, const int* __restrict__ srcS,
                                                const float* __restrict__ b1,
                                                const float* __restrict__ nsrc, const float* __restrict__ ndst,
                                                unsigned short* __restrict__ Hb, int N) {
  int lane = threadIdx.x & 63;
  int q = lane >> 4, l16 = lane & 15;
  int d = blockIdx.x * 4 + (threadIdx.x >> 6);
  if (d >= N) return;
  int start = offs[d], end = offs[d + 1];
  float a[8] = {0.f, 0.f, 0.f, 0.f, 0.f, 0.f, 0.f, 0.f};
  int e = start;
  for (; e + 8 <= end; e += 8) {
    int s0 = srcS[e + q], s1 = srcS[e + 4 + q];
    uint2 u0 = *(const uint2*)(Z8 + (size_t)s0 * 128 + l16 * 8);
    uint2 u1 = *(const uint2*)(Z8 + (size_t)s1 * 128 + l16 * 8);
    f32x2 p0 = __builtin_amdgcn_cvt_pk_f32_fp8(u0.x, false), p1 = __builtin_amdgcn_cvt_pk_f32_fp8(u0.x, true);
    f32x2 p2 = __builtin_amdgcn_cvt_pk_f32_fp8(u0.y, false), p3 = __builtin_amdgcn_cvt_pk_f32_fp8(u0.y, true);
    f32x2 r0 = __builtin_amdgcn_cvt_pk_f32_fp8(u1.x, false), r1 = __builtin_amdgcn_cvt_pk_f32_fp8(u1.x, true);
    f32x2 r2 = __builtin_amdgcn_cvt_pk_f32_fp8(u1.y, false), r3 = __builtin_amdgcn_cvt_pk_f32_fp8(u1.y, true);
    a[0] += p0[0] + r0[0]; a[1] += p0[1] + r0[1];
    a[2] += p1[0] + r1[0]; a[3] += p1[1] + r1[1];
    a[4] += p2[0] + r2[0]; a[5] += p2[1] + r2[1];
    a[6] += p3[0] + r3[0]; a[7] += p3[1] + r3[1];
  }
  for (; e + 4 <= end; e += 4) {
    int s = srcS[e + q];
    uint2 u = *(const uint2*)(Z8 + (size_t)s * 128 + l16 * 8);
    f32x2 p0 = __builtin_amdgcn_cvt_pk_f32_fp8(u.x, false), p1 = __builtin_amdgcn_cvt_pk_f32_fp8(u.x, true);
    f32x2 p2 = __builtin_amdgcn_cvt_pk_f32_fp8(u.y, false), p3 = __builtin_amdgcn_cvt_pk_f32_fp8(u.y, true);
    a[0] += p0[0]; a[1] += p0[1]; a[2] += p1[0]; a[3] += p1[1];
    a[4] += p2[0]; a[5] += p2[1]; a[6] += p3[0]; a[7] += p3[1];
  }
  if (e < end) {
    int idx = e + q;
    uint2 u = make_uint2(0u, 0u);
    if (idx < end) {
      int s = srcS[idx];
      u = *(const uint2*)(Z8 + (size_t)s * 128 + l16 * 8);
    }
    f32x2 p0 = __builtin_amdgcn_cvt_pk_f32_fp8(u.x, false), p1 = __builtin_amdgcn_cvt_pk_f32_fp8(u.x, true);
    f32x2 p2 = __builtin_amdgcn_cvt_pk_f32_fp8(u.y, false), p3 = __builtin_amdgcn_cvt_pk_f32_fp8(u.y, true);
    a[0] += p0[0]; a[1] += p0[1]; a[2] += p1[0]; a[3] += p1[1];
    a[4] += p2[0]; a[5] += p2[1]; a[6] += p3[0]; a[7] += p3[1];
  }
#pragma unroll
  for (int i = 0; i < 8; ++i) {
    a[i] += __shfl_xor(a[i], 16, 64);
    a[i] += __shfl_xor(a[i], 32, 64);
  }
  if (q == 0) {
    float nd = ndst[d], ns = nsrc[d];
    int f = l16 * 8;
    float4 bA = *(const float4*)(b1 + f);
    float4 bB = *(const float4*)(b1 + f + 4);
    float h0 = fmaxf(fmaf(nd, a[0], bA.x), 0.f) * ns;
    float h1 = fmaxf(fmaf(nd, a[1], bA.y), 0.f) * ns;
    float h2 = fmaxf(fmaf(nd, a[2], bA.z), 0.f) * ns;
    float h3 = fmaxf(fmaf(nd, a[3], bA.w), 0.f) * ns;
    float h4 = fmaxf(fmaf(nd, a[4], bB.x), 0.f) * ns;
    float h5 = fmaxf(fmaf(nd, a[5], bB.y), 0.f) * ns;
    float h6 = fmaxf(fmaf(nd, a[6], bB.z), 0.f) * ns;
    float h7 = fmaxf(fmaf(nd, a[7], bB.w), 0.f) * ns;
    uint4 o;
    o.x = (unsigned)f2bf(h0) | ((unsigned)f2bf(h1) << 16);
    o.y = (unsigned)f2bf(h2) | ((unsigned)f2bf(h3) << 16);
    o.z = (unsigned)f2bf(h4) | ((unsigned)f2bf(h5) << 16);
    o.w = (unsigned)f2bf(h6) | ((unsigned)f2bf(h7) << 16);
    *(uint4*)(Hb + (size_t)d * 128 + f) = o;
  }
}

// ---- k_pw: per src-bucket — 128 KB LDS P-tile, 1024 threads (16 waves) ----
__global__ __launch_bounds__(1024, 1) void k_pw(const unsigned* __restrict__ pairS, const int* __restrict__ bsS,
                                                const uint2* __restrict__ pwg, float* __restrict__ P, int N) {
  __shared__ float tile[512 * 64];   // 128 KB
  int k = blockIdx.x, base = k << 9;
  int b0 = bsS[k], b1 = bsS[k + 1];
  for (int i = threadIdx.x; i < 512 * 64; i += 1024) tile[i] = 0.f;
  __syncthreads();
  for (int i = b0 + threadIdx.x; i < b1; i += 1024) {
    unsigned pk = pairS[i];
    unsigned dv = pk & 0x1FFFFu;
    unsigned sloc = pk >> 17;
    uint2 u = pwg[dv];
    union { unsigned u; float f; } w; w.u = u.x;
    atomicAdd(&tile[sloc * 64 + u.y], w.f);
  }
  __syncthreads();
  for (int i = threadIdx.x; i < 512 * 64; i += 1024) {
    int node = base + (i >> 6);
    if (node < N) P[(size_t)node * 64 + (i & 63)] = tile[i];
  }
}

// ---- k_poolgemm: part[b] = P[rows]^T · H[rows]  (streaming split-K GEMM) ----
__global__ __launch_bounds__(256) void k_poolgemm(const float* __restrict__ P,
                                                  const unsigned short* __restrict__ Hb,
                                                  float* __restrict__ part, int N) {
  __shared__ float Pl[KC * 64];    // 8 KB
  __shared__ float Hl[KC * 128];   // 16 KB
  int t = threadIdx.x;
  int chunk = (N + gridDim.x - 1) / gridDim.x;
  int r0 = blockIdx.x * chunk, r1 = min(N, r0 + chunk);
  float acc[4][8] = {};
  int gq = (t & 15) * 4, fo = (t >> 4) * 8;
  for (int rb = r0; rb < r1; rb += KC) {
    {
      int idx = t * 8;
      int r = idx >> 6, c = idx & 63;
      int row = rb + r;
      float4 z = make_float4(0.f, 0.f, 0.f, 0.f);
      float4 v0 = z, v1 = z;
      if (row < r1) {
        v0 = *(const float4*)(P + (size_t)row * 64 + c);
        v1 = *(const float4*)(P + (size_t)row * 64 + c + 4);
      }
      *(float4*)(Pl + idx) = v0;
      *(float4*)(Pl + idx + 4) = v1;
    }
    {
      int idx = t * 16;
      int r = idx >> 7, c = idx & 127;
      int row = rb + r;
      if (row < r1) {
        uint4 ua = *(const uint4*)(Hb + (size_t)row * 128 + c);
        uint4 ub = *(const uint4*)(Hb + (size_t)row * 128 + c + 8);
        *(float4*)(Hl + idx)      = make_float4(bflo(ua.x), bfhi(ua.x), bflo(ua.y), bfhi(ua.y));
        *(float4*)(Hl + idx + 4)  = make_float4(bflo(ua.z), bfhi(ua.z), bflo(ua.w), bfhi(ua.w));
        *(float4*)(Hl + idx + 8)  = make_float4(bflo(ub.x), bfhi(ub.x), bflo(ub.y), bfhi(ub.y));
        *(float4*)(Hl + idx + 12) = make_float4(bflo(ub.z), bfhi(ub.z), bflo(ub.w), bfhi(ub.w));
      } else {
        float4 z = make_float4(0.f, 0.f, 0.f, 0.f);
        *(float4*)(Hl + idx) = z; *(float4*)(Hl + idx + 4) = z;
        *(float4*)(Hl + idx + 8) = z; *(float4*)(Hl + idx + 12) = z;
      }
    }
    __syncthreads();
#pragma unroll 4
    for (int r = 0; r < KC; ++r) {
      float4 pv = *(const float4*)(Pl + r * 64 + gq);
      float4 h0 = *(const float4*)(Hl + r * 128 + fo);
      float4 h1 = *(const float4*)(Hl + r * 128 + fo + 4);
      const float* pf = (const float*)&pv;
      const float* hf0 = (const float*)&h0;
      const float* hf1 = (const float*)&h1;
#pragma unroll
      for (int gg = 0; gg < 4; ++gg) {
#pragma unroll
        for (int ff = 0; ff < 4; ++ff) {
          acc[gg][ff]     = fmaf(pf[gg], hf0[ff], acc[gg][ff]);
          acc[gg][ff + 4] = fmaf(pf[gg], hf1[ff], acc[gg][ff + 4]);
        }
      }
    }
    __syncthreads();
  }
  float* base = part + (size_t)blockIdx.x * 64 * DD;
#pragma unroll
  for (int gg = 0; gg < 4; ++gg) {
    *(float4*)(base + (gq + gg) * DD + fo)     = make_float4(acc[gg][0], acc[gg][1], acc[gg][2], acc[gg][3]);
    *(float4*)(base + (gq + gg) * DD + fo + 4) = make_float4(acc[gg][4], acc[gg][5], acc[gg][6], acc[gg][7]);
  }
}

// ---- out: fold split-K partials, then @W2 + b2 ----
__global__ __launch_bounds__(128) void k_out(const float* __restrict__ part, const float* __restrict__ W2,
                                             const float* __restrict__ b2, float* __restrict__ out) {
  __shared__ float p[DD];
  int g = blockIdx.x, d = threadIdx.x;
  float s = 0.f;
#pragma unroll 4
  for (int k = 0; k < GB; ++k) s += part[(size_t)k * 64 * DD + g * DD + d];
  p[d] = s;
  __syncthreads();
  float a = b2[d];
#pragma unroll 4
  for (int k = 0; k < DD; ++k) a = fmaf(p[k], W2[k * DD + d], a);
  out[g * DD + d] = a;
}

extern "C" void kernel_launch(void* const* d_in, const int* in_sizes, int n_in,
                              void* d_out, int out_size, void* d_ws, size_t ws_size,
                              hipStream_t stream) {
  const float* X  = (const float*)d_in[0];
  const float* W1 = (const float*)d_in[1];
  const float* b1 = (const float*)d_in[2];
  const float* W2 = (const float*)d_in[3];
  const float* b2 = (const float*)d_in[4];
  const int* src  = (const int*)d_in[5];
  const int* dst  = (const int*)d_in[6];
  const int* gid  = (const int*)d_in[7];
  int E = in_sizes[5];
  int N = in_sizes[7];
  int G = out_size / DD;   // 64
  int nb = (N >> 9) + 1;   // node buckets

  char* w = (char*)d_ws;
  size_t o = 0;
  auto carve = [&](size_t bytes) { char* p = w + o; o += (bytes + 255) & ~(size_t)255; return p; };
  // zero-init region
  int*   gcnt   = (int*)  carve((size_t)G * 4);
  size_t zeroBytes = o;
  // rest (fully written before read)
  unsigned* histD = (unsigned*)carve((size_t)PB * 256 * 4);
  unsigned* histS = (unsigned*)carve((size_t)PB * 256 * 4);
  unsigned* tot   = (unsigned*)carve(512 * 4);
  int*   bsD    = (int*)  carve(257 * 4);
  int*   bsS    = (int*)  carve(257 * 4);
  unsigned* pairD = (unsigned*)carve((size_t)E * 4);  // } pairD+pairS (12.8 MB) aliased as part
  unsigned* pairS = (unsigned*)carve((size_t)E * 4);  // }   (GB*32KB = 12.58 MB fits)
  int*   srcS   = (int*)  carve((size_t)E * 4);
  int*   offs   = (int*)  carve((size_t)(N + 1) * 4);
  int*   degI   = (int*)  carve((size_t)N * 4);
  float* nsrc   = (float*)carve((size_t)N * 4);
  float* ndst   = (float*)carve((size_t)N * 4);
  uint2* pwg    = (uint2*)carve((size_t)N * 8);
  unsigned short* Wt = (unsigned short*)carve(128 * 128 * 2);
  unsigned char*  Z8 = (unsigned char*)carve((size_t)N * DD);      // fp8
  unsigned short* Hb = (unsigned short*)carve((size_t)N * DD * 2);
  float* P      = (float*)carve((size_t)N * 64 * 4);
  float* part   = (float*)pairD;   // pairD/pairS dead after k_pw

  hipMemsetAsync(d_ws, 0, zeroBytes, stream);

  k_gcnt<<<256, 256, 0, stream>>>(gid, gcnt, N, G);
  k_part1a<<<PB, 256, 0, stream>>>(src, dst, histD, histS, E);
  k_pscanA<<<512, 256, 0, stream>>>(histD, histS, tot);
  k_pscanB<<<1, 256, 0, stream>>>(tot, bsD, bsS);
  k_pscanC<<<2 * PB, 256, 0, stream>>>(histD, histS, bsD, bsS);
  k_part1c<<<PB, 256, 0, stream>>>(src, dst, histD, histS, pairD, pairS, E);
  k_part2d<<<nb, 256, 0, stream>>>(pairD, bsD, offs, degI, srcS, N);
  k_part2s<<<nb, 256, 0, stream>>>(pairS, bsS, nsrc, N);
  k_norm<<<(N + 255) / 256, 256, 0, stream>>>(degI, gcnt, gid, ndst, pwg, N);
  k_wprep<<<128, 128, 0, stream>>>(W1, Wt);
  k_gemm1<<<(N + 63) / 64, 256, 0, stream>>>(X, Wt, nsrc, Z8, N);
  k_layer1<<<(N + 3) / 4, 256, 0, stream>>>(Z8, offs, srcS, b1, nsrc, ndst, Hb, N);
  k_pw<<<nb, 1024, 0, stream>>>(pairS, bsS, pwg, P, N);
  k_poolgemm<<<GB, 256, 0, stream>>>(P, Hb, part, N);
  k_out<<<G, DD, 0, stream>>>(part, W2, b2, (float*)d_out);
}

// Round 11
// 360.146 us; speedup vs baseline: 1.8154x; 1.0262x over previous
//
#include <hip/hip_runtime.h>
#include <cstdint>

// GCN via radix partition (bucket = node>>9), packed u32 edge records.
// part1c: LDS-staged local counting sort -> ordered run writes (kills line ping-pong).
// Z table fp8-e4m3 (12.8 MB); layer1 = half-wave gather (32 lanes x 4B/row).
// pooled = P^T H; out = pooled@W2+b2.

#define DD 128
#define PB 512    // partition pass-1 blocks
#define GB 384    // poolgemm split-K blocks (part aliased onto pairD+pairS)
#define KC 32     // poolgemm K-chunk
#define CHK 3200  // max edges per part1c block (ceil(E/PB) must be <= this)

typedef __attribute__((ext_vector_type(8))) short bf16x8;
typedef __attribute__((ext_vector_type(4))) float f32x4;
typedef __attribute__((ext_vector_type(2))) float f32x2;

__device__ __forceinline__ unsigned short f2bf(float f) {
  union { float f; unsigned u; } v; v.f = f;
  unsigned r = (v.u + 0x7fff + ((v.u >> 16) & 1)) >> 16;   // round-nearest-even
  return (unsigned short)r;
}
__device__ __forceinline__ float bfhi(unsigned u) {
  union { unsigned u; float f; } v; v.u = u & 0xffff0000u; return v.f;
}
__device__ __forceinline__ float bflo(unsigned u) {
  union { unsigned u; float f; } v; v.u = u << 16; return v.f;
}
__device__ __forceinline__ unsigned char f2fp8(float f) {
  return (unsigned char)(__builtin_amdgcn_cvt_pk_fp8_f32(f, f, 0, false) & 0xff);
}

// ---- pass 1a: per-block 256-bin LDS histograms of dst>>9 and src>>9 + gcnt ----
__global__ __launch_bounds__(256) void k_part1a(const int* __restrict__ src, const int* __restrict__ dst,
                                                const int* __restrict__ gid,
                                                unsigned* __restrict__ histD, unsigned* __restrict__ histS,
                                                int* __restrict__ gcnt, int E, int N, int G) {
  __shared__ unsigned hD[256], hS[256];
  __shared__ int h64[64];
  hD[threadIdx.x] = 0; hS[threadIdx.x] = 0;
  if (threadIdx.x < 64) h64[threadIdx.x] = 0;
  __syncthreads();
  int chunk = (E + gridDim.x - 1) / gridDim.x;
  int e0 = blockIdx.x * chunk, e1 = min(E, e0 + chunk);
  for (int e = e0 + threadIdx.x; e < e1; e += 256) {
    atomicAdd(&hD[(unsigned)dst[e] >> 9], 1u);
    atomicAdd(&hS[(unsigned)src[e] >> 9], 1u);
  }
  int stride = gridDim.x * 256;
  for (int i = blockIdx.x * 256 + threadIdx.x; i < N; i += stride)
    atomicAdd(&h64[gid[i]], 1);
  __syncthreads();
  histD[blockIdx.x * 256 + threadIdx.x] = hD[threadIdx.x];
  histS[blockIdx.x * 256 + threadIdx.x] = hS[threadIdx.x];
  if (threadIdx.x < (unsigned)G) {
    int v = h64[threadIdx.x];
    if (v) atomicAdd(&gcnt[threadIdx.x], v);
  }
}

// ---- pscanA: per (table,bucket) — scan the PB per-block counts ----
__global__ __launch_bounds__(256) void k_pscanA(unsigned* __restrict__ histD, unsigned* __restrict__ histS,
                                                unsigned* __restrict__ tot) {
  __shared__ unsigned excl[PB], psc[256];
  int table = blockIdx.x >> 8, b = blockIdx.x & 255;
  unsigned* hist = table ? histS : histD;
  int t = threadIdx.x;
  unsigned s0 = hist[(2 * t) * 256 + b];
  unsigned s1 = hist[(2 * t + 1) * 256 + b];
  unsigned pr = s0 + s1;
  psc[t] = pr;
  __syncthreads();
  for (int off = 1; off < 256; off <<= 1) {
    unsigned x = (t >= off) ? psc[t - off] : 0;
    __syncthreads();
    psc[t] += x;
    __syncthreads();
  }
  unsigned pex = psc[t] - pr;
  excl[2 * t] = pex;
  excl[2 * t + 1] = pex + s0;
  __syncthreads();
  hist[(2 * t) * 256 + b] = excl[2 * t];
  hist[(2 * t + 1) * 256 + b] = excl[2 * t + 1];
  if (t == 255) tot[table * 256 + b] = psc[255];
}

// ---- pscanB: one block — scan bucket totals for both tables ----
__global__ __launch_bounds__(256) void k_pscanB(const unsigned* __restrict__ tot,
                                                int* __restrict__ bsD, int* __restrict__ bsS) {
  __shared__ unsigned s[256];
  int t = threadIdx.x;
#pragma unroll
  for (int table = 0; table < 2; ++table) {
    int* bs = table ? bsS : bsD;
    unsigned v = tot[table * 256 + t];
    s[t] = v;
    __syncthreads();
    for (int off = 1; off < 256; off <<= 1) {
      unsigned x = (t >= off) ? s[t - off] : 0;
      __syncthreads();
      s[t] += x;
      __syncthreads();
    }
    bs[t] = (int)(s[t] - v);
    if (t == 255) bs[256] = (int)s[255];
    __syncthreads();
  }
}

// ---- pscanC: add bucket base into per-(block,bucket) cursors ----
__global__ __launch_bounds__(256) void k_pscanC(unsigned* __restrict__ histD, unsigned* __restrict__ histS,
                                                const int* __restrict__ bsD, const int* __restrict__ bsS) {
  int table = blockIdx.x >> 9, i = blockIdx.x & (PB - 1);
  unsigned* hist = table ? histS : histD;
  const int* bs = table ? bsS : bsD;
  hist[i * 256 + threadIdx.x] += (unsigned)bs[threadIdx.x];
}

// ---- pass 1c: LDS-staged local counting sort, then ORDERED run write-out ----
// pairD: (dst&511)<<17 | src ; pairS: (src&511)<<17 | dst   (N < 2^17)
__global__ __launch_bounds__(256) void k_part1c(const int* __restrict__ src, const int* __restrict__ dst,
                                                const unsigned* __restrict__ histD, const unsigned* __restrict__ histS,
                                                unsigned* __restrict__ pairD, unsigned* __restrict__ pairS, int E) {
  __shared__ unsigned pk[CHK];
  __shared__ unsigned char bk[CHK];
  __shared__ unsigned hist[256], cur[256], gbase[256], psc[256];
  int chunk = (E + gridDim.x - 1) / gridDim.x;
  int e0 = blockIdx.x * chunk, e1 = min(E, e0 + chunk);
  int n = e1 - e0;
  int t = threadIdx.x;
#pragma unroll
  for (int table = 0; table < 2; ++table) {
    const unsigned* gcur = (table ? histS : histD) + blockIdx.x * 256;
    unsigned* out = table ? pairS : pairD;
    hist[t] = 0;
    __syncthreads();
    for (int i = t; i < n; i += 256) {
      unsigned key = (unsigned)(table ? src[e0 + i] : dst[e0 + i]);
      atomicAdd(&hist[key >> 9], 1u);
    }
    __syncthreads();
    unsigned v = hist[t];
    psc[t] = v;
    __syncthreads();
    for (int off = 1; off < 256; off <<= 1) {
      unsigned x = (t >= off) ? psc[t - off] : 0;
      __syncthreads();
      psc[t] += x;
      __syncthreads();
    }
    unsigned excl = psc[t] - v;
    cur[t] = excl;
    gbase[t] = gcur[t] - excl;
    __syncthreads();
    for (int i = t; i < n; i += 256) {
      unsigned sv = (unsigned)src[e0 + i], dv = (unsigned)dst[e0 + i];
      unsigned key = table ? sv : dv;
      unsigned val = table ? (((sv & 511u) << 17) | dv) : (((dv & 511u) << 17) | sv);
      unsigned b = key >> 9;
      unsigned p = atomicAdd(&cur[b], 1u);
      pk[p] = val;
      bk[p] = (unsigned char)b;
    }
    __syncthreads();
    for (int i = t; i < n; i += 256)
      out[gbase[bk[i]] + i] = pk[i];
    __syncthreads();
  }
}

// ---- pass 2d: per dst-bucket — hist, scan, write offs/degI, place srcS ----
__global__ __launch_bounds__(256) void k_part2d(const unsigned* __restrict__ pairD, const int* __restrict__ bsD,
                                                int* __restrict__ offs, int* __restrict__ degI,
                                                int* __restrict__ srcS, int N) {
  __shared__ unsigned hist[512], excl[512], psc[256];
  int k = blockIdx.x, base = k << 9;
  int b0 = bsD[k], b1 = bsD[k + 1];
  hist[threadIdx.x] = 0; hist[threadIdx.x + 256] = 0;
  __syncthreads();
  for (int i = b0 + threadIdx.x; i < b1; i += 256)
    atomicAdd(&hist[pairD[i] >> 17], 1u);
  __syncthreads();
  unsigned s0 = hist[2 * threadIdx.x], s1 = hist[2 * threadIdx.x + 1];
  unsigned pr = s0 + s1;
  psc[threadIdx.x] = pr;
  __syncthreads();
  for (int off = 1; off < 256; off <<= 1) {
    unsigned x = (threadIdx.x >= off) ? psc[threadIdx.x - off] : 0;
    __syncthreads();
    psc[threadIdx.x] += x;
    __syncthreads();
  }
  unsigned pex = psc[threadIdx.x] - pr;
  excl[2 * threadIdx.x] = pex;
  excl[2 * threadIdx.x + 1] = pex + s0;
  __syncthreads();
  for (int j = threadIdx.x; j < 512; j += 256) {
    int node = base + j;
    if (node <= N) offs[node] = b0 + (int)excl[j];
    if (node < N) degI[node] = (int)hist[j];
  }
  __syncthreads();
  for (int i = b0 + threadIdx.x; i < b1; i += 256) {
    unsigned pk = pairD[i];
    unsigned pos = atomicAdd(&excl[pk >> 17], 1u);
    srcS[b0 + (int)pos] = (int)(pk & 0x1FFFFu);
  }
}

// ---- pass 2s (lite): per src-bucket — hist only -> nsrc ----
__global__ __launch_bounds__(256) void k_part2s(const unsigned* __restrict__ pairS, const int* __restrict__ bsS,
                                                float* __restrict__ nsrc, int N) {
  __shared__ unsigned hist[512];
  int k = blockIdx.x, base = k << 9;
  int b0 = bsS[k], b1 = bsS[k + 1];
  hist[threadIdx.x] = 0; hist[threadIdx.x + 256] = 0;
  __syncthreads();
  for (int i = b0 + threadIdx.x; i < b1; i += 256)
    atomicAdd(&hist[pairS[i] >> 17], 1u);
  __syncthreads();
  for (int j = threadIdx.x; j < 512; j += 256) {
    int node = base + j;
    if (node < N) {
      float g = (float)hist[j]; g = g > 0.f ? g : 1.f;
      nsrc[node] = rsqrtf(g);
    }
  }
}

// ---- norms for dst side + packed (poolw, gid) ----
__global__ __launch_bounds__(256) void k_norm(const int* __restrict__ degI, const int* __restrict__ gcnt,
                                              const int* __restrict__ gid,
                                              float* __restrict__ ndst, uint2* __restrict__ pwg, int N) {
  int i = blockIdx.x * blockDim.x + threadIdx.x;
  if (i >= N) return;
  float gi = (float)degI[i]; gi = gi > 0.f ? gi : 1.f;
  float nd = rsqrtf(gi);
  ndst[i] = nd;
  float c = (float)gcnt[gid[i]]; c = c > 1.f ? c : 1.f;
  float w = nd / c;
  union { float f; unsigned u; } v; v.f = w;
  pwg[i] = make_uint2(v.u, (unsigned)gid[i]);
}

// ---- wprep: Wt[n][k] = bf16(W1[k][n]) ----
__global__ __launch_bounds__(128) void k_wprep(const float* __restrict__ W, unsigned short* __restrict__ Wt) {
  int n = blockIdx.x, k = threadIdx.x;
  Wt[n * 128 + k] = f2bf(W[k * 128 + n]);
}

// ---- GEMM1 (MFMA): Z8 = fp8( (X @ W1) * nsrc[row] ), LDS-free ----
__global__ __launch_bounds__(256) void k_gemm1(const float* __restrict__ X, const unsigned short* __restrict__ Wt,
                                               const float* __restrict__ nsrc,
                                               unsigned char* __restrict__ Z8, int N) {
  int wave = threadIdx.x >> 6, lane = threadIdx.x & 63;
  int quad = lane >> 4, l16 = lane & 15;
  int row0 = blockIdx.x * 64 + wave * 16;
  int arow = row0 + l16; if (arow >= N) arow = N - 1;
  const float* xr = X + (size_t)arow * 128 + quad * 8;
  f32x4 acc[8];
#pragma unroll
  for (int i = 0; i < 8; ++i) acc[i] = (f32x4){0.f, 0.f, 0.f, 0.f};
#pragma unroll
  for (int kb = 0; kb < 128; kb += 32) {
    float4 x0 = *(const float4*)(xr + kb);
    float4 x1 = *(const float4*)(xr + kb + 4);
    bf16x8 a;
    a[0] = (short)f2bf(x0.x); a[1] = (short)f2bf(x0.y);
    a[2] = (short)f2bf(x0.z); a[3] = (short)f2bf(x0.w);
    a[4] = (short)f2bf(x1.x); a[5] = (short)f2bf(x1.y);
    a[6] = (short)f2bf(x1.z); a[7] = (short)f2bf(x1.w);
#pragma unroll
    for (int nt = 0; nt < 8; ++nt) {
      bf16x8 b = *(const bf16x8*)(Wt + (size_t)(nt * 16 + l16) * 128 + kb + quad * 8);
      acc[nt] = __builtin_amdgcn_mfma_f32_16x16x32_bf16(a, b, acc[nt], 0, 0, 0);
    }
  }
  int rbase = row0 + quad * 4;
#pragma unroll
  for (int r = 0; r < 4; ++r) {
    int row = rbase + r;
    if (row < N) {
      float s = nsrc[row];
#pragma unroll
      for (int nt = 0; nt < 8; ++nt)
        Z8[(size_t)row * 128 + nt * 16 + l16] = f2fp8(acc[nt][r] * s);
    }
  }
}

// ---- layer1: per-dst gather-reduce (fp8 rows, half-wave pairs) + fused post-op ----
__global__ __launch_bounds__(256) void k_layer1(const unsigned char* __restrict__ Z8,
                                                const int* __restrict__ offs, const int* __restrict__ srcS,
                                                const float* __restrict__ b1,
                                                const float* __restrict__ nsrc, const float* __restrict__ ndst,
                                                unsigned short* __restrict__ Hb, int N) {
  int lane = threadIdx.x & 63;
  int half = lane >> 5, l32 = lane & 31;
  int d = blockIdx.x * 4 + (threadIdx.x >> 6);
  if (d >= N) return;
  int start = offs[d], end = offs[d + 1];
  float a0 = 0.f, a1 = 0.f, a2 = 0.f, a3 = 0.f;
  int e = start;
  for (; e + 8 <= end; e += 8) {
    int s0 = srcS[e + half], s1 = srcS[e + 2 + half];
    int s2 = srcS[e + 4 + half], s3 = srcS[e + 6 + half];
    unsigned u0 = *(const unsigned*)(Z8 + (size_t)s0 * 128 + l32 * 4);
    unsigned u1 = *(const unsigned*)(Z8 + (size_t)s1 * 128 + l32 * 4);
    unsigned u2 = *(const unsigned*)(Z8 + (size_t)s2 * 128 + l32 * 4);
    unsigned u3 = *(const unsigned*)(Z8 + (size_t)s3 * 128 + l32 * 4);
    f32x2 p0 = __builtin_amdgcn_cvt_pk_f32_fp8(u0, false), q0 = __builtin_amdgcn_cvt_pk_f32_fp8(u0, true);
    f32x2 p1 = __builtin_amdgcn_cvt_pk_f32_fp8(u1, false), q1 = __builtin_amdgcn_cvt_pk_f32_fp8(u1, true);
    f32x2 p2 = __builtin_amdgcn_cvt_pk_f32_fp8(u2, false), q2 = __builtin_amdgcn_cvt_pk_f32_fp8(u2, true);
    f32x2 p3 = __builtin_amdgcn_cvt_pk_f32_fp8(u3, false), q3 = __builtin_amdgcn_cvt_pk_f32_fp8(u3, true);
    a0 += (p0[0] + p1[0]) + (p2[0] + p3[0]);
    a1 += (p0[1] + p1[1]) + (p2[1] + p3[1]);
    a2 += (q0[0] + q1[0]) + (q2[0] + q3[0]);
    a3 += (q0[1] + q1[1]) + (q2[1] + q3[1]);
  }
  for (; e + 2 <= end; e += 2) {
    int s = srcS[e + half];
    unsigned u = *(const unsigned*)(Z8 + (size_t)s * 128 + l32 * 4);
    f32x2 p = __builtin_amdgcn_cvt_pk_f32_fp8(u, false), q = __builtin_amdgcn_cvt_pk_f32_fp8(u, true);
    a0 += p[0]; a1 += p[1]; a2 += q[0]; a3 += q[1];
  }
  if (e < end && half == 0) {
    int s = srcS[e];
    unsigned u = *(const unsigned*)(Z8 + (size_t)s * 128 + l32 * 4);
    f32x2 p = __builtin_amdgcn_cvt_pk_f32_fp8(u, false), q = __builtin_amdgcn_cvt_pk_f32_fp8(u, true);
    a0 += p[0]; a1 += p[1]; a2 += q[0]; a3 += q[1];
  }
  a0 += __shfl_xor(a0, 32, 64);
  a1 += __shfl_xor(a1, 32, 64);
  a2 += __shfl_xor(a2, 32, 64);
  a3 += __shfl_xor(a3, 32, 64);
  if (half == 0) {
    float nd = ndst[d], ns = nsrc[d];
    int f = l32 * 4;
    float h0 = fmaxf(fmaf(nd, a0, b1[f + 0]), 0.f) * ns;
    float h1 = fmaxf(fmaf(nd, a1, b1[f + 1]), 0.f) * ns;
    float h2 = fmaxf(fmaf(nd, a2, b1[f + 2]), 0.f) * ns;
    float h3 = fmaxf(fmaf(nd, a3, b1[f + 3]), 0.f) * ns;
    ushort4 o; o.x = f2bf(h0); o.y = f2bf(h1); o.z = f2bf(h2); o.w = f2bf(h3);
    *(ushort4*)(Hb + (size_t)d * 128 + f) = o;
  }
}

// ---- k_pw: per src-bucket — 128 KB LDS P-tile, 1024 threads (16 waves) ----
__global__ __launch_bounds__(1024, 1) void k_pw(const unsigned* __restrict__ pairS, const int* __restrict__ bsS,
                                                const uint2* __restrict__ pwg, float* __restrict__ P, int N) {
  __shared__ float tile[512 * 64];   // 128 KB
  int k = blockIdx.x, base = k << 9;
  int b0 = bsS[k], b1 = bsS[k + 1];
  for (int i = threadIdx.x; i < 512 * 64; i += 1024) tile[i] = 0.f;
  __syncthreads();
  for (int i = b0 + threadIdx.x; i < b1; i += 1024) {
    unsigned pk = pairS[i];
    unsigned dv = pk & 0x1FFFFu;
    unsigned sloc = pk >> 17;
    uint2 u = pwg[dv];
    union { unsigned u; float f; } w; w.u = u.x;
    atomicAdd(&tile[sloc * 64 + u.y], w.f);
  }
  __syncthreads();
  for (int i = threadIdx.x; i < 512 * 64; i += 1024) {
    int node = base + (i >> 6);
    if (node < N) P[(size_t)node * 64 + (i & 63)] = tile[i];
  }
}

// ---- k_poolgemm: part[b] = P[rows]^T · H[rows]  (streaming split-K GEMM) ----
__global__ __launch_bounds__(256) void k_poolgemm(const float* __restrict__ P,
                                                  const unsigned short* __restrict__ Hb,
                                                  float* __restrict__ part, int N) {
  __shared__ float Pl[KC * 64];    // 8 KB
  __shared__ float Hl[KC * 128];   // 16 KB
  int t = threadIdx.x;
  int chunk = (N + gridDim.x - 1) / gridDim.x;
  int r0 = blockIdx.x * chunk, r1 = min(N, r0 + chunk);
  float acc[4][8] = {};
  int gq = (t & 15) * 4, fo = (t >> 4) * 8;
  for (int rb = r0; rb < r1; rb += KC) {
    {
      int idx = t * 8;
      int r = idx >> 6, c = idx & 63;
      int row = rb + r;
      float4 z = make_float4(0.f, 0.f, 0.f, 0.f);
      float4 v0 = z, v1 = z;
      if (row < r1) {
        v0 = *(const float4*)(P + (size_t)row * 64 + c);
        v1 = *(const float4*)(P + (size_t)row * 64 + c + 4);
      }
      *(float4*)(Pl + idx) = v0;
      *(float4*)(Pl + idx + 4) = v1;
    }
    {
      int idx = t * 16;
      int r = idx >> 7, c = idx & 127;
      int row = rb + r;
      if (row < r1) {
        uint4 ua = *(const uint4*)(Hb + (size_t)row * 128 + c);
        uint4 ub = *(const uint4*)(Hb + (size_t)row * 128 + c + 8);
        *(float4*)(Hl + idx)      = make_float4(bflo(ua.x), bfhi(ua.x), bflo(ua.y), bfhi(ua.y));
        *(float4*)(Hl + idx + 4)  = make_float4(bflo(ua.z), bfhi(ua.z), bflo(ua.w), bfhi(ua.w));
        *(float4*)(Hl + idx + 8)  = make_float4(bflo(ub.x), bfhi(ub.x), bflo(ub.y), bfhi(ub.y));
        *(float4*)(Hl + idx + 12) = make_float4(bflo(ub.z), bfhi(ub.z), bflo(ub.w), bfhi(ub.w));
      } else {
        float4 z = make_float4(0.f, 0.f, 0.f, 0.f);
        *(float4*)(Hl + idx) = z; *(float4*)(Hl + idx + 4) = z;
        *(float4*)(Hl + idx + 8) = z; *(float4*)(Hl + idx + 12) = z;
      }
    }
    __syncthreads();
#pragma unroll 4
    for (int r = 0; r < KC; ++r) {
      float4 pv = *(const float4*)(Pl + r * 64 + gq);
      float4 h0 = *(const float4*)(Hl + r * 128 + fo);
      float4 h1 = *(const float4*)(Hl + r * 128 + fo + 4);
      const float* pf = (const float*)&pv;
      const float* hf0 = (const float*)&h0;
      const float* hf1 = (const float*)&h1;
#pragma unroll
      for (int gg = 0; gg < 4; ++gg) {
#pragma unroll
        for (int ff = 0; ff < 4; ++ff) {
          acc[gg][ff]     = fmaf(pf[gg], hf0[ff], acc[gg][ff]);
          acc[gg][ff + 4] = fmaf(pf[gg], hf1[ff], acc[gg][ff + 4]);
        }
      }
    }
    __syncthreads();
  }
  float* base = part + (size_t)blockIdx.x * 64 * DD;
#pragma unroll
  for (int gg = 0; gg < 4; ++gg) {
    *(float4*)(base + (gq + gg) * DD + fo)     = make_float4(acc[gg][0], acc[gg][1], acc[gg][2], acc[gg][3]);
    *(float4*)(base + (gq + gg) * DD + fo + 4) = make_float4(acc[gg][4], acc[gg][5], acc[gg][6], acc[gg][7]);
  }
}

// ---- out: fold split-K partials, then @W2 + b2 ----
__global__ __launch_bounds__(128) void k_out(const float* __restrict__ part, const float* __restrict__ W2,
                                             const float* __restrict__ b2, float* __restrict__ out) {
  __shared__ float p[DD];
  int g = blockIdx.x, d = threadIdx.x;
  float s = 0.f;
#pragma unroll 4
  for (int k = 0; k < GB; ++k) s += part[(size_t)k * 64 * DD + g * DD + d];
  p[d] = s;
  __syncthreads();
  float a = b2[d];
#pragma unroll 4
  for (int k = 0; k < DD; ++k) a = fmaf(p[k], W2[k * DD + d], a);
  out[g * DD + d] = a;
}

extern "C" void kernel_launch(void* const* d_in, const int* in_sizes, int n_in,
                              void* d_out, int out_size, void* d_ws, size_t ws_size,
                              hipStream_t stream) {
  const float* X  = (const float*)d_in[0];
  const float* W1 = (const float*)d_in[1];
  const float* b1 = (const float*)d_in[2];
  const float* W2 = (const float*)d_in[3];
  const float* b2 = (const float*)d_in[4];
  const int* src  = (const int*)d_in[5];
  const int* dst  = (const int*)d_in[6];
  const int* gid  = (const int*)d_in[7];
  int E = in_sizes[5];
  int N = in_sizes[7];
  int G = out_size / DD;   // 64
  int nb = (N >> 9) + 1;   // node buckets

  char* w = (char*)d_ws;
  size_t o = 0;
  auto carve = [&](size_t bytes) { char* p = w + o; o += (bytes + 255) & ~(size_t)255; return p; };
  // zero-init region
  int*   gcnt   = (int*)  carve((size_t)G * 4);
  size_t zeroBytes = o;
  // rest (fully written before read)
  unsigned* histD = (unsigned*)carve((size_t)PB * 256 * 4);
  unsigned* histS = (unsigned*)carve((size_t)PB * 256 * 4);
  unsigned* tot   = (unsigned*)carve(512 * 4);
  int*   bsD    = (int*)  carve(257 * 4);
  int*   bsS    = (int*)  carve(257 * 4);
  unsigned* pairD = (unsigned*)carve((size_t)E * 4);  // } pairD+pairS (12.8 MB) aliased as part
  unsigned* pairS = (unsigned*)carve((size_t)E * 4);  // }   (GB*32KB = 12.58 MB fits)
  int*   srcS   = (int*)  carve((size_t)E * 4);
  int*   offs   = (int*)  carve((size_t)(N + 1) * 4);
  int*   degI   = (int*)  carve((size_t)N * 4);
  float* nsrc   = (float*)carve((size_t)N * 4);
  float* ndst   = (float*)carve((size_t)N * 4);
  uint2* pwg    = (uint2*)carve((size_t)N * 8);
  unsigned short* Wt = (unsigned short*)carve(128 * 128 * 2);
  unsigned char*  Z8 = (unsigned char*)carve((size_t)N * DD);      // fp8
  unsigned short* Hb = (unsigned short*)carve((size_t)N * DD * 2);
  float* P      = (float*)carve((size_t)N * 64 * 4);
  float* part   = (float*)pairD;   // pairD/pairS dead after k_pw

  hipMemsetAsync(d_ws, 0, zeroBytes, stream);

  k_part1a<<<PB, 256, 0, stream>>>(src, dst, gid, histD, histS, gcnt, E, N, G);
  k_pscanA<<<512, 256, 0, stream>>>(histD, histS, tot);
  k_pscanB<<<1, 256, 0, stream>>>(tot, bsD, bsS);
  k_pscanC<<<2 * PB, 256, 0, stream>>>(histD, histS, bsD, bsS);
  k_part1c<<<PB, 256, 0, stream>>>(src, dst, histD, histS, pairD, pairS, E);
  k_part2d<<<nb, 256, 0, stream>>>(pairD, bsD, offs, degI, srcS, N);
  k_part2s<<<nb, 256, 0, stream>>>(pairS, bsS, nsrc, N);
  k_norm<<<(N + 255) / 256, 256, 0, stream>>>(degI, gcnt, gid, ndst, pwg, N);
  k_wprep<<<128, 128, 0, stream>>>(W1, Wt);
  k_gemm1<<<(N + 63) / 64, 256, 0, stream>>>(X, Wt, nsrc, Z8, N);
  k_layer1<<<(N + 3) / 4, 256, 0, stream>>>(Z8, offs, srcS, b1, nsrc, ndst, Hb, N);
  k_pw<<<nb, 1024, 0, stream>>>(pairS, bsS, pwg, P, N);
  k_poolgemm<<<GB, 256, 0, stream>>>(P, Hb, part, N);
  k_out<<<G, DD, 0, stream>>>(part, W2, b2, (float*)d_out);
}

// Round 12
// 313.853 us; speedup vs baseline: 2.0831x; 1.1475x over previous
//
#include <hip/hip_runtime.h>
#include <cstdint>

// GCN via radix partition (bucket = node>>9), packed u32 edge records.
// part1c: LDS-staged local counting sort -> ordered run writes.
// Z fp8-e4m3 (12.8 MB). pooled = P^T H via MFMA (P blocked bf16), fold, tiny out.

#define DD 128
#define PB 512    // partition pass-1 blocks
#define GB 384    // poolgemm split-K blocks (part aliased onto pairD+pairS)
#define KC 32     // poolgemm K-chunk
#define CHK 3200  // max edges per part1c block

typedef __attribute__((ext_vector_type(8))) short bf16x8;
typedef __attribute__((ext_vector_type(4))) float f32x4;
typedef __attribute__((ext_vector_type(2))) float f32x2;

__device__ __forceinline__ unsigned short f2bf(float f) {
  union { float f; unsigned u; } v; v.f = f;
  unsigned r = (v.u + 0x7fff + ((v.u >> 16) & 1)) >> 16;   // round-nearest-even
  return (unsigned short)r;
}
__device__ __forceinline__ float bfhi(unsigned u) {
  union { unsigned u; float f; } v; v.u = u & 0xffff0000u; return v.f;
}
__device__ __forceinline__ float bflo(unsigned u) {
  union { unsigned u; float f; } v; v.u = u << 16; return v.f;
}
__device__ __forceinline__ unsigned char f2fp8(float f) {
  return (unsigned char)(__builtin_amdgcn_cvt_pk_fp8_f32(f, f, 0, false) & 0xff);
}

// ---- pass 1a: per-block 256-bin LDS histograms of dst>>9 and src>>9 + gcnt ----
__global__ __launch_bounds__(256) void k_part1a(const int* __restrict__ src, const int* __restrict__ dst,
                                                const int* __restrict__ gid,
                                                unsigned* __restrict__ histD, unsigned* __restrict__ histS,
                                                int* __restrict__ gcnt, int E, int N, int G) {
  __shared__ unsigned hD[256], hS[256];
  __shared__ int h64[64];
  hD[threadIdx.x] = 0; hS[threadIdx.x] = 0;
  if (threadIdx.x < 64) h64[threadIdx.x] = 0;
  __syncthreads();
  int chunk = (E + gridDim.x - 1) / gridDim.x;
  int e0 = blockIdx.x * chunk, e1 = min(E, e0 + chunk);
  for (int e = e0 + threadIdx.x; e < e1; e += 256) {
    atomicAdd(&hD[(unsigned)dst[e] >> 9], 1u);
    atomicAdd(&hS[(unsigned)src[e] >> 9], 1u);
  }
  int stride = gridDim.x * 256;
  for (int i = blockIdx.x * 256 + threadIdx.x; i < N; i += stride)
    atomicAdd(&h64[gid[i]], 1);
  __syncthreads();
  histD[blockIdx.x * 256 + threadIdx.x] = hD[threadIdx.x];
  histS[blockIdx.x * 256 + threadIdx.x] = hS[threadIdx.x];
  if (threadIdx.x < (unsigned)G) {
    int v = h64[threadIdx.x];
    if (v) atomicAdd(&gcnt[threadIdx.x], v);
  }
}

// ---- pscanA: per (table,bucket) — scan the PB per-block counts ----
__global__ __launch_bounds__(256) void k_pscanA(unsigned* __restrict__ histD, unsigned* __restrict__ histS,
                                                unsigned* __restrict__ tot) {
  __shared__ unsigned excl[PB], psc[256];
  int table = blockIdx.x >> 8, b = blockIdx.x & 255;
  unsigned* hist = table ? histS : histD;
  int t = threadIdx.x;
  unsigned s0 = hist[(2 * t) * 256 + b];
  unsigned s1 = hist[(2 * t + 1) * 256 + b];
  unsigned pr = s0 + s1;
  psc[t] = pr;
  __syncthreads();
  for (int off = 1; off < 256; off <<= 1) {
    unsigned x = (t >= off) ? psc[t - off] : 0;
    __syncthreads();
    psc[t] += x;
    __syncthreads();
  }
  unsigned pex = psc[t] - pr;
  excl[2 * t] = pex;
  excl[2 * t + 1] = pex + s0;
  __syncthreads();
  hist[(2 * t) * 256 + b] = excl[2 * t];
  hist[(2 * t + 1) * 256 + b] = excl[2 * t + 1];
  if (t == 255) tot[table * 256 + b] = psc[255];
}

// ---- pscanB: one block — scan bucket totals for both tables ----
__global__ __launch_bounds__(256) void k_pscanB(const unsigned* __restrict__ tot,
                                                int* __restrict__ bsD, int* __restrict__ bsS) {
  __shared__ unsigned s[256];
  int t = threadIdx.x;
#pragma unroll
  for (int table = 0; table < 2; ++table) {
    int* bs = table ? bsS : bsD;
    unsigned v = tot[table * 256 + t];
    s[t] = v;
    __syncthreads();
    for (int off = 1; off < 256; off <<= 1) {
      unsigned x = (t >= off) ? s[t - off] : 0;
      __syncthreads();
      s[t] += x;
      __syncthreads();
    }
    bs[t] = (int)(s[t] - v);
    if (t == 255) bs[256] = (int)s[255];
    __syncthreads();
  }
}

// ---- pscanC: add bucket base into per-(block,bucket) cursors ----
__global__ __launch_bounds__(256) void k_pscanC(unsigned* __restrict__ histD, unsigned* __restrict__ histS,
                                                const int* __restrict__ bsD, const int* __restrict__ bsS) {
  int table = blockIdx.x >> 9, i = blockIdx.x & (PB - 1);
  unsigned* hist = table ? histS : histD;
  const int* bs = table ? bsS : bsD;
  hist[i * 256 + threadIdx.x] += (unsigned)bs[threadIdx.x];
}

// ---- pass 1c: LDS-staged local counting sort, then ORDERED run write-out ----
// pairD: (dst&511)<<17 | src ; pairS: (src&511)<<17 | dst   (N < 2^17)
__global__ __launch_bounds__(256) void k_part1c(const int* __restrict__ src, const int* __restrict__ dst,
                                                const unsigned* __restrict__ histD, const unsigned* __restrict__ histS,
                                                unsigned* __restrict__ pairD, unsigned* __restrict__ pairS, int E) {
  __shared__ unsigned pk[CHK];
  __shared__ unsigned char bk[CHK];
  __shared__ unsigned hist[256], cur[256], gbase[256], psc[256];
  int chunk = (E + gridDim.x - 1) / gridDim.x;
  int e0 = blockIdx.x * chunk, e1 = min(E, e0 + chunk);
  int n = e1 - e0;
  int t = threadIdx.x;
#pragma unroll
  for (int table = 0; table < 2; ++table) {
    const unsigned* gcur = (table ? histS : histD) + blockIdx.x * 256;
    unsigned* out = table ? pairS : pairD;
    hist[t] = 0;
    __syncthreads();
    for (int i = t; i < n; i += 256) {
      unsigned key = (unsigned)(table ? src[e0 + i] : dst[e0 + i]);
      atomicAdd(&hist[key >> 9], 1u);
    }
    __syncthreads();
    unsigned v = hist[t];
    psc[t] = v;
    __syncthreads();
    for (int off = 1; off < 256; off <<= 1) {
      unsigned x = (t >= off) ? psc[t - off] : 0;
      __syncthreads();
      psc[t] += x;
      __syncthreads();
    }
    unsigned excl = psc[t] - v;
    cur[t] = excl;
    gbase[t] = gcur[t] - excl;
    __syncthreads();
    for (int i = t; i < n; i += 256) {
      unsigned sv = (unsigned)src[e0 + i], dv = (unsigned)dst[e0 + i];
      unsigned key = table ? sv : dv;
      unsigned val = table ? (((sv & 511u) << 17) | dv) : (((dv & 511u) << 17) | sv);
      unsigned b = key >> 9;
      unsigned p = atomicAdd(&cur[b], 1u);
      pk[p] = val;
      bk[p] = (unsigned char)b;
    }
    __syncthreads();
    for (int i = t; i < n; i += 256)
      out[gbase[bk[i]] + i] = pk[i];
    __syncthreads();
  }
}

// ---- pass 2d: per dst-bucket — hist, scan, write offs/degI, place srcS ----
__global__ __launch_bounds__(256) void k_part2d(const unsigned* __restrict__ pairD, const int* __restrict__ bsD,
                                                int* __restrict__ offs, int* __restrict__ degI,
                                                int* __restrict__ srcS, int N) {
  __shared__ unsigned hist[512], excl[512], psc[256];
  int k = blockIdx.x, base = k << 9;
  int b0 = bsD[k], b1 = bsD[k + 1];
  hist[threadIdx.x] = 0; hist[threadIdx.x + 256] = 0;
  __syncthreads();
  for (int i = b0 + threadIdx.x; i < b1; i += 256)
    atomicAdd(&hist[pairD[i] >> 17], 1u);
  __syncthreads();
  unsigned s0 = hist[2 * threadIdx.x], s1 = hist[2 * threadIdx.x + 1];
  unsigned pr = s0 + s1;
  psc[threadIdx.x] = pr;
  __syncthreads();
  for (int off = 1; off < 256; off <<= 1) {
    unsigned x = (threadIdx.x >= off) ? psc[threadIdx.x - off] : 0;
    __syncthreads();
    psc[threadIdx.x] += x;
    __syncthreads();
  }
  unsigned pex = psc[threadIdx.x] - pr;
  excl[2 * threadIdx.x] = pex;
  excl[2 * threadIdx.x + 1] = pex + s0;
  __syncthreads();
  for (int j = threadIdx.x; j < 512; j += 256) {
    int node = base + j;
    if (node <= N) offs[node] = b0 + (int)excl[j];
    if (node < N) degI[node] = (int)hist[j];
  }
  __syncthreads();
  for (int i = b0 + threadIdx.x; i < b1; i += 256) {
    unsigned pkv = pairD[i];
    unsigned pos = atomicAdd(&excl[pkv >> 17], 1u);
    srcS[b0 + (int)pos] = (int)(pkv & 0x1FFFFu);
  }
}

// ---- norms for dst side + packed (poolw, gid) ----
__global__ __launch_bounds__(256) void k_norm(const int* __restrict__ degI, const int* __restrict__ gcnt,
                                              const int* __restrict__ gid,
                                              float* __restrict__ ndst, uint2* __restrict__ pwg, int N) {
  int i = blockIdx.x * blockDim.x + threadIdx.x;
  if (i >= N) return;
  float gi = (float)degI[i]; gi = gi > 0.f ? gi : 1.f;
  float nd = rsqrtf(gi);
  ndst[i] = nd;
  float c = (float)gcnt[gid[i]]; c = c > 1.f ? c : 1.f;
  float w = nd / c;
  union { float f; unsigned u; } v; v.f = w;
  pwg[i] = make_uint2(v.u, (unsigned)gid[i]);
}

// ---- k_pw (fused part2s): per src-bucket — out-degree hist -> nsrc,
//      and 128 KB LDS P-tile -> blocked bf16 P_blk[(k>>3)][g][k&7] ----
__global__ __launch_bounds__(1024, 1) void k_pw(const unsigned* __restrict__ pairS, const int* __restrict__ bsS,
                                                const uint2* __restrict__ pwg,
                                                unsigned short* __restrict__ P16,
                                                float* __restrict__ nsrc, int N) {
  __shared__ float tile[512 * 64];   // 128 KB
  __shared__ unsigned hist[512];     // 2 KB
  int k = blockIdx.x, base = k << 9;
  int b0 = bsS[k], b1 = bsS[k + 1];
  for (int i = threadIdx.x; i < 512 * 64; i += 1024) tile[i] = 0.f;
  if (threadIdx.x < 512) hist[threadIdx.x] = 0;
  __syncthreads();
  for (int i = b0 + threadIdx.x; i < b1; i += 1024) {
    unsigned pkv = pairS[i];
    unsigned dv = pkv & 0x1FFFFu;
    unsigned sloc = pkv >> 17;
    atomicAdd(&hist[sloc], 1u);
    uint2 u = pwg[dv];
    union { unsigned u; float f; } w; w.u = u.x;
    atomicAdd(&tile[sloc * 64 + u.y], w.f);
  }
  __syncthreads();
  if (threadIdx.x < 512) {
    int node = base + threadIdx.x;
    if (node < N) {
      float g = (float)hist[threadIdx.x]; g = g > 0.f ? g : 1.f;
      nsrc[node] = rsqrtf(g);
    }
  }
  // blocked bf16 write: rows >= N are zero (tile untouched) -> poolgemm needs no K guard
  for (int grp = threadIdx.x; grp < 4096; grp += 1024) {
    int qb = grp >> 6, g = grp & 63;
    unsigned w0 = (unsigned)f2bf(tile[(qb * 8 + 0) * 64 + g]) | ((unsigned)f2bf(tile[(qb * 8 + 1) * 64 + g]) << 16);
    unsigned w1 = (unsigned)f2bf(tile[(qb * 8 + 2) * 64 + g]) | ((unsigned)f2bf(tile[(qb * 8 + 3) * 64 + g]) << 16);
    unsigned w2 = (unsigned)f2bf(tile[(qb * 8 + 4) * 64 + g]) | ((unsigned)f2bf(tile[(qb * 8 + 5) * 64 + g]) << 16);
    unsigned w3 = (unsigned)f2bf(tile[(qb * 8 + 6) * 64 + g]) | ((unsigned)f2bf(tile[(qb * 8 + 7) * 64 + g]) << 16);
    uint4 o = make_uint4(w0, w1, w2, w3);
    *(uint4*)(P16 + ((size_t)(base >> 3) + qb) * 512 + g * 8) = o;
  }
}

// ---- wprep: Wt[n][k] = bf16(W1[k][n]) ----
__global__ __launch_bounds__(128) void k_wprep(const float* __restrict__ W, unsigned short* __restrict__ Wt) {
  int n = blockIdx.x, k = threadIdx.x;
  Wt[n * 128 + k] = f2bf(W[k * 128 + n]);
}

// ---- GEMM1 (MFMA): Z8 = fp8( (X @ W1) * nsrc[row] ), LDS-free ----
__global__ __launch_bounds__(256) void k_gemm1(const float* __restrict__ X, const unsigned short* __restrict__ Wt,
                                               const float* __restrict__ nsrc,
                                               unsigned char* __restrict__ Z8, int N) {
  int wave = threadIdx.x >> 6, lane = threadIdx.x & 63;
  int quad = lane >> 4, l16 = lane & 15;
  int row0 = blockIdx.x * 64 + wave * 16;
  int arow = row0 + l16; if (arow >= N) arow = N - 1;
  const float* xr = X + (size_t)arow * 128 + quad * 8;
  f32x4 acc[8];
#pragma unroll
  for (int i = 0; i < 8; ++i) acc[i] = (f32x4){0.f, 0.f, 0.f, 0.f};
#pragma unroll
  for (int kb = 0; kb < 128; kb += 32) {
    float4 x0 = *(const float4*)(xr + kb);
    float4 x1 = *(const float4*)(xr + kb + 4);
    bf16x8 a;
    a[0] = (short)f2bf(x0.x); a[1] = (short)f2bf(x0.y);
    a[2] = (short)f2bf(x0.z); a[3] = (short)f2bf(x0.w);
    a[4] = (short)f2bf(x1.x); a[5] = (short)f2bf(x1.y);
    a[6] = (short)f2bf(x1.z); a[7] = (short)f2bf(x1.w);
#pragma unroll
    for (int nt = 0; nt < 8; ++nt) {
      bf16x8 b = *(const bf16x8*)(Wt + (size_t)(nt * 16 + l16) * 128 + kb + quad * 8);
      acc[nt] = __builtin_amdgcn_mfma_f32_16x16x32_bf16(a, b, acc[nt], 0, 0, 0);
    }
  }
  int rbase = row0 + quad * 4;
#pragma unroll
  for (int r = 0; r < 4; ++r) {
    int row = rbase + r;
    if (row < N) {
      float s = nsrc[row];
#pragma unroll
      for (int nt = 0; nt < 8; ++nt)
        Z8[(size_t)row * 128 + nt * 16 + l16] = f2fp8(acc[nt][r] * s);
    }
  }
}

// ---- layer1: per-dst gather-reduce (fp8 rows, half-wave pairs) + fused post-op ----
__global__ __launch_bounds__(256) void k_layer1(const unsigned char* __restrict__ Z8,
                                                const int* __restrict__ offs, const int* __restrict__ srcS,
                                                const float* __restrict__ b1,
                                                const float* __restrict__ nsrc, const float* __restrict__ ndst,
                                                unsigned short* __restrict__ Hb, int N) {
  int lane = threadIdx.x & 63;
  int half = lane >> 5, l32 = lane & 31;
  int d = blockIdx.x * 4 + (threadIdx.x >> 6);
  if (d >= N) return;
  int start = offs[d], end = offs[d + 1];
  float a0 = 0.f, a1 = 0.f, a2 = 0.f, a3 = 0.f;
  int e = start;
  for (; e + 8 <= end; e += 8) {
    int s0 = srcS[e + half], s1 = srcS[e + 2 + half];
    int s2 = srcS[e + 4 + half], s3 = srcS[e + 6 + half];
    unsigned u0 = *(const unsigned*)(Z8 + (size_t)s0 * 128 + l32 * 4);
    unsigned u1 = *(const unsigned*)(Z8 + (size_t)s1 * 128 + l32 * 4);
    unsigned u2 = *(const unsigned*)(Z8 + (size_t)s2 * 128 + l32 * 4);
    unsigned u3 = *(const unsigned*)(Z8 + (size_t)s3 * 128 + l32 * 4);
    f32x2 p0 = __builtin_amdgcn_cvt_pk_f32_fp8(u0, false), q0 = __builtin_amdgcn_cvt_pk_f32_fp8(u0, true);
    f32x2 p1 = __builtin_amdgcn_cvt_pk_f32_fp8(u1, false), q1 = __builtin_amdgcn_cvt_pk_f32_fp8(u1, true);
    f32x2 p2 = __builtin_amdgcn_cvt_pk_f32_fp8(u2, false), q2 = __builtin_amdgcn_cvt_pk_f32_fp8(u2, true);
    f32x2 p3 = __builtin_amdgcn_cvt_pk_f32_fp8(u3, false), q3 = __builtin_amdgcn_cvt_pk_f32_fp8(u3, true);
    a0 += (p0[0] + p1[0]) + (p2[0] + p3[0]);
    a1 += (p0[1] + p1[1]) + (p2[1] + p3[1]);
    a2 += (q0[0] + q1[0]) + (q2[0] + q3[0]);
    a3 += (q0[1] + q1[1]) + (q2[1] + q3[1]);
  }
  for (; e + 2 <= end; e += 2) {
    int s = srcS[e + half];
    unsigned u = *(const unsigned*)(Z8 + (size_t)s * 128 + l32 * 4);
    f32x2 p = __builtin_amdgcn_cvt_pk_f32_fp8(u, false), q = __builtin_amdgcn_cvt_pk_f32_fp8(u, true);
    a0 += p[0]; a1 += p[1]; a2 += q[0]; a3 += q[1];
  }
  if (e < end && half == 0) {
    int s = srcS[e];
    unsigned u = *(const unsigned*)(Z8 + (size_t)s * 128 + l32 * 4);
    f32x2 p = __builtin_amdgcn_cvt_pk_f32_fp8(u, false), q = __builtin_amdgcn_cvt_pk_f32_fp8(u, true);
    a0 += p[0]; a1 += p[1]; a2 += q[0]; a3 += q[1];
  }
  a0 += __shfl_xor(a0, 32, 64);
  a1 += __shfl_xor(a1, 32, 64);
  a2 += __shfl_xor(a2, 32, 64);
  a3 += __shfl_xor(a3, 32, 64);
  if (half == 0) {
    float nd = ndst[d], ns = nsrc[d];
    int f = l32 * 4;
    float h0 = fmaxf(fmaf(nd, a0, b1[f + 0]), 0.f) * ns;
    float h1 = fmaxf(fmaf(nd, a1, b1[f + 1]), 0.f) * ns;
    float h2 = fmaxf(fmaf(nd, a2, b1[f + 2]), 0.f) * ns;
    float h3 = fmaxf(fmaf(nd, a3, b1[f + 3]), 0.f) * ns;
    ushort4 o; o.x = f2bf(h0); o.y = f2bf(h1); o.z = f2bf(h2); o.w = f2bf(h3);
    *(ushort4*)(Hb + (size_t)d * 128 + f) = o;
  }
}

// ---- k_poolgemm (MFMA): part[b] = P_blk^T · H  (split-K, bf16 inputs, f32 acc) ----
// wave w owns g-tile w; A-frag = one 16B load from P_blk; B-frag from swizzled LDS H.
__global__ __launch_bounds__(256) void k_poolgemm(const unsigned short* __restrict__ P16,
                                                  const unsigned short* __restrict__ Hb,
                                                  float* __restrict__ part, int N, int Kpad, int chunk) {
  __shared__ unsigned short Hl[KC * 128];   // 8 KB, 16-short groups XOR-swizzled by (row>>3)
  int t = threadIdx.x;
  int r0 = blockIdx.x * chunk;
  int r1 = min(Kpad, r0 + chunk);
  int wv = t >> 6, lane = t & 63, quad = lane >> 4, l16 = lane & 15;
  f32x4 acc[8];
#pragma unroll
  for (int i = 0; i < 8; ++i) acc[i] = (f32x4){0.f, 0.f, 0.f, 0.f};
  for (int rb = r0; rb < r1; rb += KC) {
    int r = t >> 3, c = (t & 7) * 16;
    int cs = c ^ ((r >> 3) * 16);        // swizzle 16-short group by row-octet
    int row = rb + r;
    if (row < N) {
      const uint4* srcp = (const uint4*)(Hb + (size_t)row * 128 + c);
      *(uint4*)(Hl + r * 128 + cs) = srcp[0];
      *(uint4*)(Hl + r * 128 + cs + 8) = srcp[1];
    } else {
      uint4 z = make_uint4(0, 0, 0, 0);
      *(uint4*)(Hl + r * 128 + cs) = z;
      *(uint4*)(Hl + r * 128 + cs + 8) = z;
    }
    __syncthreads();
    bf16x8 a = *(const bf16x8*)(P16 + ((size_t)(rb >> 3) + quad) * 512 + (wv * 16 + l16) * 8);
#pragma unroll
    for (int ft = 0; ft < 8; ++ft) {
      bf16x8 b;
#pragma unroll
      for (int j = 0; j < 8; ++j) {
        int rr = quad * 8 + j;
        b[j] = (short)Hl[rr * 128 + ((ft ^ (rr >> 3)) * 16) + l16];
      }
      acc[ft] = __builtin_amdgcn_mfma_f32_16x16x32_bf16(a, b, acc[ft], 0, 0, 0);
    }
    __syncthreads();
  }
  float* bp = part + (size_t)blockIdx.x * 64 * DD;
#pragma unroll
  for (int ft = 0; ft < 8; ++ft)
#pragma unroll
    for (int rg = 0; rg < 4; ++rg)
      bp[(wv * 16 + quad * 4 + rg) * DD + ft * 16 + l16] = acc[ft][rg];
}

// ---- fold split-K partials into pooled (zero-init) ----
__global__ __launch_bounds__(256) void k_fold(const float* __restrict__ part, float* __restrict__ pooled) {
  int tid = blockIdx.x * 256 + threadIdx.x;   // grid 256 -> 65536 threads, 8 groups
  int o = tid & 8191, grp = tid >> 13;
  float s = 0.f;
  for (int k = grp; k < GB; k += 8) s += part[(size_t)k * 8192 + o];
  unsafeAtomicAdd(&pooled[o], s);
}

// ---- out = pooled @ W2 + b2 ----
__global__ __launch_bounds__(128) void k_out(const float* __restrict__ pooled, const float* __restrict__ W2,
                                             const float* __restrict__ b2, float* __restrict__ out) {
  __shared__ float p[DD];
  int g = blockIdx.x, d = threadIdx.x;
  p[d] = pooled[g * DD + d];
  __syncthreads();
  float a = b2[d];
#pragma unroll 4
  for (int k = 0; k < DD; ++k) a = fmaf(p[k], W2[k * DD + d], a);
  out[g * DD + d] = a;
}

extern "C" void kernel_launch(void* const* d_in, const int* in_sizes, int n_in,
                              void* d_out, int out_size, void* d_ws, size_t ws_size,
                              hipStream_t stream) {
  const float* X  = (const float*)d_in[0];
  const float* W1 = (const float*)d_in[1];
  const float* b1 = (const float*)d_in[2];
  const float* W2 = (const float*)d_in[3];
  const float* b2 = (const float*)d_in[4];
  const int* src  = (const int*)d_in[5];
  const int* dst  = (const int*)d_in[6];
  const int* gid  = (const int*)d_in[7];
  int E = in_sizes[5];
  int N = in_sizes[7];
  int G = out_size / DD;   // 64
  int nb = (N >> 9) + 1;   // node buckets
  int Kpad = nb << 9;
  int chunk = ((Kpad + GB * KC - 1) / (GB * KC)) * KC;

  char* w = (char*)d_ws;
  size_t o = 0;
  auto carve = [&](size_t bytes) { char* p = w + o; o += (bytes + 255) & ~(size_t)255; return p; };
  // zero-init region
  int*   gcnt   = (int*)  carve((size_t)G * 4);
  float* pooled = (float*)carve((size_t)G * DD * 4);
  size_t zeroBytes = o;
  // rest (fully written before read)
  unsigned* histD = (unsigned*)carve((size_t)PB * 256 * 4);
  unsigned* histS = (unsigned*)carve((size_t)PB * 256 * 4);
  unsigned* tot   = (unsigned*)carve(512 * 4);
  int*   bsD    = (int*)  carve(257 * 4);
  int*   bsS    = (int*)  carve(257 * 4);
  unsigned* pairD = (unsigned*)carve((size_t)E * 4);  // } pairD+pairS (12.8 MB) aliased as part
  unsigned* pairS = (unsigned*)carve((size_t)E * 4);  // }   (GB*32KB = 12.58 MB fits)
  int*   srcS   = (int*)  carve((size_t)E * 4);
  int*   offs   = (int*)  carve((size_t)(N + 1) * 4);
  int*   degI   = (int*)  carve((size_t)N * 4);
  float* nsrc   = (float*)carve((size_t)N * 4);
  float* ndst   = (float*)carve((size_t)N * 4);
  uint2* pwg    = (uint2*)carve((size_t)N * 8);
  unsigned short* Wt = (unsigned short*)carve(128 * 128 * 2);
  unsigned char*  Z8 = (unsigned char*)carve((size_t)N * DD);       // fp8
  unsigned short* Hb = (unsigned short*)carve((size_t)N * DD * 2);
  unsigned short* P16 = (unsigned short*)carve((size_t)Kpad * 64 * 2);  // blocked bf16
  float* part   = (float*)pairD;   // pairD dead after part2d, pairS dead after k_pw

  hipMemsetAsync(d_ws, 0, zeroBytes, stream);

  k_part1a<<<PB, 256, 0, stream>>>(src, dst, gid, histD, histS, gcnt, E, N, G);
  k_pscanA<<<512, 256, 0, stream>>>(histD, histS, tot);
  k_pscanB<<<1, 256, 0, stream>>>(tot, bsD, bsS);
  k_pscanC<<<2 * PB, 256, 0, stream>>>(histD, histS, bsD, bsS);
  k_part1c<<<PB, 256, 0, stream>>>(src, dst, histD, histS, pairD, pairS, E);
  k_part2d<<<nb, 256, 0, stream>>>(pairD, bsD, offs, degI, srcS, N);
  k_norm<<<(N + 255) / 256, 256, 0, stream>>>(degI, gcnt, gid, ndst, pwg, N);
  k_pw<<<nb, 1024, 0, stream>>>(pairS, bsS, pwg, P16, nsrc, N);
  k_wprep<<<128, 128, 0, stream>>>(W1, Wt);
  k_gemm1<<<(N + 63) / 64, 256, 0, stream>>>(X, Wt, nsrc, Z8, N);
  k_layer1<<<(N + 3) / 4, 256, 0, stream>>>(Z8, offs, srcS, b1, nsrc, ndst, Hb, N);
  k_poolgemm<<<GB, 256, 0, stream>>>(P16, Hb, part, N, Kpad, chunk);
  k_fold<<<256, 256, 0, stream>>>(part, pooled);
  k_out<<<G, DD, 0, stream>>>(pooled, W2, b2, (float*)d_out);
}